// Round 10
// baseline (582.003 us; speedup 1.0000x reference)
//
#include <hip/hip_runtime.h>
#include <hip/hip_bf16.h>
#include <math.h>

#define L_SEQ 1024
#define BB 2
#define DD 512
#define HH 8
#define DFFN 2048
#define NSTATE 16
#define DI 1024
#define EPSF 1e-5f

typedef __hip_bfloat16 bf16;
typedef __attribute__((ext_vector_type(8))) short short8v;
typedef __attribute__((ext_vector_type(4))) short short4v;
typedef __attribute__((ext_vector_type(4))) float float4v;

__device__ __forceinline__ float bf2f(bf16 v){ return __bfloat162float(v); }
__device__ __forceinline__ bf16 f2bf(float v){ return __float2bfloat16(v); }
__device__ __forceinline__ short f2bfs(float v){
  bf16 t = __float2bfloat16(v);
  short s; __builtin_memcpy(&s, &t, 2);
  return s;
}

// dA[n] = q^(n+1) via binary powers
__device__ __forceinline__ void powtab(float q1, float* dA){
  float q2=q1*q1, q4=q2*q2, q8=q4*q4;
  dA[0]=q1;       dA[1]=q2;       dA[2]=q2*q1;     dA[3]=q4;
  dA[4]=q4*q1;    dA[5]=q4*q2;    dA[6]=q4*q2*q1;  dA[7]=q8;
  dA[8]=q8*q1;    dA[9]=q8*q2;    dA[10]=q8*q2*q1; dA[11]=q8*q4;
  dA[12]=q8*q4*q1;dA[13]=q8*q4*q2;dA[14]=q8*q4*q2*q1;dA[15]=q8*q8;
}

// ---------------- fused convert + dtype detect ----------------
struct CvtTabF { const void* src[25]; unsigned int off[26]; };
struct CvtTabW { const void* src[12]; unsigned int off[13]; };

__global__ __launch_bounds__(256) void k_cvt(CvtTabF tf, CvtTabW tb,
                                             const unsigned int* __restrict__ w0,
                                             float* __restrict__ dstF, bf16* __restrict__ dstB,
                                             int* __restrict__ flag, int totF, int totB){
  __shared__ int cnt;
  if (threadIdx.x==0) cnt = 0;
  __syncthreads();
  {
    unsigned int x = w0[threadIdx.x];
    unsigned int low = x & 0xffffu;
    int e = (int)((low >> 7) & 0xffu);
    int vote = (low==0u) || (e >= 110 && e <= 140);
    atomicAdd(&cnt, vote);
  }
  __syncthreads();
  const int isbf = (cnt >= 128) ? 1 : 0;      // 1 = bf16 inputs, 0 = fp32
  if (blockIdx.x==0 && threadIdx.x==0) flag[0] = isbf;
  const int tot = totF + totB;
  for (int g = blockIdx.x*256 + threadIdx.x; g < tot; g += gridDim.x*256){
    if (g < totF){
      int k = 0;
      while (tf.off[k+1] <= (unsigned int)g) ++k;
      int e = g - (int)tf.off[k];
      dstF[g] = isbf ? bf2f(((const bf16*)tf.src[k])[e]) : ((const float*)tf.src[k])[e];
    } else {
      int g2 = g - totF;
      int k = 0;
      while (tb.off[k+1] <= (unsigned int)g2) ++k;
      int e = g2 - (int)tb.off[k];
      if (isbf) dstB[g2] = ((const bf16*)tb.src[k])[e];
      else      dstB[g2] = f2bf(((const float*)tb.src[k])[e]);
    }
  }
}

// ---------------- 64-tile batched MFMA GEMM ----------------
__global__ __launch_bounds__(256) void k_mfma_gemm(
    const void* __restrict__ Ab, int cA, long long sAb, long long sAh, long long sAm,
    const void* __restrict__ Bb, long long sBb, long long sBh, long long sBrow, int cB,
    void* __restrict__ Cb, int outBf, long long sCb, long long sCh, long long sCm,
    const float* __restrict__ bias, float scale, int act, int K, int H)
{
  __shared__ short As[64*40];
  __shared__ short Bs[64*40];
  const int tid = threadIdx.x;
  int bx = blockIdx.x, by = blockIdx.y;
  if (gridDim.z == 1 && (gridDim.y & 7) == 0){
    int gx = gridDim.x;
    int lin = by*gx + bx;
    int xcd = lin & 7, i = lin >> 3;
    by = xcd*(gridDim.y >> 3) + i / gx;
    bx = i % gx;
  }
  const int z = blockIdx.z; const int zb = z / H; const int zh = z % H;
  const int col0 = bx << 6, m0 = by << 6;
  const float* Af = (const float*)Ab;
  const bf16*  Aw = (const bf16*)Ab;
  const long long aoff = zb*sAb + zh*sAh;
  const float* Bf = (const float*)Bb;
  const bf16* Bw = (const bf16*)Bb;
  const long long boff = zb*sBb + zh*sBh;
  float4v acc[4];
  #pragma unroll
  for (int i=0;i<4;++i) acc[i] = (float4v)(0.f);
  const int lane = tid & 63, w = tid >> 6;
  const int lr = lane & 15, quad = lane >> 4;

  for (int k0 = 0; k0 < K; k0 += 32){
    if (cA == 1){
      int row = tid >> 2, k8 = (tid & 3) << 3;
      short8v v = *(const short8v*)&Aw[aoff + (long long)(m0+row)*sAm + k0 + k8];
      *(short8v*)&As[row*40 + k8] = v;
    } else {
      #pragma unroll
      for (int i=0;i<2;++i){
        int g = tid + i*256;
        int row = g >> 3, k4 = (g & 7) << 2;
        float4 v = *(const float4*)&Af[aoff + (long long)(m0+row)*sAm + k0 + k4];
        short4v s4; s4.x=f2bfs(v.x); s4.y=f2bfs(v.y); s4.z=f2bfs(v.z); s4.w=f2bfs(v.w);
        *(short4v*)&As[row*40 + k4] = s4;
      }
    }
    if (cB == 2){
      int row = tid >> 2, k8 = (tid & 3) << 3;
      short8v v = *(const short8v*)&Bw[boff + (long long)(col0+row)*sBrow + k0 + k8];
      *(short8v*)&Bs[row*40 + k8] = v;
    } else {
      #pragma unroll
      for (int i=0;i<2;++i){
        int g = tid + i*256;
        int row = g >> 3, k4 = (g & 7) << 2;
        float4 v = *(const float4*)&Bf[boff + (long long)(col0+row)*sBrow + k0 + k4];
        short4v s4; s4.x=f2bfs(v.x); s4.y=f2bfs(v.y); s4.z=f2bfs(v.z); s4.w=f2bfs(v.w);
        *(short4v*)&Bs[row*40 + k4] = s4;
      }
    }
    __syncthreads();
    short8v a = *(short8v*)&As[(w*16 + lr)*40 + quad*8];
    #pragma unroll
    for (int cb=0; cb<4; ++cb){
      short8v bfr = *(short8v*)&Bs[(cb*16 + lr)*40 + quad*8];
      acc[cb] = __builtin_amdgcn_mfma_f32_16x16x32_bf16(a, bfr, acc[cb], 0, 0, 0);
    }
    __syncthreads();
  }
  #pragma unroll
  for (int cb=0; cb<4; ++cb){
    #pragma unroll
    for (int r=0;r<4;++r){
      int m = m0 + w*16 + quad*4 + r;
      int n = col0 + cb*16 + lr;
      float v = acc[cb][r] * scale;
      if (bias) v += bias[n];
      if (act==1) v = fmaxf(v,0.f);
      else if (act==2) v = 0.5f*v*(1.f + erff(v*0.70710678118654752f));
      else if (act==3) v = fmaxf(v,0.f) + log1pf(__expf(-fabsf(v)));
      if (outBf) ((bf16*)Cb)[zb*sCb + zh*sCh + (long long)m*sCm + n] = f2bf(v);
      else       ((float*)Cb)[zb*sCb + zh*sCh + (long long)m*sCm + n] = v;
    }
  }
}

// ---------------- 128x64-tile GEMM (BM=128, BN=64, BK=32; 8 MFMA/wave/K-step) ----------------
__global__ __launch_bounds__(256) void k_gemm_bigA(
    const void* __restrict__ Ab, int cA, long long sAm,
    const bf16* __restrict__ Bw, long long sBrow,
    void* __restrict__ Cb, int outBf, long long sCm,
    const float* __restrict__ bias, int act, int K)
{
  __shared__ short As[128*40];
  __shared__ short Bs[64*40];
  const int tid = threadIdx.x;
  int bx = blockIdx.x, by = blockIdx.y;
  if ((gridDim.y & 7) == 0){
    int gx = gridDim.x;
    int lin = by*gx + bx;
    int xcd = lin & 7, i = lin >> 3;
    by = xcd*(gridDim.y >> 3) + i / gx;
    bx = i % gx;
  }
  const int col0 = bx << 6, m0 = by << 7;
  const float* Af = (const float*)Ab;
  const bf16*  Aw = (const bf16*)Ab;
  const int lane = tid & 63, w = tid >> 6;
  const int lr = lane & 15, quad = lane >> 4;
  float4v acc[2][4];
  #pragma unroll
  for (int mi=0;mi<2;++mi)
    #pragma unroll
    for (int cb=0;cb<4;++cb) acc[mi][cb] = (float4v)(0.f);

  for (int k0 = 0; k0 < K; k0 += 32){
    if (cA == 1){
      #pragma unroll
      for (int i=0;i<2;++i){
        int idx = tid + i*256;
        int row = idx >> 2, k8 = (idx & 3) << 3;
        *(short8v*)&As[row*40 + k8] =
          *(const short8v*)&Aw[(long long)(m0+row)*sAm + k0 + k8];
      }
    } else {
      #pragma unroll
      for (int i=0;i<4;++i){
        int g = tid + i*256;
        int row = g >> 3, k4 = (g & 7) << 2;
        float4 v = *(const float4*)&Af[(long long)(m0+row)*sAm + k0 + k4];
        short4v s4; s4.x=f2bfs(v.x); s4.y=f2bfs(v.y); s4.z=f2bfs(v.z); s4.w=f2bfs(v.w);
        *(short4v*)&As[row*40 + k4] = s4;
      }
    }
    {
      int row = tid >> 2, k8 = (tid & 3) << 3;
      *(short8v*)&Bs[row*40 + k8] =
        *(const short8v*)&Bw[(long long)(col0+row)*sBrow + k0 + k8];
    }
    __syncthreads();
    short8v a[2], bfr[4];
    #pragma unroll
    for (int mi=0;mi<2;++mi) a[mi] = *(short8v*)&As[(w*32 + mi*16 + lr)*40 + quad*8];
    #pragma unroll
    for (int cb=0;cb<4;++cb) bfr[cb] = *(short8v*)&Bs[(cb*16 + lr)*40 + quad*8];
    #pragma unroll
    for (int mi=0;mi<2;++mi)
      #pragma unroll
      for (int cb=0;cb<4;++cb)
        acc[mi][cb] = __builtin_amdgcn_mfma_f32_16x16x32_bf16(a[mi], bfr[cb], acc[mi][cb], 0,0,0);
    __syncthreads();
  }
  #pragma unroll
  for (int mi=0;mi<2;++mi)
    #pragma unroll
    for (int cb=0;cb<4;++cb)
      #pragma unroll
      for (int r=0;r<4;++r){
        int m = m0 + w*32 + mi*16 + quad*4 + r;
        int n = col0 + cb*16 + lr;
        float v = acc[mi][cb][r];
        if (bias) v += bias[n];
        if (act==1) v = fmaxf(v,0.f);
        else if (act==2) v = 0.5f*v*(1.f + erff(v*0.70710678118654752f));
        if (outBf) ((bf16*)Cb)[(long long)m*sCm + n] = f2bf(v);
        else       ((float*)Cb)[(long long)m*sCm + n] = v;
      }
}

// ---------------- split-K 64-tile GEMM -> separate partial buffers ----------------
__global__ __launch_bounds__(256) void k_gemm_skp(
    const void* __restrict__ Ab, int cA, long long sAz, long long sAm,
    const bf16* __restrict__ Bw, long long sBrow,
    float* __restrict__ Cp, long long sCp, long long sCm,
    const float* __restrict__ bias, int K, int KS)
{
  __shared__ short As[64*40];
  __shared__ short Bs[64*40];
  const int tid = threadIdx.x;
  int bx, by, bz;
  {
    int gx = gridDim.x, gy = gridDim.y, gz = gridDim.z;
    int lin = ((int)blockIdx.z*gy + blockIdx.y)*gx + blockIdx.x;
    int xcd = lin & 7, i = lin >> 3;
    bx = i % gx; int rest = i / gx;
    int pair = xcd * ((gy*gz) >> 3) + rest;
    by = pair % gy; bz = pair / gy;
  }
  const int zb = bz / KS, kc = bz % KS;
  const int Kc = K / KS;
  const int col0 = bx << 6, m0 = by << 6;
  const float* Af = (const float*)Ab;
  const bf16*  Aw = (const bf16*)Ab;
  const long long aoff = (long long)zb*sAz;
  float4v acc[4];
  #pragma unroll
  for (int i=0;i<4;++i) acc[i] = (float4v)(0.f);
  const int lane = tid & 63, w = tid >> 6;
  const int lr = lane & 15, quad = lane >> 4;

  const int kbeg = kc*Kc;
  for (int k0 = kbeg; k0 < kbeg + Kc; k0 += 32){
    if (cA == 1){
      int row = tid >> 2, k8 = (tid & 3) << 3;
      *(short8v*)&As[row*40 + k8] =
        *(const short8v*)&Aw[aoff + (long long)(m0+row)*sAm + k0 + k8];
    } else {
      #pragma unroll
      for (int i=0;i<2;++i){
        int g = tid + i*256;
        int row = g >> 3, k4 = (g & 7) << 2;
        float4 v = *(const float4*)&Af[aoff + (long long)(m0+row)*sAm + k0 + k4];
        short4v s4; s4.x=f2bfs(v.x); s4.y=f2bfs(v.y); s4.z=f2bfs(v.z); s4.w=f2bfs(v.w);
        *(short4v*)&As[row*40 + k4] = s4;
      }
    }
    {
      int row = tid >> 2, k8 = (tid & 3) << 3;
      *(short8v*)&Bs[row*40 + k8] =
        *(const short8v*)&Bw[(long long)(col0+row)*sBrow + k0 + k8];
    }
    __syncthreads();
    short8v a = *(short8v*)&As[(w*16 + lr)*40 + quad*8];
    #pragma unroll
    for (int cb=0; cb<4; ++cb){
      short8v bfr = *(short8v*)&Bs[(cb*16 + lr)*40 + quad*8];
      acc[cb] = __builtin_amdgcn_mfma_f32_16x16x32_bf16(a, bfr, acc[cb], 0, 0, 0);
    }
    __syncthreads();
  }
  #pragma unroll
  for (int cb=0; cb<4; ++cb){
    #pragma unroll
    for (int r=0;r<4;++r){
      int m = m0 + w*16 + quad*4 + r;
      int n = col0 + cb*16 + lr;
      float v = acc[cb][r];
      if (kc == 0 && bias) v += bias[n];
      Cp[(long long)bz*sCp + (long long)m*sCm + n] = v;
    }
  }
}

// ---------------- split-K atomic GEMM (xproj only; dbc pre-zeroed by conv) ----------------
__global__ __launch_bounds__(256) void k_gemm_sk(
    const void* __restrict__ Ab, int cA, long long sAz, long long sAm,
    const bf16* __restrict__ Bw, long long sBrow,
    float* __restrict__ Cb, long long sCz, long long sCm,
    const float* __restrict__ bias, int K, int KS)
{
  __shared__ short As[64*40];
  __shared__ short Bs[64*40];
  const int tid = threadIdx.x;
  int bx, by, bz;
  {
    int gx = gridDim.x, gy = gridDim.y, gz = gridDim.z;
    int lin = ((int)blockIdx.z*gy + blockIdx.y)*gx + blockIdx.x;
    int xcd = lin & 7, i = lin >> 3;
    bx = i % gx; int rest = i / gx;
    int pair = xcd * ((gy*gz) >> 3) + rest;
    by = pair % gy; bz = pair / gy;
  }
  const int zb = bz / KS, kc = bz % KS;
  const int Kc = K / KS;
  const int col0 = bx << 6, m0 = by << 6;
  const bf16*  Aw = (const bf16*)Ab;
  const float* Af = (const float*)Ab;
  const long long aoff = (long long)zb*sAz;
  float4v acc[4];
  #pragma unroll
  for (int i=0;i<4;++i) acc[i] = (float4v)(0.f);
  const int lane = tid & 63, w = tid >> 6;
  const int lr = lane & 15, quad = lane >> 4;

  const int kbeg = kc*Kc;
  for (int k0 = kbeg; k0 < kbeg + Kc; k0 += 32){
    if (cA == 1){
      int row = tid >> 2, k8 = (tid & 3) << 3;
      *(short8v*)&As[row*40 + k8] =
        *(const short8v*)&Aw[aoff + (long long)(m0+row)*sAm + k0 + k8];
    } else {
      #pragma unroll
      for (int i=0;i<2;++i){
        int g = tid + i*256;
        int row = g >> 3, k4 = (g & 7) << 2;
        float4 v = *(const float4*)&Af[aoff + (long long)(m0+row)*sAm + k0 + k4];
        short4v s4; s4.x=f2bfs(v.x); s4.y=f2bfs(v.y); s4.z=f2bfs(v.z); s4.w=f2bfs(v.w);
        *(short4v*)&As[row*40 + k4] = s4;
      }
    }
    {
      int row = tid >> 2, k8 = (tid & 3) << 3;
      *(short8v*)&Bs[row*40 + k8] =
        *(const short8v*)&Bw[(long long)(col0+row)*sBrow + k0 + k8];
    }
    __syncthreads();
    short8v a = *(short8v*)&As[(w*16 + lr)*40 + quad*8];
    #pragma unroll
    for (int cb=0; cb<4; ++cb){
      short8v bfr = *(short8v*)&Bs[(cb*16 + lr)*40 + quad*8];
      acc[cb] = __builtin_amdgcn_mfma_f32_16x16x32_bf16(a, bfr, acc[cb], 0, 0, 0);
    }
    __syncthreads();
  }
  #pragma unroll
  for (int cb=0; cb<4; ++cb){
    #pragma unroll
    for (int r=0;r<4;++r){
      int m = m0 + w*16 + quad*4 + r;
      int n = col0 + cb*16 + lr;
      float v = acc[cb][r];
      if (kc == 0 && bias) v += bias[n];
      atomicAdd(&Cb[(long long)zb*sCz + (long long)m*sCm + n], v);
    }
  }
}

// ---------------- flash attention, split-K partials (8 chunks of 128 kpos), bf16 Opart ----------------
__global__ __launch_bounds__(256) void k_flash2(
    const bf16* __restrict__ Qb, int ldq, int qoff,
    const bf16* __restrict__ Kb, int ldk, int koff,
    const bf16* __restrict__ Vb, int ldv, int voff,
    bf16* __restrict__ Opart, float* __restrict__ Ml, float scale)
{
  __shared__ short Qs[64*40];
  __shared__ short Ks[64*40];
  __shared__ short Vs[64*40];
  __shared__ short Ps[64*40];
  const int tid = threadIdx.x;
  const int q0 = blockIdx.x << 6;
  const int z = blockIdx.y; const int b = z >> 3; const int hoff = (z & 7) << 6;
  const int kc = blockIdx.z;
  const int lane = tid & 63, w = tid >> 6;
  const int lr = lane & 15, quad = lane >> 4;

  #pragma unroll
  for (int i=0;i<2;++i){
    int idx = tid + i*256;
    int row = idx >> 3, d8 = (idx & 7) << 3;
    *(short8v*)&Qs[row*40 + d8] =
      *(const short8v*)&Qb[(size_t)((q0+row)*BB + b)*ldq + qoff + hoff + d8];
  }

  float m_r[4], l_r[4];
  #pragma unroll
  for (int r=0;r<4;++r){ m_r[r] = -1e30f; l_r[r] = 0.f; }
  float4v acc_o[4];
  #pragma unroll
  for (int cb=0;cb<4;++cb) acc_o[cb] = (float4v)(0.f);

  short8v kr[2], vr[2];
  #pragma unroll
  for (int i=0;i<2;++i){
    int idx = tid + i*256;
    int row = kc*128 + (idx >> 3); int d8 = (idx & 7) << 3;
    kr[i] = *(const short8v*)&Kb[(size_t)(row*BB + b)*ldk + koff + hoff + d8];
    vr[i] = *(const short8v*)&Vb[(size_t)(row*BB + b)*ldv + voff + hoff + d8];
  }

  for (int kt=0; kt<2; ++kt){
    __syncthreads();
    #pragma unroll
    for (int i=0;i<2;++i){
      int idx = tid + i*256;
      int row = idx >> 3, d8 = (idx & 7) << 3;
      *(short8v*)&Ks[row*40 + d8] = kr[i];
      int sc = row ^ d8;
      #pragma unroll
      for (int j=0;j<8;++j) Vs[(d8+j)*40 + sc] = vr[i][j];
    }
    if (kt < 1){
      #pragma unroll
      for (int i=0;i<2;++i){
        int idx = tid + i*256;
        int row = kc*128 + 64 + (idx >> 3); int d8 = (idx & 7) << 3;
        kr[i] = *(const short8v*)&Kb[(size_t)(row*BB + b)*ldk + koff + hoff + d8];
        vr[i] = *(const short8v*)&Vb[(size_t)(row*BB + b)*ldv + voff + hoff + d8];
      }
    }
    __syncthreads();
    short8v a0 = *(short8v*)&Qs[(w*16+lr)*40 + quad*8];
    short8v a1 = *(short8v*)&Qs[(w*16+lr)*40 + quad*8 + 32];
    float4v s[4];
    #pragma unroll
    for (int cb=0;cb<4;++cb){
      short8v b0 = *(short8v*)&Ks[(cb*16+lr)*40 + quad*8];
      short8v b1 = *(short8v*)&Ks[(cb*16+lr)*40 + quad*8 + 32];
      float4v t = __builtin_amdgcn_mfma_f32_16x16x32_bf16(a0, b0, (float4v)(0.f), 0,0,0);
      s[cb] = __builtin_amdgcn_mfma_f32_16x16x32_bf16(a1, b1, t, 0,0,0);
    }
    #pragma unroll
    for (int cb=0;cb<4;++cb)
      #pragma unroll
      for (int r=0;r<4;++r) s[cb][r] *= scale;
    float al[4];
    #pragma unroll
    for (int r=0;r<4;++r){
      float mx = fmaxf(fmaxf(s[0][r],s[1][r]),fmaxf(s[2][r],s[3][r]));
      #pragma unroll
      for (int ofs=1; ofs<16; ofs<<=1) mx = fmaxf(mx, __shfl_xor(mx, ofs));
      float mnew = fmaxf(m_r[r], mx);
      al[r] = __expf(m_r[r] - mnew);
      float sum = 0.f;
      #pragma unroll
      for (int cb=0;cb<4;++cb){
        float p = __expf(s[cb][r] - mnew);
        s[cb][r] = p;
        sum += p;
      }
      #pragma unroll
      for (int ofs=1; ofs<16; ofs<<=1) sum += __shfl_xor(sum, ofs);
      l_r[r] = l_r[r]*al[r] + sum;
      m_r[r] = mnew;
    }
    #pragma unroll
    for (int cb=0;cb<4;++cb)
      #pragma unroll
      for (int r=0;r<4;++r){
        acc_o[cb][r] *= al[r];
        Ps[(w*16 + quad*4 + r)*40 + cb*16 + lr] = f2bfs(s[cb][r]);
      }
    __syncthreads();
    short8v p0 = *(short8v*)&Ps[(w*16+lr)*40 + quad*8];
    short8v p1 = *(short8v*)&Ps[(w*16+lr)*40 + quad*8 + 32];
    #pragma unroll
    for (int cb=0;cb<4;++cb){
      int dcol = cb*16 + lr;
      int sw = (dcol >> 3) & 7;
      short8v v0 = *(short8v*)&Vs[dcol*40 + ((quad ^ sw) << 3)];
      short8v v1 = *(short8v*)&Vs[dcol*40 + (((quad+4) ^ sw) << 3)];
      acc_o[cb] = __builtin_amdgcn_mfma_f32_16x16x32_bf16(p0, v0, acc_o[cb], 0,0,0);
      acc_o[cb] = __builtin_amdgcn_mfma_f32_16x16x32_bf16(p1, v1, acc_o[cb], 0,0,0);
    }
  }
  #pragma unroll
  for (int r=0;r<4;++r){
    int row = q0 + w*16 + quad*4 + r;
    size_t obase = ((size_t)(kc*16 + z)*1024 + row)*64;
    #pragma unroll
    for (int cb=0;cb<4;++cb)
      Opart[obase + cb*16 + lr] = f2bf(acc_o[cb][r]);
    if (lr == 0){
      size_t mi = ((size_t)kc*16384 + z*1024 + row)*2;
      Ml[mi] = m_r[r]; Ml[mi+1] = l_r[r];
    }
  }
}

// ---------------- combine 8 split-K partials (bf16 Opart) ----------------
__global__ __launch_bounds__(256) void k_fcomb(const bf16* __restrict__ Opart, const float* __restrict__ Ml,
                                               bf16* __restrict__ O, float* __restrict__ Mfin)
{
  int gid = blockIdx.x*256 + threadIdx.x;   // 1M
  int row = gid >> 6, d = gid & 63;
  int z = row >> 10, q = row & 1023;
  float m[8], l[8];
  #pragma unroll
  for (int kc=0;kc<8;++kc){
    size_t mi = ((size_t)kc*16384 + row)*2;
    m[kc] = Ml[mi]; l[kc] = Ml[mi+1];
  }
  float ms = -1e30f;
  #pragma unroll
  for (int kc=0;kc<8;++kc) ms = fmaxf(ms, m[kc]);
  float ls = 0.f, o = 0.f;
  #pragma unroll
  for (int kc=0;kc<8;++kc){
    float c = __expf(m[kc]-ms);
    ls += l[kc]*c;
    o  += bf2f(Opart[((size_t)kc*16384 + row)*64 + d]) * c;
  }
  o /= ls;
  int b = z >> 3, hoff = (z & 7) << 6;
  O[((size_t)q*BB + b)*512 + hoff + d] = f2bf(o);
  if (d == 0){ Mfin[(size_t)row*2] = ms; Mfin[(size_t)row*2+1] = ls; }
}

// ---------------- head-mean of P from Q,K + final m,l ----------------
__global__ __launch_bounds__(256) void k_pmean(
    const bf16* __restrict__ Qb, int ldq,
    const bf16* __restrict__ Kb, int ldk,
    const float* __restrict__ Mfin, void* __restrict__ out,
    const int* __restrict__ flag, float scale)
{
  __shared__ short Qs[64*40];
  __shared__ short Ks[64*40];
  const int tid = threadIdx.x;
  const int k0 = blockIdx.x << 6, q0 = blockIdx.y << 6;
  const int b = blockIdx.z;
  const int lane = tid & 63, w = tid >> 6;
  const int lr = lane & 15, quad = lane >> 4;
  float acc[4][4];
  #pragma unroll
  for (int cb=0;cb<4;++cb)
    #pragma unroll
    for (int r=0;r<4;++r) acc[cb][r] = 0.f;

  for (int h=0; h<8; ++h){
    int z = b*8 + h, hoff = h << 6;
    __syncthreads();
    #pragma unroll
    for (int i=0;i<2;++i){
      int idx = tid + i*256;
      int row = idx >> 3, d8 = (idx & 7) << 3;
      *(short8v*)&Qs[row*40 + d8] = *(const short8v*)&Qb[((size_t)(q0+row)*BB + b)*ldq + hoff + d8];
      *(short8v*)&Ks[row*40 + d8] = *(const short8v*)&Kb[((size_t)(k0+row)*BB + b)*ldk + hoff + d8];
    }
    __syncthreads();
    float mm[4], li[4];
    #pragma unroll
    for (int r=0;r<4;++r){
      int qrow = q0 + w*16 + quad*4 + r;
      size_t mi = ((size_t)z*1024 + qrow)*2;
      mm[r] = Mfin[mi]; li[r] = 1.f/Mfin[mi+1];
    }
    short8v a0 = *(short8v*)&Qs[(w*16+lr)*40 + quad*8];
    short8v a1 = *(short8v*)&Qs[(w*16+lr)*40 + quad*8 + 32];
    #pragma unroll
    for (int cb=0;cb<4;++cb){
      short8v b0 = *(short8v*)&Ks[(cb*16+lr)*40 + quad*8];
      short8v b1 = *(short8v*)&Ks[(cb*16+lr)*40 + quad*8 + 32];
      float4v t = __builtin_amdgcn_mfma_f32_16x16x32_bf16(a0, b0, (float4v)(0.f), 0,0,0);
      t = __builtin_amdgcn_mfma_f32_16x16x32_bf16(a1, b1, t, 0,0,0);
      #pragma unroll
      for (int r=0;r<4;++r)
        acc[cb][r] += __expf(t[r]*scale - mm[r]) * li[r];
    }
  }
  #pragma unroll
  for (int cb=0;cb<4;++cb)
    #pragma unroll
    for (int r=0;r<4;++r){
      int q = q0 + w*16 + quad*4 + r;
      int k = k0 + cb*16 + lr;
      float v = acc[cb][r] * 0.125f;
      size_t o = (size_t)(1u<<20) + ((size_t)b<<20) + (size_t)q*1024 + k;
      if (flag[0]) ((bf16*)out)[o] = f2bf(v);
      else         ((float*)out)[o] = v;
    }
}

// ---------------- norms (consume split-K partials) ----------------
__global__ __launch_bounds__(256) void k_add_rmsnorm(float* __restrict__ x, const float* __restrict__ tp,
                                                     long long pstr, int KS, const float* __restrict__ w){
  int row = blockIdx.x; size_t base = (size_t)row*DD;
  int tid = threadIdx.x;
  float v0 = x[base+tid], v1 = x[base+tid+256];
  for (int k=0;k<KS;++k){ v0 += tp[k*pstr + base+tid]; v1 += tp[k*pstr + base+tid+256]; }
  __shared__ float red[256];
  red[tid] = v0*v0 + v1*v1; __syncthreads();
  for (int s=128;s>0;s>>=1){ if(tid<s) red[tid]+=red[tid+s]; __syncthreads(); }
  float rms = rsqrtf(red[0]*(1.f/DD) + EPSF);
  x[base+tid]     = v0 * w[tid]     * rms;
  x[base+tid+256] = v1 * w[tid+256] * rms;
}

__global__ __launch_bounds__(256) void k_add_rmsnorm_out(const float* __restrict__ x, const float* __restrict__ tp,
                                                         long long pstr, int KS,
                                                         const float* __restrict__ w, void* __restrict__ out,
                                                         const int* __restrict__ flag){
  int row = blockIdx.x; size_t base = (size_t)row*DD;
  int tid = threadIdx.x;
  float v0 = x[base+tid], v1 = x[base+tid+256];
  for (int k=0;k<KS;++k){ v0 += tp[k*pstr + base+tid]; v1 += tp[k*pstr + base+tid+256]; }
  __shared__ float red[256];
  red[tid] = v0*v0 + v1*v1; __syncthreads();
  for (int s=128;s>0;s>>=1){ if(tid<s) red[tid]+=red[tid+s]; __syncthreads(); }
  float rms = rsqrtf(red[0]*(1.f/DD) + EPSF);
  float o0 = v0 * w[tid]     * rms;
  float o1 = v1 * w[tid+256] * rms;
  if (flag[0]){ ((bf16*)out)[base+tid] = f2bf(o0); ((bf16*)out)[base+tid+256] = f2bf(o1); }
  else        { ((float*)out)[base+tid] = o0;      ((float*)out)[base+tid+256] = o1; }
}

// fused: tgt = rmsnorm(tgt + sum tp, n2w); xn = layernorm(tgt, ln1) (bf16)
__global__ __launch_bounds__(256) void k_rms_ln(float* __restrict__ tgt, const float* __restrict__ tp,
                                                long long pstr, const float* __restrict__ n2w,
                                                const float* __restrict__ lw, const float* __restrict__ lb,
                                                bf16* __restrict__ xn){
  int r = blockIdx.x;
  int b = r >> 10, l = r & 1023;
  size_t base = ((size_t)l*BB + b)*DD;
  int tid = threadIdx.x;
  float v0 = tgt[base+tid] + tp[base+tid] + tp[pstr + base+tid];
  float v1 = tgt[base+tid+256] + tp[base+tid+256] + tp[pstr + base+tid+256];
  __shared__ float red[256];
  red[tid] = v0*v0 + v1*v1; __syncthreads();
  for (int s=128;s>0;s>>=1){ if(tid<s) red[tid]+=red[tid+s]; __syncthreads(); }
  float rms = rsqrtf(red[0]*(1.f/DD) + EPSF);
  v0 = v0 * n2w[tid]     * rms;
  v1 = v1 * n2w[tid+256] * rms;
  tgt[base+tid] = v0; tgt[base+tid+256] = v1;
  __syncthreads();
  red[tid] = v0 + v1; __syncthreads();
  for (int s=128;s>0;s>>=1){ if(tid<s) red[tid]+=red[tid+s]; __syncthreads(); }
  float mean = red[0]*(1.f/DD);
  __syncthreads();
  red[tid] = v0*v0 + v1*v1; __syncthreads();
  for (int s=128;s>0;s>>=1){ if(tid<s) red[tid]+=red[tid+s]; __syncthreads(); }
  float var = red[0]*(1.f/DD) - mean*mean;
  float rstd = rsqrtf(var + EPSF);
  size_t dst = (size_t)r*DD;
  xn[dst+tid]     = f2bf((v0-mean)*rstd*lw[tid]     + lb[tid]);
  xn[dst+tid+256] = f2bf((v1-mean)*rstd*lw[tid+256] + lb[tid+256]);
}

// combine_ln over yproj partials
__global__ __launch_bounds__(256) void k_combine_ln(const float* __restrict__ yp, long long pstr,
                                                    const float* __restrict__ w, const float* __restrict__ bias,
                                                    bf16* __restrict__ mo){
  int r = blockIdx.x; int b = r>>10, l = r&1023;
  size_t rf = (size_t)r*DD;
  size_t rb = ((size_t)(b<<10) + (1023 - l))*DD;
  int tid = threadIdx.x;
  float v0 = yp[rf+tid]     + yp[pstr + rf+tid]     + yp[2*pstr + rb+tid]     + yp[3*pstr + rb+tid];
  float v1 = yp[rf+tid+256] + yp[pstr + rf+tid+256] + yp[2*pstr + rb+tid+256] + yp[3*pstr + rb+tid+256];
  __shared__ float red[256];
  red[tid] = v0 + v1; __syncthreads();
  for (int s=128;s>0;s>>=1){ if(tid<s) red[tid]+=red[tid+s]; __syncthreads(); }
  float mean = red[0]*(1.f/DD);
  __syncthreads();
  red[tid] = v0*v0 + v1*v1; __syncthreads();
  for (int s=128;s>0;s>>=1){ if(tid<s) red[tid]+=red[tid+s]; __syncthreads(); }
  float var = red[0]*(1.f/DD) - mean*mean;
  float rstd = rsqrtf(var + EPSF);
  mo[rf+tid]     = f2bf((v0-mean)*rstd*w[tid]     + bias[tid]);
  mo[rf+tid+256] = f2bf((v1-mean)*rstd*w[tid+256] + bias[tid+256]);
}

__global__ __launch_bounds__(256) void k_bimamba_final(float* __restrict__ tgt, const float* __restrict__ fp,
                                                       long long pstr, const float* __restrict__ w){
  int r = blockIdx.x; int b = r>>10, l = r&1023;
  size_t t = ((size_t)l*BB + b)*DD;
  size_t f = (size_t)r*DD;
  int tid = threadIdx.x;
  float v0 = 2.f*tgt[t+tid], v1 = 2.f*tgt[t+tid+256];
  #pragma unroll
  for (int k=0;k<4;++k){ v0 += fp[k*pstr + f+tid]; v1 += fp[k*pstr + f+tid+256]; }
  __shared__ float red[256];
  red[tid] = v0*v0 + v1*v1; __syncthreads();
  for (int s=128;s>0;s>>=1){ if(tid<s) red[tid]+=red[tid+s]; __syncthreads(); }
  float rms = rsqrtf(red[0]*(1.f/DD) + EPSF);
  tgt[t+tid]     = v0 * w[tid]     * rms;
  tgt[t+tid+256] = v1 * w[tid+256] * rms;
}

// ---------------- causal depthwise conv + silu -> bf16 (+dbc zeroing) ----------------
__global__ __launch_bounds__(256) void k_conv_silu(const float* __restrict__ xz, const float* __restrict__ cw,
                                                   const float* __restrict__ cb, bf16* __restrict__ xmc,
                                                   float* __restrict__ dbcz){
  int rev = blockIdx.y;
  int idx = blockIdx.x*256 + threadIdx.x;  // 2M
  if (rev == 0 && blockIdx.x < 1024) dbcz[idx] = 0.f;   // zero 262144 dbc floats
  int c = idx & 1023;
  int l = (idx >> 10) & 1023;
  int b = idx >> 20;
  float acc = cb[c];
  float w4[4];
  #pragma unroll
  for (int j=0;j<4;++j) w4[j] = cw[(c<<2)+j];
  #pragma unroll
  for (int j=0;j<4;++j){
    int t = l - 3 + j;
    if (t >= 0){
      int src = rev ? (1023 - t) : t;
      acc = fmaf(w4[j], xz[((size_t)(b<<10) + src)*2048 + c], acc);
    }
  }
  xmc[(size_t)rev*(2u<<20) + idx] = f2bf(acc / (1.f + __expf(-acc)));
}

// ---------------- chunked selective scan: 64 chunks of 16 steps ----------------
__global__ __launch_bounds__(256) void k_scan1(
    const bf16* __restrict__ delta_f, const bf16* __restrict__ delta_b,
    const bf16* __restrict__ xmc_f,  const bf16* __restrict__ xmc_b,
    const float* __restrict__ dbc_f,  const float* __restrict__ dbc_b,
    const float* __restrict__ Alog,
    float* __restrict__ hend, float* __restrict__ Sdl)
{
  int ch = blockIdx.x*256 + threadIdx.x;
  int c = blockIdx.y;
  int dir = ch >> 11, b = (ch >> 10) & 1, d = ch & 1023;
  const bf16* delta = dir ? delta_b : delta_f;
  const bf16* xmc   = dir ? xmc_b   : xmc_f;
  const float* dbc  = dir ? dbc_b   : dbc_f;
  float Av[NSTATE]; bool fast = true;
  #pragma unroll
  for (int n=0;n<NSTATE;++n){
    Av[n] = -__expf(Alog[d*NSTATE+n]);
    fast = fast && (fabsf(Av[n] + (float)(n+1)) < 1e-4f*(float)(n+1));
  }
  float h[NSTATE];
  #pragma unroll
  for (int n=0;n<NSTATE;++n) h[n]=0.f;
  float S = 0.f;
  int r0 = b*1024 + c*16;
  for (int t=0;t<16;++t){
    int r = r0 + t;
    float dl = bf2f(delta[((size_t)r<<10) + d]);
    float x  = bf2f(xmc[((size_t)r<<10) + d]);
    const float4* bp = (const float4*)(dbc + (size_t)r*64 + 32);
    float Bv[NSTATE];
    ((float4*)Bv)[0]=bp[0]; ((float4*)Bv)[1]=bp[1]; ((float4*)Bv)[2]=bp[2]; ((float4*)Bv)[3]=bp[3];
    S += dl;
    float dx = dl*x;
    float dA[NSTATE];
    if (fast){ powtab(__expf(-dl), dA); }
    else {
      #pragma unroll
      for (int n=0;n<NSTATE;++n) dA[n] = __expf(dl*Av[n]);
    }
    #pragma unroll
    for (int n=0;n<NSTATE;++n)
      h[n] = fmaf(dA[n], h[n], dx*Bv[n]);
  }
  size_t base = ((size_t)c*4096 + ch)*16;
  #pragma unroll
  for (int n=0;n<NSTATE;++n) hend[base+n] = h[n];
  Sdl[c*4096 + ch] = S;
}

__global__ __launch_bounds__(256) void k_scan_carry(const float* __restrict__ Alog,
                                                    float* __restrict__ hh, const float* __restrict__ Sdl)
{
  int g = blockIdx.x*256 + threadIdx.x;   // 65536
  int ch = g >> 4, n = g & 15;
  int d = ch & 1023;
  float Av = -__expf(Alog[d*16+n]);
  float h = 0.f;
  for (int c=0;c<64;++c){
    size_t base = ((size_t)c*4096 + ch)*16 + n;
    float he = hh[base];
    hh[base] = h;
    h = fmaf(__expf(Av*Sdl[c*4096+ch]), h, he);
  }
}

__global__ __launch_bounds__(256) void k_scan2(
    const bf16* __restrict__ delta_f, const bf16* __restrict__ delta_b,
    const bf16* __restrict__ xmc_f,  const bf16* __restrict__ xmc_b,
    const float* __restrict__ dbc_f,  const float* __restrict__ dbc_b,
    const float* __restrict__ Alog,   const float* __restrict__ hin,
    const float* __restrict__ xz,     const float* __restrict__ Dp,
    bf16* __restrict__ yo)
{
  int ch = blockIdx.x*256 + threadIdx.x;
  int c = blockIdx.y;
  int dir = ch >> 11, b = (ch >> 10) & 1, d = ch & 1023;
  const bf16* delta = dir ? delta_b : delta_f;
  const bf16* xmc   = dir ? xmc_b   : xmc_f;
  const float* dbc  = dir ? dbc_b   : dbc_f;
  float Av[NSTATE]; bool fast = true;
  #pragma unroll
  for (int n=0;n<NSTATE;++n){
    Av[n] = -__expf(Alog[d*NSTATE+n]);
    fast = fast && (fabsf(Av[n] + (float)(n+1)) < 1e-4f*(float)(n+1));
  }
  float h[NSTATE];
  size_t cbase = ((size_t)c*4096 + ch)*16;
  #pragma unroll
  for (int n=0;n<NSTATE;++n) h[n] = hin[cbase+n];
  float Dd = Dp[d];
  int r0 = b*1024 + c*16;
  for (int t=0;t<16;++t){
    int r = r0 + t;
    int lidx = c*16 + t;
    float dl = bf2f(delta[((size_t)r<<10) + d]);
    float x  = bf2f(xmc[((size_t)r<<10) + d]);
    const float4* bp = (const float4*)(dbc + (size_t)r*64 + 32);
    float Bv[NSTATE], Cv[NSTATE];
    ((float4*)Bv)[0]=bp[0]; ((float4*)Bv)[1]=bp[1]; ((float4*)Bv)[2]=bp[2]; ((float4*)Bv)[3]=bp[3];
    ((float4*)Cv)[0]=bp[4]; ((float4*)Cv)[1]=bp[5]; ((float4*)Cv)[2]=bp[6]; ((float4*)Cv)[3]=bp[7];
    float dx = dl*x;
    float dA[NSTATE];
    if (fast){ powtab(__expf(-dl), dA); }
    else {
      #pragma unroll
      for (int n=0;n<NSTATE;++n) dA[n] = __expf(dl*Av[n]);
    }
    float acc0 = 0.f, acc1 = 0.f;
    #pragma unroll
    for (int n=0;n<NSTATE;n+=2){
      h[n]   = fmaf(dA[n],   h[n],   dx*Bv[n]);
      h[n+1] = fmaf(dA[n+1], h[n+1], dx*Bv[n+1]);
      acc0 = fmaf(h[n],   Cv[n],   acc0);
      acc1 = fmaf(h[n+1], Cv[n+1], acc1);
    }
    float acc = acc0 + acc1;
    int src = dir ? (1023 - lidx) : lidx;
    float zz = xz[((size_t)(b<<10) + src)*2048 + 1024 + d];
    float sg = zz / (1.f + __expf(-zz));
    yo[(size_t)dir*(2u<<20) + ((size_t)r<<10) + d] = f2bf((acc + Dd*x) * sg);
  }
}

extern "C" void kernel_launch(void* const* d_in, const int* in_sizes, int n_in,
                              void* d_out, int out_size, void* d_ws, size_t ws_size,
                              hipStream_t stream)
{
  if (n_in < 37) return;
  static const unsigned int SZ[37] = {
    1048576,1048576,786432,1536,262144,512,786432,1536,262144,512,
    512,512,512,512,1048576,2048,1048576,512,512,512,
    512,512,1048576,2048,1048576,512,1048576,2048,4096,1024,
    65536,32768,1024,16384,1024,524288,512
  };
  static const unsigned char ISW[37] = {
    0,0,1,0,1,0,1,0,1,0, 0,0,0,0,1,0,1,0,0,0,
    0,0,1,0,1,0,1,0,0,0, 1,1,0,0,0,1,0
  };
  const long long MF = 1u<<20;
  if (ws_size < (size_t)(32*MF)*sizeof(float)) return;   // 128 MB

  float* ws = (float*)d_ws;
  float* inF = ws;                       // fp32 params arena  [0, 3MF)
  bf16*  inB = (bf16*)(ws + 3*MF);       // bf16 weight arena  [3MF, 7MF)
  float* t2    = ws + 7*MF;
  float* mbuf  = ws + 8*MF;
  float* proj  = ws + 9*MF;              // 3MF
  float* big   = ws + 12*MF;             // 16MF
  float* ff1   = ws + 28*MF;             // 2MF (bf16 4M els; ybf/ff1B)

  CvtTabF tf; CvtTabW tb;
  unsigned int fOff[37], bOff[37];
  {
    int nf=0, nb=0; unsigned int of=0, ob=0;
    for (int i=0;i<37;++i){
      if (ISW[i]){ tb.src[nb]=d_in[i]; tb.off[nb]=ob; bOff[i]=ob; ob+=SZ[i]; ++nb; }
      else       { tf.src[nf]=d_in[i]; tf.off[nf]=of; fOff[i]=of; of+=SZ[i]; ++nf; }
    }
    tf.off[25]=of; tb.off[12]=ob;
    int* flag = (int*)(ws + 3*MF - 16);

    #define PF(i) (inF + fOff[i])
    #define PW(i) (inB + bOff[i])

    float* tgt_f = PF(0);
    float* mem_f = PF(1);
    bf16* qkvB   = (bf16*)proj;          // 3M els
    bf16* qB     = (bf16*)proj;          // 1M els (CA)
    bf16* kvB    = (bf16*)(proj + 1*MF); // 2M els (CA)
    bf16* attnoB = (bf16*)mbuf;          // 1M els
    bf16* xnB    = (bf16*)t2;            // 1M els
    // attention phase (big):
    bf16*  OpartB  = (bf16*)big;            // 8M els = 4MF
    float* Ml      = big + 4*MF;            // 256K floats
    float* Mfin    = big + 4*MF + 262144;   // 32K
    float* tpart   = big + 5*MF;            // 2 partials x 1MF
    // mamba phase (big):
    float* xz      = big;                   // 4MF
    bf16*  xmc_f   = (bf16*)(big + 4*MF);   // 2M els
    bf16*  xmc_b   = (bf16*)(big + 5*MF);
    bf16*  delta_f = (bf16*)(big + 6*MF);
    bf16*  delta_b = (bf16*)(big + 7*MF);
    float* hend    = big + 8*MF;            // 4MF
    float* Sdl     = big + 12*MF;           // 256K
    float* dbc_f   = proj;
    float* dbc_b   = proj + 131072;
    float* ffop    = big;                   // 4 partials x 1MF (after xz dead)
    float* lin2p   = big + 4*MF;            // 4 partials x 1MF
    float* yprojp  = big + 8*MF;            // 4 partials x 1MF (after hend dead)
    bf16*  ybf     = (bf16*)ff1;            // 4M els
    bf16*  ff1B    = (bf16*)ff1;
    bf16*  mbufB   = (bf16*)mbuf;

    k_cvt<<<4096,256,0,stream>>>(tf, tb, (const unsigned int*)d_in[0], inF, inB, flag, (int)of, (int)ob);

    // ---- self attention ----
    k_gemm_bigA<<<dim3(24,16),256,0,stream>>>(tgt_f,0,512, PW(2),512, qkvB,1,1536, PF(3),0,512);
    k_flash2<<<dim3(16,16,8),256,0,stream>>>(qkvB,1536,0, qkvB,1536,512, qkvB,1536,1024, OpartB, Ml, 0.125f);
    k_fcomb<<<4096,256,0,stream>>>(OpartB, Ml, attnoB, Mfin);
    k_gemm_skp<<<dim3(8,32,2),256,0,stream>>>(attnoB,1,0,512, PW(4),512, tpart,MF,512, PF(5), 512, 2);
    k_add_rmsnorm<<<2048,256,0,stream>>>(tgt_f, tpart, MF, 2, PF(10));

    // ---- cross attention ----
    k_mfma_gemm<<<dim3(8,32,1),256,0,stream>>>(tgt_f,0,0,0,512, PW(6),0,0,512,2, qB,1,0,0,512, PF(7),1.f,0,512,1);
    k_mfma_gemm<<<dim3(16,32,1),256,0,stream>>>(mem_f,0,0,0,512, PW(6)+(size_t)512*512,0,0,512,2, kvB,1,0,0,1024, PF(7)+512,1.f,0,512,1);
    k_flash2<<<dim3(16,16,8),256,0,stream>>>(qB,512,0, kvB,1024,0, kvB,1024,512, OpartB, Ml, 0.125f);
    k_fcomb<<<4096,256,0,stream>>>(OpartB, Ml, attnoB, Mfin);
    k_pmean<<<dim3(16,16,2),256,0,stream>>>(qB,512, kvB,1024, Mfin, d_out, flag, 0.125f);
    k_gemm_skp<<<dim3(8,32,2),256,0,stream>>>(attnoB,1,0,512, PW(8),512, tpart,MF,512, PF(9), 512, 2);
    k_rms_ln<<<2048,256,0,stream>>>(tgt_f, tpart, MF, PF(11), PF(18), PF(19), xnB);

    // ---- bimamba ----
    k_gemm_bigA<<<dim3(32,16),256,0,stream>>>(xnB,1,512, PW(26),512, xz,0,2048, PF(27),0,512);
    k_conv_silu<<<dim3(8192,2),256,0,stream>>>(xz, PF(28), PF(29), xmc_f, dbc_f);
    k_gemm_sk<<<dim3(1,32,8),256,0,stream>>>(xmc_f,1,2*MF,1024, PW(30),1024, dbc_f,131072,64, nullptr, 1024, 4);
    k_mfma_gemm<<<dim3(16,32,2),256,0,stream>>>(dbc_f,0,131072,0,64, PW(31),0,0,32,2, delta_f,1,2*MF,0,1024, PF(32),1.f,3,32,1);
    k_scan1<<<dim3(16,64),256,0,stream>>>(delta_f,delta_b,xmc_f,xmc_b,dbc_f,dbc_b, PF(33), hend, Sdl);
    k_scan_carry<<<256,256,0,stream>>>(PF(33), hend, Sdl);
    k_scan2<<<dim3(16,64),256,0,stream>>>(delta_f,delta_b,xmc_f,xmc_b,dbc_f,dbc_b, PF(33), hend, xz, PF(34), ybf);
    k_gemm_skp<<<dim3(8,32,4),256,0,stream>>>(ybf,1,2*MF,1024, PW(35),1024, yprojp,MF,512, PF(36), 1024, 2);
    k_combine_ln<<<2048,256,0,stream>>>(yprojp, MF, PF(20), PF(21), mbufB);
    k_gemm_bigA<<<dim3(32,16),256,0,stream>>>(mbufB,1,512, PW(22),512, ff1B,1,2048, PF(23),2,512);
    k_gemm_skp<<<dim3(8,32,4),256,0,stream>>>(ff1B,1,0,2048, PW(24),2048, ffop,MF,512, PF(25), 2048, 4);
    k_bimamba_final<<<2048,256,0,stream>>>(tgt_f, ffop, MF, PF(12));

    // ---- final FFN ----
    k_gemm_bigA<<<dim3(32,16),256,0,stream>>>(tgt_f,0,512, PW(14),512, ff1B,1,2048, PF(15),1,512);
    k_gemm_skp<<<dim3(8,32,4),256,0,stream>>>(ff1B,1,0,2048, PW(16),2048, lin2p,MF,512, PF(17), 2048, 4);
    k_add_rmsnorm_out<<<2048,256,0,stream>>>(tgt_f, lin2p, MF, 4, PF(13), d_out, flag);
    #undef PF
    #undef PW
  }
}

// Round 11
// 555.231 us; speedup vs baseline: 1.0482x; 1.0482x over previous
//
#include <hip/hip_runtime.h>
#include <hip/hip_bf16.h>
#include <math.h>

#define L_SEQ 1024
#define BB 2
#define DD 512
#define HH 8
#define DFFN 2048
#define NSTATE 16
#define DI 1024
#define EPSF 1e-5f

typedef __hip_bfloat16 bf16;
typedef __attribute__((ext_vector_type(8))) short short8v;
typedef __attribute__((ext_vector_type(4))) short short4v;
typedef __attribute__((ext_vector_type(4))) float float4v;

__device__ __forceinline__ float bf2f(bf16 v){ return __bfloat162float(v); }
__device__ __forceinline__ bf16 f2bf(float v){ return __float2bfloat16(v); }
__device__ __forceinline__ short f2bfs(float v){
  bf16 t = __float2bfloat16(v);
  short s; __builtin_memcpy(&s, &t, 2);
  return s;
}
__device__ __forceinline__ float s2f(short s){
  union{unsigned int i; float f;} c; c.i = ((unsigned int)(unsigned short)s) << 16; return c.f;
}

// dA[n] = q^(n+1) via binary powers
__device__ __forceinline__ void powtab(float q1, float* dA){
  float q2=q1*q1, q4=q2*q2, q8=q4*q4;
  dA[0]=q1;       dA[1]=q2;       dA[2]=q2*q1;     dA[3]=q4;
  dA[4]=q4*q1;    dA[5]=q4*q2;    dA[6]=q4*q2*q1;  dA[7]=q8;
  dA[8]=q8*q1;    dA[9]=q8*q2;    dA[10]=q8*q2*q1; dA[11]=q8*q4;
  dA[12]=q8*q4*q1;dA[13]=q8*q4*q2;dA[14]=q8*q4*q2*q1;dA[15]=q8*q8;
}

// ---------------- fused convert + dtype detect (4-wide vectorized) ----------------
struct CvtTabF { const void* src[25]; unsigned int off[26]; };
struct CvtTabW { const void* src[12]; unsigned int off[13]; };

__global__ __launch_bounds__(256) void k_cvt(CvtTabF tf, CvtTabW tb,
                                             const unsigned int* __restrict__ w0,
                                             float* __restrict__ dstF, bf16* __restrict__ dstB,
                                             int* __restrict__ flag, int totF4, int totB4){
  __shared__ int cnt;
  if (threadIdx.x==0) cnt = 0;
  __syncthreads();
  {
    unsigned int x = w0[threadIdx.x];
    unsigned int low = x & 0xffffu;
    int e = (int)((low >> 7) & 0xffu);
    int vote = (low==0u) || (e >= 110 && e <= 140);
    atomicAdd(&cnt, vote);
  }
  __syncthreads();
  const int isbf = (cnt >= 128) ? 1 : 0;      // 1 = bf16 inputs, 0 = fp32
  if (blockIdx.x==0 && threadIdx.x==0) flag[0] = isbf;
  const int tot4 = totF4 + totB4;
  for (int g4 = blockIdx.x*256 + threadIdx.x; g4 < tot4; g4 += gridDim.x*256){
    if (g4 < totF4){
      int g = g4 << 2;
      int k = 0;
      while (tf.off[k+1] <= (unsigned int)g) ++k;
      int e = g - (int)tf.off[k];
      float4 o;
      if (isbf){
        short4v s = *(const short4v*)((const bf16*)tf.src[k] + e);
        o.x=s2f(s.x); o.y=s2f(s.y); o.z=s2f(s.z); o.w=s2f(s.w);
      } else {
        o = *(const float4*)((const float*)tf.src[k] + e);
      }
      *(float4*)(dstF + g) = o;
    } else {
      int g = (g4 - totF4) << 2;
      int k = 0;
      while (tb.off[k+1] <= (unsigned int)g) ++k;
      int e = g - (int)tb.off[k];
      short4v s;
      if (isbf){
        s = *(const short4v*)((const bf16*)tb.src[k] + e);
      } else {
        float4 v = *(const float4*)((const float*)tb.src[k] + e);
        s.x=f2bfs(v.x); s.y=f2bfs(v.y); s.z=f2bfs(v.z); s.w=f2bfs(v.w);
      }
      *(short4v*)((short*)dstB + g) = s;
    }
  }
}

// ---------------- 64-tile batched MFMA GEMM ----------------
__global__ __launch_bounds__(256) void k_mfma_gemm(
    const void* __restrict__ Ab, int cA, long long sAb, long long sAh, long long sAm,
    const void* __restrict__ Bb, long long sBb, long long sBh, long long sBrow, int cB,
    void* __restrict__ Cb, int outBf, long long sCb, long long sCh, long long sCm,
    const float* __restrict__ bias, float scale, int act, int K, int H)
{
  __shared__ short As[64*40];
  __shared__ short Bs[64*40];
  const int tid = threadIdx.x;
  int bx = blockIdx.x, by = blockIdx.y;
  if (gridDim.z == 1 && (gridDim.y & 7) == 0){
    int gx = gridDim.x;
    int lin = by*gx + bx;
    int xcd = lin & 7, i = lin >> 3;
    by = xcd*(gridDim.y >> 3) + i / gx;
    bx = i % gx;
  }
  const int z = blockIdx.z; const int zb = z / H; const int zh = z % H;
  const int col0 = bx << 6, m0 = by << 6;
  const float* Af = (const float*)Ab;
  const bf16*  Aw = (const bf16*)Ab;
  const long long aoff = zb*sAb + zh*sAh;
  const float* Bf = (const float*)Bb;
  const bf16* Bw = (const bf16*)Bb;
  const long long boff = zb*sBb + zh*sBh;
  float4v acc[4];
  #pragma unroll
  for (int i=0;i<4;++i) acc[i] = (float4v)(0.f);
  const int lane = tid & 63, w = tid >> 6;
  const int lr = lane & 15, quad = lane >> 4;

  for (int k0 = 0; k0 < K; k0 += 32){
    if (cA == 1){
      int row = tid >> 2, k8 = (tid & 3) << 3;
      short8v v = *(const short8v*)&Aw[aoff + (long long)(m0+row)*sAm + k0 + k8];
      *(short8v*)&As[row*40 + k8] = v;
    } else {
      #pragma unroll
      for (int i=0;i<2;++i){
        int g = tid + i*256;
        int row = g >> 3, k4 = (g & 7) << 2;
        float4 v = *(const float4*)&Af[aoff + (long long)(m0+row)*sAm + k0 + k4];
        short4v s4; s4.x=f2bfs(v.x); s4.y=f2bfs(v.y); s4.z=f2bfs(v.z); s4.w=f2bfs(v.w);
        *(short4v*)&As[row*40 + k4] = s4;
      }
    }
    if (cB == 2){
      int row = tid >> 2, k8 = (tid & 3) << 3;
      short8v v = *(const short8v*)&Bw[boff + (long long)(col0+row)*sBrow + k0 + k8];
      *(short8v*)&Bs[row*40 + k8] = v;
    } else {
      #pragma unroll
      for (int i=0;i<2;++i){
        int g = tid + i*256;
        int row = g >> 3, k4 = (g & 7) << 2;
        float4 v = *(const float4*)&Bf[boff + (long long)(col0+row)*sBrow + k0 + k4];
        short4v s4; s4.x=f2bfs(v.x); s4.y=f2bfs(v.y); s4.z=f2bfs(v.z); s4.w=f2bfs(v.w);
        *(short4v*)&Bs[row*40 + k4] = s4;
      }
    }
    __syncthreads();
    short8v a = *(short8v*)&As[(w*16 + lr)*40 + quad*8];
    #pragma unroll
    for (int cb=0; cb<4; ++cb){
      short8v bfr = *(short8v*)&Bs[(cb*16 + lr)*40 + quad*8];
      acc[cb] = __builtin_amdgcn_mfma_f32_16x16x32_bf16(a, bfr, acc[cb], 0, 0, 0);
    }
    __syncthreads();
  }
  #pragma unroll
  for (int cb=0; cb<4; ++cb){
    #pragma unroll
    for (int r=0;r<4;++r){
      int m = m0 + w*16 + quad*4 + r;
      int n = col0 + cb*16 + lr;
      float v = acc[cb][r] * scale;
      if (bias) v += bias[n];
      if (act==1) v = fmaxf(v,0.f);
      else if (act==2) v = 0.5f*v*(1.f + erff(v*0.70710678118654752f));
      else if (act==3) v = fmaxf(v,0.f) + log1pf(__expf(-fabsf(v)));
      if (outBf) ((bf16*)Cb)[zb*sCb + zh*sCh + (long long)m*sCm + n] = f2bf(v);
      else       ((float*)Cb)[zb*sCb + zh*sCh + (long long)m*sCm + n] = v;
    }
  }
}

// ---------------- split-K 64-tile GEMM -> separate partial buffers ----------------
__global__ __launch_bounds__(256) void k_gemm_skp(
    const void* __restrict__ Ab, int cA, long long sAz, long long sAm,
    const bf16* __restrict__ Bw, long long sBrow,
    float* __restrict__ Cp, long long sCp, long long sCm,
    const float* __restrict__ bias, int K, int KS)
{
  __shared__ short As[64*40];
  __shared__ short Bs[64*40];
  const int tid = threadIdx.x;
  int bx, by, bz;
  {
    int gx = gridDim.x, gy = gridDim.y, gz = gridDim.z;
    int lin = ((int)blockIdx.z*gy + blockIdx.y)*gx + blockIdx.x;
    int xcd = lin & 7, i = lin >> 3;
    bx = i % gx; int rest = i / gx;
    int pair = xcd * ((gy*gz) >> 3) + rest;
    by = pair % gy; bz = pair / gy;
  }
  const int zb = bz / KS, kc = bz % KS;
  const int Kc = K / KS;
  const int col0 = bx << 6, m0 = by << 6;
  const float* Af = (const float*)Ab;
  const bf16*  Aw = (const bf16*)Ab;
  const long long aoff = (long long)zb*sAz;
  float4v acc[4];
  #pragma unroll
  for (int i=0;i<4;++i) acc[i] = (float4v)(0.f);
  const int lane = tid & 63, w = tid >> 6;
  const int lr = lane & 15, quad = lane >> 4;

  const int kbeg = kc*Kc;
  for (int k0 = kbeg; k0 < kbeg + Kc; k0 += 32){
    if (cA == 1){
      int row = tid >> 2, k8 = (tid & 3) << 3;
      *(short8v*)&As[row*40 + k8] =
        *(const short8v*)&Aw[aoff + (long long)(m0+row)*sAm + k0 + k8];
    } else {
      #pragma unroll
      for (int i=0;i<2;++i){
        int g = tid + i*256;
        int row = g >> 3, k4 = (g & 7) << 2;
        float4 v = *(const float4*)&Af[aoff + (long long)(m0+row)*sAm + k0 + k4];
        short4v s4; s4.x=f2bfs(v.x); s4.y=f2bfs(v.y); s4.z=f2bfs(v.z); s4.w=f2bfs(v.w);
        *(short4v*)&As[row*40 + k4] = s4;
      }
    }
    {
      int row = tid >> 2, k8 = (tid & 3) << 3;
      *(short8v*)&Bs[row*40 + k8] =
        *(const short8v*)&Bw[(long long)(col0+row)*sBrow + k0 + k8];
    }
    __syncthreads();
    short8v a = *(short8v*)&As[(w*16 + lr)*40 + quad*8];
    #pragma unroll
    for (int cb=0; cb<4; ++cb){
      short8v bfr = *(short8v*)&Bs[(cb*16 + lr)*40 + quad*8];
      acc[cb] = __builtin_amdgcn_mfma_f32_16x16x32_bf16(a, bfr, acc[cb], 0, 0, 0);
    }
    __syncthreads();
  }
  #pragma unroll
  for (int cb=0; cb<4; ++cb){
    #pragma unroll
    for (int r=0;r<4;++r){
      int m = m0 + w*16 + quad*4 + r;
      int n = col0 + cb*16 + lr;
      float v = acc[cb][r];
      if (kc == 0 && bias) v += bias[n];
      Cp[(long long)bz*sCp + (long long)m*sCm + n] = v;
    }
  }
}

// ---------------- split-K atomic GEMM (xproj only; dbc pre-zeroed by conv) ----------------
__global__ __launch_bounds__(256) void k_gemm_sk(
    const void* __restrict__ Ab, int cA, long long sAz, long long sAm,
    const bf16* __restrict__ Bw, long long sBrow,
    float* __restrict__ Cb, long long sCz, long long sCm,
    const float* __restrict__ bias, int K, int KS)
{
  __shared__ short As[64*40];
  __shared__ short Bs[64*40];
  const int tid = threadIdx.x;
  int bx, by, bz;
  {
    int gx = gridDim.x, gy = gridDim.y, gz = gridDim.z;
    int lin = ((int)blockIdx.z*gy + blockIdx.y)*gx + blockIdx.x;
    int xcd = lin & 7, i = lin >> 3;
    bx = i % gx; int rest = i / gx;
    int pair = xcd * ((gy*gz) >> 3) + rest;
    by = pair % gy; bz = pair / gy;
  }
  const int zb = bz / KS, kc = bz % KS;
  const int Kc = K / KS;
  const int col0 = bx << 6, m0 = by << 6;
  const bf16*  Aw = (const bf16*)Ab;
  const float* Af = (const float*)Ab;
  const long long aoff = (long long)zb*sAz;
  float4v acc[4];
  #pragma unroll
  for (int i=0;i<4;++i) acc[i] = (float4v)(0.f);
  const int lane = tid & 63, w = tid >> 6;
  const int lr = lane & 15, quad = lane >> 4;

  const int kbeg = kc*Kc;
  for (int k0 = kbeg; k0 < kbeg + Kc; k0 += 32){
    if (cA == 1){
      int row = tid >> 2, k8 = (tid & 3) << 3;
      *(short8v*)&As[row*40 + k8] =
        *(const short8v*)&Aw[aoff + (long long)(m0+row)*sAm + k0 + k8];
    } else {
      #pragma unroll
      for (int i=0;i<2;++i){
        int g = tid + i*256;
        int row = g >> 3, k4 = (g & 7) << 2;
        float4 v = *(const float4*)&Af[aoff + (long long)(m0+row)*sAm + k0 + k4];
        short4v s4; s4.x=f2bfs(v.x); s4.y=f2bfs(v.y); s4.z=f2bfs(v.z); s4.w=f2bfs(v.w);
        *(short4v*)&As[row*40 + k4] = s4;
      }
    }
    {
      int row = tid >> 2, k8 = (tid & 3) << 3;
      *(short8v*)&Bs[row*40 + k8] =
        *(const short8v*)&Bw[(long long)(col0+row)*sBrow + k0 + k8];
    }
    __syncthreads();
    short8v a = *(short8v*)&As[(w*16 + lr)*40 + quad*8];
    #pragma unroll
    for (int cb=0; cb<4; ++cb){
      short8v bfr = *(short8v*)&Bs[(cb*16 + lr)*40 + quad*8];
      acc[cb] = __builtin_amdgcn_mfma_f32_16x16x32_bf16(a, bfr, acc[cb], 0, 0, 0);
    }
    __syncthreads();
  }
  #pragma unroll
  for (int cb=0; cb<4; ++cb){
    #pragma unroll
    for (int r=0;r<4;++r){
      int m = m0 + w*16 + quad*4 + r;
      int n = col0 + cb*16 + lr;
      float v = acc[cb][r];
      if (kc == 0 && bias) v += bias[n];
      atomicAdd(&Cb[(long long)zb*sCz + (long long)m*sCm + n], v);
    }
  }
}

// ---------------- flash attention, split-K partials (8 chunks of 128 kpos), bf16 Opart ----------------
__global__ __launch_bounds__(256) void k_flash2(
    const bf16* __restrict__ Qb, int ldq, int qoff,
    const bf16* __restrict__ Kb, int ldk, int koff,
    const bf16* __restrict__ Vb, int ldv, int voff,
    bf16* __restrict__ Opart, float* __restrict__ Ml, float scale)
{
  __shared__ short Qs[64*40];
  __shared__ short Ks[64*40];
  __shared__ short Vs[64*40];
  __shared__ short Ps[64*40];
  const int tid = threadIdx.x;
  const int q0 = blockIdx.x << 6;
  const int z = blockIdx.y; const int b = z >> 3; const int hoff = (z & 7) << 6;
  const int kc = blockIdx.z;
  const int lane = tid & 63, w = tid >> 6;
  const int lr = lane & 15, quad = lane >> 4;

  #pragma unroll
  for (int i=0;i<2;++i){
    int idx = tid + i*256;
    int row = idx >> 3, d8 = (idx & 7) << 3;
    *(short8v*)&Qs[row*40 + d8] =
      *(const short8v*)&Qb[(size_t)((q0+row)*BB + b)*ldq + qoff + hoff + d8];
  }

  float m_r[4], l_r[4];
  #pragma unroll
  for (int r=0;r<4;++r){ m_r[r] = -1e30f; l_r[r] = 0.f; }
  float4v acc_o[4];
  #pragma unroll
  for (int cb=0;cb<4;++cb) acc_o[cb] = (float4v)(0.f);

  short8v kr[2], vr[2];
  #pragma unroll
  for (int i=0;i<2;++i){
    int idx = tid + i*256;
    int row = kc*128 + (idx >> 3); int d8 = (idx & 7) << 3;
    kr[i] = *(const short8v*)&Kb[(size_t)(row*BB + b)*ldk + koff + hoff + d8];
    vr[i] = *(const short8v*)&Vb[(size_t)(row*BB + b)*ldv + voff + hoff + d8];
  }

  for (int kt=0; kt<2; ++kt){
    __syncthreads();
    #pragma unroll
    for (int i=0;i<2;++i){
      int idx = tid + i*256;
      int row = idx >> 3, d8 = (idx & 7) << 3;
      *(short8v*)&Ks[row*40 + d8] = kr[i];
      int sc = row ^ d8;
      #pragma unroll
      for (int j=0;j<8;++j) Vs[(d8+j)*40 + sc] = vr[i][j];
    }
    if (kt < 1){
      #pragma unroll
      for (int i=0;i<2;++i){
        int idx = tid + i*256;
        int row = kc*128 + 64 + (idx >> 3); int d8 = (idx & 7) << 3;
        kr[i] = *(const short8v*)&Kb[(size_t)(row*BB + b)*ldk + koff + hoff + d8];
        vr[i] = *(const short8v*)&Vb[(size_t)(row*BB + b)*ldv + voff + hoff + d8];
      }
    }
    __syncthreads();
    short8v a0 = *(short8v*)&Qs[(w*16+lr)*40 + quad*8];
    short8v a1 = *(short8v*)&Qs[(w*16+lr)*40 + quad*8 + 32];
    float4v s[4];
    #pragma unroll
    for (int cb=0;cb<4;++cb){
      short8v b0 = *(short8v*)&Ks[(cb*16+lr)*40 + quad*8];
      short8v b1 = *(short8v*)&Ks[(cb*16+lr)*40 + quad*8 + 32];
      float4v t = __builtin_amdgcn_mfma_f32_16x16x32_bf16(a0, b0, (float4v)(0.f), 0,0,0);
      s[cb] = __builtin_amdgcn_mfma_f32_16x16x32_bf16(a1, b1, t, 0,0,0);
    }
    #pragma unroll
    for (int cb=0;cb<4;++cb)
      #pragma unroll
      for (int r=0;r<4;++r) s[cb][r] *= scale;
    float al[4];
    #pragma unroll
    for (int r=0;r<4;++r){
      float mx = fmaxf(fmaxf(s[0][r],s[1][r]),fmaxf(s[2][r],s[3][r]));
      #pragma unroll
      for (int ofs=1; ofs<16; ofs<<=1) mx = fmaxf(mx, __shfl_xor(mx, ofs));
      float mnew = fmaxf(m_r[r], mx);
      al[r] = __expf(m_r[r] - mnew);
      float sum = 0.f;
      #pragma unroll
      for (int cb=0;cb<4;++cb){
        float p = __expf(s[cb][r] - mnew);
        s[cb][r] = p;
        sum += p;
      }
      #pragma unroll
      for (int ofs=1; ofs<16; ofs<<=1) sum += __shfl_xor(sum, ofs);
      l_r[r] = l_r[r]*al[r] + sum;
      m_r[r] = mnew;
    }
    #pragma unroll
    for (int cb=0;cb<4;++cb)
      #pragma unroll
      for (int r=0;r<4;++r){
        acc_o[cb][r] *= al[r];
        Ps[(w*16 + quad*4 + r)*40 + cb*16 + lr] = f2bfs(s[cb][r]);
      }
    __syncthreads();
    short8v p0 = *(short8v*)&Ps[(w*16+lr)*40 + quad*8];
    short8v p1 = *(short8v*)&Ps[(w*16+lr)*40 + quad*8 + 32];
    #pragma unroll
    for (int cb=0;cb<4;++cb){
      int dcol = cb*16 + lr;
      int sw = (dcol >> 3) & 7;
      short8v v0 = *(short8v*)&Vs[dcol*40 + ((quad ^ sw) << 3)];
      short8v v1 = *(short8v*)&Vs[dcol*40 + (((quad+4) ^ sw) << 3)];
      acc_o[cb] = __builtin_amdgcn_mfma_f32_16x16x32_bf16(p0, v0, acc_o[cb], 0,0,0);
      acc_o[cb] = __builtin_amdgcn_mfma_f32_16x16x32_bf16(p1, v1, acc_o[cb], 0,0,0);
    }
  }
  #pragma unroll
  for (int r=0;r<4;++r){
    int row = q0 + w*16 + quad*4 + r;
    size_t obase = ((size_t)(kc*16 + z)*1024 + row)*64;
    #pragma unroll
    for (int cb=0;cb<4;++cb)
      Opart[obase + cb*16 + lr] = f2bf(acc_o[cb][r]);
    if (lr == 0){
      size_t mi = ((size_t)kc*16384 + z*1024 + row)*2;
      Ml[mi] = m_r[r]; Ml[mi+1] = l_r[r];
    }
  }
}

// ---------------- combine 8 split-K partials (bf16 Opart) ----------------
__global__ __launch_bounds__(256) void k_fcomb(const bf16* __restrict__ Opart, const float* __restrict__ Ml,
                                               bf16* __restrict__ O, float* __restrict__ Mfin)
{
  int gid = blockIdx.x*256 + threadIdx.x;   // 1M
  int row = gid >> 6, d = gid & 63;
  int z = row >> 10, q = row & 1023;
  float m[8], l[8];
  #pragma unroll
  for (int kc=0;kc<8;++kc){
    size_t mi = ((size_t)kc*16384 + row)*2;
    m[kc] = Ml[mi]; l[kc] = Ml[mi+1];
  }
  float ms = -1e30f;
  #pragma unroll
  for (int kc=0;kc<8;++kc) ms = fmaxf(ms, m[kc]);
  float ls = 0.f, o = 0.f;
  #pragma unroll
  for (int kc=0;kc<8;++kc){
    float c = __expf(m[kc]-ms);
    ls += l[kc]*c;
    o  += bf2f(Opart[((size_t)kc*16384 + row)*64 + d]) * c;
  }
  o /= ls;
  int b = z >> 3, hoff = (z & 7) << 6;
  O[((size_t)q*BB + b)*512 + hoff + d] = f2bf(o);
  if (d == 0){ Mfin[(size_t)row*2] = ms; Mfin[(size_t)row*2+1] = ls; }
}

// ---------------- head-mean of P from Q,K + final m,l ----------------
__global__ __launch_bounds__(256) void k_pmean(
    const bf16* __restrict__ Qb, int ldq,
    const bf16* __restrict__ Kb, int ldk,
    const float* __restrict__ Mfin, void* __restrict__ out,
    const int* __restrict__ flag, float scale)
{
  __shared__ short Qs[64*40];
  __shared__ short Ks[64*40];
  const int tid = threadIdx.x;
  const int k0 = blockIdx.x << 6, q0 = blockIdx.y << 6;
  const int b = blockIdx.z;
  const int lane = tid & 63, w = tid >> 6;
  const int lr = lane & 15, quad = lane >> 4;
  float acc[4][4];
  #pragma unroll
  for (int cb=0;cb<4;++cb)
    #pragma unroll
    for (int r=0;r<4;++r) acc[cb][r] = 0.f;

  for (int h=0; h<8; ++h){
    int z = b*8 + h, hoff = h << 6;
    __syncthreads();
    #pragma unroll
    for (int i=0;i<2;++i){
      int idx = tid + i*256;
      int row = idx >> 3, d8 = (idx & 7) << 3;
      *(short8v*)&Qs[row*40 + d8] = *(const short8v*)&Qb[((size_t)(q0+row)*BB + b)*ldq + hoff + d8];
      *(short8v*)&Ks[row*40 + d8] = *(const short8v*)&Kb[((size_t)(k0+row)*BB + b)*ldk + hoff + d8];
    }
    __syncthreads();
    float mm[4], li[4];
    #pragma unroll
    for (int r=0;r<4;++r){
      int qrow = q0 + w*16 + quad*4 + r;
      size_t mi = ((size_t)z*1024 + qrow)*2;
      mm[r] = Mfin[mi]; li[r] = 1.f/Mfin[mi+1];
    }
    short8v a0 = *(short8v*)&Qs[(w*16+lr)*40 + quad*8];
    short8v a1 = *(short8v*)&Qs[(w*16+lr)*40 + quad*8 + 32];
    #pragma unroll
    for (int cb=0;cb<4;++cb){
      short8v b0 = *(short8v*)&Ks[(cb*16+lr)*40 + quad*8];
      short8v b1 = *(short8v*)&Ks[(cb*16+lr)*40 + quad*8 + 32];
      float4v t = __builtin_amdgcn_mfma_f32_16x16x32_bf16(a0, b0, (float4v)(0.f), 0,0,0);
      t = __builtin_amdgcn_mfma_f32_16x16x32_bf16(a1, b1, t, 0,0,0);
      #pragma unroll
      for (int r=0;r<4;++r)
        acc[cb][r] += __expf(t[r]*scale - mm[r]) * li[r];
    }
  }
  #pragma unroll
  for (int cb=0;cb<4;++cb)
    #pragma unroll
    for (int r=0;r<4;++r){
      int q = q0 + w*16 + quad*4 + r;
      int k = k0 + cb*16 + lr;
      float v = acc[cb][r] * 0.125f;
      size_t o = (size_t)(1u<<20) + ((size_t)b<<20) + (size_t)q*1024 + k;
      if (flag[0]) ((bf16*)out)[o] = f2bf(v);
      else         ((float*)out)[o] = v;
    }
}

// ---------------- norms (consume split-K partials) ----------------
__global__ __launch_bounds__(256) void k_add_rmsnorm(float* __restrict__ x, const float* __restrict__ tp,
                                                     long long pstr, int KS, const float* __restrict__ w){
  int row = blockIdx.x; size_t base = (size_t)row*DD;
  int tid = threadIdx.x;
  float v0 = x[base+tid], v1 = x[base+tid+256];
  for (int k=0;k<KS;++k){ v0 += tp[k*pstr + base+tid]; v1 += tp[k*pstr + base+tid+256]; }
  __shared__ float red[256];
  red[tid] = v0*v0 + v1*v1; __syncthreads();
  for (int s=128;s>0;s>>=1){ if(tid<s) red[tid]+=red[tid+s]; __syncthreads(); }
  float rms = rsqrtf(red[0]*(1.f/DD) + EPSF);
  x[base+tid]     = v0 * w[tid]     * rms;
  x[base+tid+256] = v1 * w[tid+256] * rms;
}

__global__ __launch_bounds__(256) void k_add_rmsnorm_out(const float* __restrict__ x, const float* __restrict__ tp,
                                                         long long pstr, int KS,
                                                         const float* __restrict__ w, void* __restrict__ out,
                                                         const int* __restrict__ flag){
  int row = blockIdx.x; size_t base = (size_t)row*DD;
  int tid = threadIdx.x;
  float v0 = x[base+tid], v1 = x[base+tid+256];
  for (int k=0;k<KS;++k){ v0 += tp[k*pstr + base+tid]; v1 += tp[k*pstr + base+tid+256]; }
  __shared__ float red[256];
  red[tid] = v0*v0 + v1*v1; __syncthreads();
  for (int s=128;s>0;s>>=1){ if(tid<s) red[tid]+=red[tid+s]; __syncthreads(); }
  float rms = rsqrtf(red[0]*(1.f/DD) + EPSF);
  float o0 = v0 * w[tid]     * rms;
  float o1 = v1 * w[tid+256] * rms;
  if (flag[0]){ ((bf16*)out)[base+tid] = f2bf(o0); ((bf16*)out)[base+tid+256] = f2bf(o1); }
  else        { ((float*)out)[base+tid] = o0;      ((float*)out)[base+tid+256] = o1; }
}

// fused: tgt = rmsnorm(tgt + sum tp, n2w); xn = layernorm(tgt, ln1) (bf16)
__global__ __launch_bounds__(256) void k_rms_ln(float* __restrict__ tgt, const float* __restrict__ tp,
                                                long long pstr, const float* __restrict__ n2w,
                                                const float* __restrict__ lw, const float* __restrict__ lb,
                                                bf16* __restrict__ xn){
  int r = blockIdx.x;
  int b = r >> 10, l = r & 1023;
  size_t base = ((size_t)l*BB + b)*DD;
  int tid = threadIdx.x;
  float v0 = tgt[base+tid] + tp[base+tid] + tp[pstr + base+tid];
  float v1 = tgt[base+tid+256] + tp[base+tid+256] + tp[pstr + base+tid+256];
  __shared__ float red[256];
  red[tid] = v0*v0 + v1*v1; __syncthreads();
  for (int s=128;s>0;s>>=1){ if(tid<s) red[tid]+=red[tid+s]; __syncthreads(); }
  float rms = rsqrtf(red[0]*(1.f/DD) + EPSF);
  v0 = v0 * n2w[tid]     * rms;
  v1 = v1 * n2w[tid+256] * rms;
  tgt[base+tid] = v0; tgt[base+tid+256] = v1;
  __syncthreads();
  red[tid] = v0 + v1; __syncthreads();
  for (int s=128;s>0;s>>=1){ if(tid<s) red[tid]+=red[tid+s]; __syncthreads(); }
  float mean = red[0]*(1.f/DD);
  __syncthreads();
  red[tid] = v0*v0 + v1*v1; __syncthreads();
  for (int s=128;s>0;s>>=1){ if(tid<s) red[tid]+=red[tid+s]; __syncthreads(); }
  float var = red[0]*(1.f/DD) - mean*mean;
  float rstd = rsqrtf(var + EPSF);
  size_t dst = (size_t)r*DD;
  xn[dst+tid]     = f2bf((v0-mean)*rstd*lw[tid]     + lb[tid]);
  xn[dst+tid+256] = f2bf((v1-mean)*rstd*lw[tid+256] + lb[tid+256]);
}

// combine_ln over yproj partials
__global__ __launch_bounds__(256) void k_combine_ln(const float* __restrict__ yp, long long pstr,
                                                    const float* __restrict__ w, const float* __restrict__ bias,
                                                    bf16* __restrict__ mo){
  int r = blockIdx.x; int b = r>>10, l = r&1023;
  size_t rf = (size_t)r*DD;
  size_t rb = ((size_t)(b<<10) + (1023 - l))*DD;
  int tid = threadIdx.x;
  float v0 = yp[rf+tid]     + yp[pstr + rf+tid]     + yp[2*pstr + rb+tid]     + yp[3*pstr + rb+tid];
  float v1 = yp[rf+tid+256] + yp[pstr + rf+tid+256] + yp[2*pstr + rb+tid+256] + yp[3*pstr + rb+tid+256];
  __shared__ float red[256];
  red[tid] = v0 + v1; __syncthreads();
  for (int s=128;s>0;s>>=1){ if(tid<s) red[tid]+=red[tid+s]; __syncthreads(); }
  float mean = red[0]*(1.f/DD);
  __syncthreads();
  red[tid] = v0*v0 + v1*v1; __syncthreads();
  for (int s=128;s>0;s>>=1){ if(tid<s) red[tid]+=red[tid+s]; __syncthreads(); }
  float var = red[0]*(1.f/DD) - mean*mean;
  float rstd = rsqrtf(var + EPSF);
  mo[rf+tid]     = f2bf((v0-mean)*rstd*w[tid]     + bias[tid]);
  mo[rf+tid+256] = f2bf((v1-mean)*rstd*w[tid+256] + bias[tid+256]);
}

__global__ __launch_bounds__(256) void k_bimamba_final(float* __restrict__ tgt, const float* __restrict__ fp,
                                                       long long pstr, const float* __restrict__ w){
  int r = blockIdx.x; int b = r>>10, l = r&1023;
  size_t t = ((size_t)l*BB + b)*DD;
  size_t f = (size_t)r*DD;
  int tid = threadIdx.x;
  float v0 = 2.f*tgt[t+tid], v1 = 2.f*tgt[t+tid+256];
  #pragma unroll
  for (int k=0;k<4;++k){ v0 += fp[k*pstr + f+tid]; v1 += fp[k*pstr + f+tid+256]; }
  __shared__ float red[256];
  red[tid] = v0*v0 + v1*v1; __syncthreads();
  for (int s=128;s>0;s>>=1){ if(tid<s) red[tid]+=red[tid+s]; __syncthreads(); }
  float rms = rsqrtf(red[0]*(1.f/DD) + EPSF);
  tgt[t+tid]     = v0 * w[tid]     * rms;
  tgt[t+tid+256] = v1 * w[tid+256] * rms;
}

// ---------------- causal depthwise conv + silu -> bf16 (+dbc zeroing) ----------------
__global__ __launch_bounds__(256) void k_conv_silu(const float* __restrict__ xz, const float* __restrict__ cw,
                                                   const float* __restrict__ cb, bf16* __restrict__ xmc,
                                                   float* __restrict__ dbcz){
  int rev = blockIdx.y;
  int idx = blockIdx.x*256 + threadIdx.x;  // 2M
  if (rev == 0 && blockIdx.x < 1024) dbcz[idx] = 0.f;   // zero 262144 dbc floats
  int c = idx & 1023;
  int l = (idx >> 10) & 1023;
  int b = idx >> 20;
  float acc = cb[c];
  float w4[4];
  #pragma unroll
  for (int j=0;j<4;++j) w4[j] = cw[(c<<2)+j];
  #pragma unroll
  for (int j=0;j<4;++j){
    int t = l - 3 + j;
    if (t >= 0){
      int src = rev ? (1023 - t) : t;
      acc = fmaf(w4[j], xz[((size_t)(b<<10) + src)*2048 + c], acc);
    }
  }
  xmc[(size_t)rev*(2u<<20) + idx] = f2bf(acc / (1.f + __expf(-acc)));
}

// ---------------- chunked selective scan: 64 chunks of 16 steps ----------------
__global__ __launch_bounds__(256) void k_scan1(
    const bf16* __restrict__ delta_f, const bf16* __restrict__ delta_b,
    const bf16* __restrict__ xmc_f,  const bf16* __restrict__ xmc_b,
    const float* __restrict__ dbc_f,  const float* __restrict__ dbc_b,
    const float* __restrict__ Alog,
    float* __restrict__ hend, float* __restrict__ Sdl)
{
  int ch = blockIdx.x*256 + threadIdx.x;
  int c = blockIdx.y;
  int dir = ch >> 11, b = (ch >> 10) & 1, d = ch & 1023;
  const bf16* delta = dir ? delta_b : delta_f;
  const bf16* xmc   = dir ? xmc_b   : xmc_f;
  const float* dbc  = dir ? dbc_b   : dbc_f;
  float Av[NSTATE]; bool fast = true;
  #pragma unroll
  for (int n=0;n<NSTATE;++n){
    Av[n] = -__expf(Alog[d*NSTATE+n]);
    fast = fast && (fabsf(Av[n] + (float)(n+1)) < 1e-4f*(float)(n+1));
  }
  float h[NSTATE];
  #pragma unroll
  for (int n=0;n<NSTATE;++n) h[n]=0.f;
  float S = 0.f;
  int r0 = b*1024 + c*16;
  for (int t=0;t<16;++t){
    int r = r0 + t;
    float dl = bf2f(delta[((size_t)r<<10) + d]);
    float x  = bf2f(xmc[((size_t)r<<10) + d]);
    const float4* bp = (const float4*)(dbc + (size_t)r*64 + 32);
    float Bv[NSTATE];
    ((float4*)Bv)[0]=bp[0]; ((float4*)Bv)[1]=bp[1]; ((float4*)Bv)[2]=bp[2]; ((float4*)Bv)[3]=bp[3];
    S += dl;
    float dx = dl*x;
    float dA[NSTATE];
    if (fast){ powtab(__expf(-dl), dA); }
    else {
      #pragma unroll
      for (int n=0;n<NSTATE;++n) dA[n] = __expf(dl*Av[n]);
    }
    #pragma unroll
    for (int n=0;n<NSTATE;++n)
      h[n] = fmaf(dA[n], h[n], dx*Bv[n]);
  }
  size_t base = ((size_t)c*4096 + ch)*16;
  #pragma unroll
  for (int n=0;n<NSTATE;++n) hend[base+n] = h[n];
  Sdl[c*4096 + ch] = S;
}

__global__ __launch_bounds__(256) void k_scan_carry(const float* __restrict__ Alog,
                                                    float* __restrict__ hh, const float* __restrict__ Sdl)
{
  int g = blockIdx.x*256 + threadIdx.x;   // 65536
  int ch = g >> 4, n = g & 15;
  int d = ch & 1023;
  float Av = -__expf(Alog[d*16+n]);
  float h = 0.f;
  for (int c=0;c<64;++c){
    size_t base = ((size_t)c*4096 + ch)*16 + n;
    float he = hh[base];
    hh[base] = h;
    h = fmaf(__expf(Av*Sdl[c*4096+ch]), h, he);
  }
}

__global__ __launch_bounds__(256) void k_scan2(
    const bf16* __restrict__ delta_f, const bf16* __restrict__ delta_b,
    const bf16* __restrict__ xmc_f,  const bf16* __restrict__ xmc_b,
    const float* __restrict__ dbc_f,  const float* __restrict__ dbc_b,
    const float* __restrict__ Alog,   const float* __restrict__ hin,
    const float* __restrict__ xz,     const float* __restrict__ Dp,
    bf16* __restrict__ yo)
{
  int ch = blockIdx.x*256 + threadIdx.x;
  int c = blockIdx.y;
  int dir = ch >> 11, b = (ch >> 10) & 1, d = ch & 1023;
  const bf16* delta = dir ? delta_b : delta_f;
  const bf16* xmc   = dir ? xmc_b   : xmc_f;
  const float* dbc  = dir ? dbc_b   : dbc_f;
  float Av[NSTATE]; bool fast = true;
  #pragma unroll
  for (int n=0;n<NSTATE;++n){
    Av[n] = -__expf(Alog[d*NSTATE+n]);
    fast = fast && (fabsf(Av[n] + (float)(n+1)) < 1e-4f*(float)(n+1));
  }
  float h[NSTATE];
  size_t cbase = ((size_t)c*4096 + ch)*16;
  #pragma unroll
  for (int n=0;n<NSTATE;++n) h[n] = hin[cbase+n];
  float Dd = Dp[d];
  int r0 = b*1024 + c*16;
  for (int t=0;t<16;++t){
    int r = r0 + t;
    int lidx = c*16 + t;
    float dl = bf2f(delta[((size_t)r<<10) + d]);
    float x  = bf2f(xmc[((size_t)r<<10) + d]);
    const float4* bp = (const float4*)(dbc + (size_t)r*64 + 32);
    float Bv[NSTATE], Cv[NSTATE];
    ((float4*)Bv)[0]=bp[0]; ((float4*)Bv)[1]=bp[1]; ((float4*)Bv)[2]=bp[2]; ((float4*)Bv)[3]=bp[3];
    ((float4*)Cv)[0]=bp[4]; ((float4*)Cv)[1]=bp[5]; ((float4*)Cv)[2]=bp[6]; ((float4*)Cv)[3]=bp[7];
    float dx = dl*x;
    float dA[NSTATE];
    if (fast){ powtab(__expf(-dl), dA); }
    else {
      #pragma unroll
      for (int n=0;n<NSTATE;++n) dA[n] = __expf(dl*Av[n]);
    }
    float acc0 = 0.f, acc1 = 0.f;
    #pragma unroll
    for (int n=0;n<NSTATE;n+=2){
      h[n]   = fmaf(dA[n],   h[n],   dx*Bv[n]);
      h[n+1] = fmaf(dA[n+1], h[n+1], dx*Bv[n+1]);
      acc0 = fmaf(h[n],   Cv[n],   acc0);
      acc1 = fmaf(h[n+1], Cv[n+1], acc1);
    }
    float acc = acc0 + acc1;
    int src = dir ? (1023 - lidx) : lidx;
    float zz = xz[((size_t)(b<<10) + src)*2048 + 1024 + d];
    float sg = zz / (1.f + __expf(-zz));
    yo[(size_t)dir*(2u<<20) + ((size_t)r<<10) + d] = f2bf((acc + Dd*x) * sg);
  }
}

extern "C" void kernel_launch(void* const* d_in, const int* in_sizes, int n_in,
                              void* d_out, int out_size, void* d_ws, size_t ws_size,
                              hipStream_t stream)
{
  if (n_in < 37) return;
  static const unsigned int SZ[37] = {
    1048576,1048576,786432,1536,262144,512,786432,1536,262144,512,
    512,512,512,512,1048576,2048,1048576,512,512,512,
    512,512,1048576,2048,1048576,512,1048576,2048,4096,1024,
    65536,32768,1024,16384,1024,524288,512
  };
  static const unsigned char ISW[37] = {
    0,0,1,0,1,0,1,0,1,0, 0,0,0,0,1,0,1,0,0,0,
    0,0,1,0,1,0,1,0,0,0, 1,1,0,0,0,1,0
  };
  const long long MF = 1u<<20;
  if (ws_size < (size_t)(32*MF)*sizeof(float)) return;   // 128 MB

  float* ws = (float*)d_ws;
  float* inF = ws;                       // fp32 params arena  [0, 3MF)
  bf16*  inB = (bf16*)(ws + 3*MF);       // bf16 weight arena  [3MF, 7MF)
  float* t2    = ws + 7*MF;
  float* mbuf  = ws + 8*MF;
  float* proj  = ws + 9*MF;              // 3MF
  float* big   = ws + 12*MF;             // 16MF
  float* ff1   = ws + 28*MF;             // 2MF (bf16 4M els; ybf/ff1B)

  CvtTabF tf; CvtTabW tb;
  unsigned int fOff[37], bOff[37];
  {
    int nf=0, nb=0; unsigned int of=0, ob=0;
    for (int i=0;i<37;++i){
      if (ISW[i]){ tb.src[nb]=d_in[i]; tb.off[nb]=ob; bOff[i]=ob; ob+=SZ[i]; ++nb; }
      else       { tf.src[nf]=d_in[i]; tf.off[nf]=of; fOff[i]=of; of+=SZ[i]; ++nf; }
    }
    tf.off[25]=of; tb.off[12]=ob;
    int* flag = (int*)(ws + 3*MF - 16);

    #define PF(i) (inF + fOff[i])
    #define PW(i) (inB + bOff[i])

    float* tgt_f = PF(0);
    float* mem_f = PF(1);
    bf16* qkvB   = (bf16*)proj;          // 3M els
    bf16* qB     = (bf16*)proj;          // 1M els (CA)
    bf16* kvB    = (bf16*)(proj + 1*MF); // 2M els (CA)
    bf16* attnoB = (bf16*)mbuf;          // 1M els
    bf16* xnB    = (bf16*)t2;            // 1M els
    // attention phase (big):
    bf16*  OpartB  = (bf16*)big;            // 8M els = 4MF
    float* Ml      = big + 4*MF;            // 256K floats
    float* Mfin    = big + 4*MF + 262144;   // 32K
    float* tpart   = big + 5*MF;            // 2 partials x 1MF
    // mamba phase (big):
    float* xz      = big;                   // 4MF
    bf16*  xmc_f   = (bf16*)(big + 4*MF);   // 2M els
    bf16*  xmc_b   = (bf16*)(big + 5*MF);
    bf16*  delta_f = (bf16*)(big + 6*MF);
    bf16*  delta_b = (bf16*)(big + 7*MF);
    float* hend    = big + 8*MF;            // 4MF
    float* Sdl     = big + 12*MF;           // 256K
    float* dbc_f   = proj;
    float* dbc_b   = proj + 131072;
    float* ffop    = big;                   // 4 partials x 1MF (after xz dead)
    float* lin2p   = big + 4*MF;            // 4 partials x 1MF
    float* yprojp  = big + 8*MF;            // 4 partials x 1MF (after hend dead)
    bf16*  ybf     = (bf16*)ff1;            // 4M els
    bf16*  ff1B    = (bf16*)ff1;
    bf16*  mbufB   = (bf16*)mbuf;

    k_cvt<<<4096,256,0,stream>>>(tf, tb, (const unsigned int*)d_in[0], inF, inB, flag,
                                 (int)(of>>2), (int)(ob>>2));

    // ---- self attention ----
    k_mfma_gemm<<<dim3(24,32,1),256,0,stream>>>(tgt_f,0,0,0,512, PW(2),0,0,512,2, qkvB,1,0,0,1536, PF(3),1.f,0,512,1);
    k_flash2<<<dim3(16,16,8),256,0,stream>>>(qkvB,1536,0, qkvB,1536,512, qkvB,1536,1024, OpartB, Ml, 0.125f);
    k_fcomb<<<4096,256,0,stream>>>(OpartB, Ml, attnoB, Mfin);
    k_gemm_skp<<<dim3(8,32,2),256,0,stream>>>(attnoB,1,0,512, PW(4),512, tpart,MF,512, PF(5), 512, 2);
    k_add_rmsnorm<<<2048,256,0,stream>>>(tgt_f, tpart, MF, 2, PF(10));

    // ---- cross attention ----
    k_mfma_gemm<<<dim3(8,32,1),256,0,stream>>>(tgt_f,0,0,0,512, PW(6),0,0,512,2, qB,1,0,0,512, PF(7),1.f,0,512,1);
    k_mfma_gemm<<<dim3(16,32,1),256,0,stream>>>(mem_f,0,0,0,512, PW(6)+(size_t)512*512,0,0,512,2, kvB,1,0,0,1024, PF(7)+512,1.f,0,512,1);
    k_flash2<<<dim3(16,16,8),256,0,stream>>>(qB,512,0, kvB,1024,0, kvB,1024,512, OpartB, Ml, 0.125f);
    k_fcomb<<<4096,256,0,stream>>>(OpartB, Ml, attnoB, Mfin);
    k_pmean<<<dim3(16,16,2),256,0,stream>>>(qB,512, kvB,1024, Mfin, d_out, flag, 0.125f);
    k_gemm_skp<<<dim3(8,32,2),256,0,stream>>>(attnoB,1,0,512, PW(8),512, tpart,MF,512, PF(9), 512, 2);
    k_rms_ln<<<2048,256,0,stream>>>(tgt_f, tpart, MF, PF(11), PF(18), PF(19), xnB);

    // ---- bimamba ----
    k_mfma_gemm<<<dim3(32,32,1),256,0,stream>>>(xnB,1,0,0,512, PW(26),0,0,512,2, xz,0,0,0,2048, PF(27),1.f,0,512,1);
    k_conv_silu<<<dim3(8192,2),256,0,stream>>>(xz, PF(28), PF(29), xmc_f, dbc_f);
    k_gemm_sk<<<dim3(1,32,8),256,0,stream>>>(xmc_f,1,2*MF,1024, PW(30),1024, dbc_f,131072,64, nullptr, 1024, 4);
    k_mfma_gemm<<<dim3(16,32,2),256,0,stream>>>(dbc_f,0,131072,0,64, PW(31),0,0,32,2, delta_f,1,2*MF,0,1024, PF(32),1.f,3,32,1);
    k_scan1<<<dim3(16,64),256,0,stream>>>(delta_f,delta_b,xmc_f,xmc_b,dbc_f,dbc_b, PF(33), hend, Sdl);
    k_scan_carry<<<256,256,0,stream>>>(PF(33), hend, Sdl);
    k_scan2<<<dim3(16,64),256,0,stream>>>(delta_f,delta_b,xmc_f,xmc_b,dbc_f,dbc_b, PF(33), hend, xz, PF(34), ybf);
    k_gemm_skp<<<dim3(8,32,4),256,0,stream>>>(ybf,1,2*MF,1024, PW(35),1024, yprojp,MF,512, PF(36), 1024, 2);
    k_combine_ln<<<2048,256,0,stream>>>(yprojp, MF, PF(20), PF(21), mbufB);
    k_mfma_gemm<<<dim3(32,32,1),256,0,stream>>>(mbufB,1,0,0,512, PW(22),0,0,512,2, ff1B,1,0,0,2048, PF(23),1.f,2,512,1);
    k_gemm_skp<<<dim3(8,32,4),256,0,stream>>>(ff1B,1,0,2048, PW(24),2048, ffop,MF,512, PF(25), 2048, 4);
    k_bimamba_final<<<2048,256,0,stream>>>(tgt_f, ffop, MF, PF(12));

    // ---- final FFN ----
    k_mfma_gemm<<<dim3(32,32,1),256,0,stream>>>(tgt_f,0,0,0,512, PW(14),0,0,512,2, ff1B,1,0,0,2048, PF(15),1.f,1,512,1);
    k_gemm_skp<<<dim3(8,32,4),256,0,stream>>>(ff1B,1,0,2048, PW(16),2048, lin2p,MF,512, PF(17), 2048, 4);
    k_add_rmsnorm_out<<<2048,256,0,stream>>>(tgt_f, lin2p, MF, 4, PF(13), d_out, flag);
    #undef PF
    #undef PW
  }
}

// Round 12
// 520.140 us; speedup vs baseline: 1.1189x; 1.0675x over previous
//
#include <hip/hip_runtime.h>
#include <hip/hip_bf16.h>
#include <math.h>

#define L_SEQ 1024
#define BB 2
#define DD 512
#define HH 8
#define DFFN 2048
#define NSTATE 16
#define DI 1024
#define EPSF 1e-5f

typedef __hip_bfloat16 bf16;
typedef __attribute__((ext_vector_type(8))) short short8v;
typedef __attribute__((ext_vector_type(4))) short short4v;
typedef __attribute__((ext_vector_type(4))) float float4v;

__device__ __forceinline__ float bf2f(bf16 v){ return __bfloat162float(v); }
__device__ __forceinline__ bf16 f2bf(float v){ return __float2bfloat16(v); }
__device__ __forceinline__ short f2bfs(float v){
  bf16 t = __float2bfloat16(v);
  short s; __builtin_memcpy(&s, &t, 2);
  return s;
}
__device__ __forceinline__ float s2f(short s){
  union{unsigned int i; float f;} c; c.i = ((unsigned int)(unsigned short)s) << 16; return c.f;
}

// dA[n] = q^(n+1) via binary powers
__device__ __forceinline__ void powtab(float q1, float* dA){
  float q2=q1*q1, q4=q2*q2, q8=q4*q4;
  dA[0]=q1;       dA[1]=q2;       dA[2]=q2*q1;     dA[3]=q4;
  dA[4]=q4*q1;    dA[5]=q4*q2;    dA[6]=q4*q2*q1;  dA[7]=q8;
  dA[8]=q8*q1;    dA[9]=q8*q2;    dA[10]=q8*q2*q1; dA[11]=q8*q4;
  dA[12]=q8*q4*q1;dA[13]=q8*q4*q2;dA[14]=q8*q4*q2*q1;dA[15]=q8*q8;
}

// ---------------- fused convert + dtype detect (4-wide vectorized) ----------------
struct CvtTabF { const void* src[25]; unsigned int off[26]; };
struct CvtTabW { const void* src[12]; unsigned int off[13]; };

__global__ __launch_bounds__(256) void k_cvt(CvtTabF tf, CvtTabW tb,
                                             const unsigned int* __restrict__ w0,
                                             float* __restrict__ dstF, bf16* __restrict__ dstB,
                                             int* __restrict__ flag, int totF4, int totB4){
  __shared__ int cnt;
  if (threadIdx.x==0) cnt = 0;
  __syncthreads();
  {
    unsigned int x = w0[threadIdx.x];
    unsigned int low = x & 0xffffu;
    int e = (int)((low >> 7) & 0xffu);
    int vote = (low==0u) || (e >= 110 && e <= 140);
    atomicAdd(&cnt, vote);
  }
  __syncthreads();
  const int isbf = (cnt >= 128) ? 1 : 0;      // 1 = bf16 inputs, 0 = fp32
  if (blockIdx.x==0 && threadIdx.x==0) flag[0] = isbf;
  const int tot4 = totF4 + totB4;
  for (int g4 = blockIdx.x*256 + threadIdx.x; g4 < tot4; g4 += gridDim.x*256){
    if (g4 < totF4){
      int g = g4 << 2;
      int k = 0;
      while (tf.off[k+1] <= (unsigned int)g) ++k;
      int e = g - (int)tf.off[k];
      float4 o;
      if (isbf){
        short4v s = *(const short4v*)((const bf16*)tf.src[k] + e);
        o.x=s2f(s.x); o.y=s2f(s.y); o.z=s2f(s.z); o.w=s2f(s.w);
      } else {
        o = *(const float4*)((const float*)tf.src[k] + e);
      }
      *(float4*)(dstF + g) = o;
    } else {
      int g = (g4 - totF4) << 2;
      int k = 0;
      while (tb.off[k+1] <= (unsigned int)g) ++k;
      int e = g - (int)tb.off[k];
      short4v s;
      if (isbf){
        s = *(const short4v*)((const bf16*)tb.src[k] + e);
      } else {
        float4 v = *(const float4*)((const float*)tb.src[k] + e);
        s.x=f2bfs(v.x); s.y=f2bfs(v.y); s.z=f2bfs(v.z); s.w=f2bfs(v.w);
      }
      *(short4v*)((short*)dstB + g) = s;
    }
  }
}

// ---------------- 64-tile batched MFMA GEMM (BK=32; used for CA proj + dt) ----------------
__global__ __launch_bounds__(256) void k_mfma_gemm(
    const void* __restrict__ Ab, int cA, long long sAb, long long sAh, long long sAm,
    const void* __restrict__ Bb, long long sBb, long long sBh, long long sBrow, int cB,
    void* __restrict__ Cb, int outBf, long long sCb, long long sCh, long long sCm,
    const float* __restrict__ bias, float scale, int act, int K, int H)
{
  __shared__ short As[64*40];
  __shared__ short Bs[64*40];
  const int tid = threadIdx.x;
  int bx = blockIdx.x, by = blockIdx.y;
  if (gridDim.z == 1 && (gridDim.y & 7) == 0){
    int gx = gridDim.x;
    int lin = by*gx + bx;
    int xcd = lin & 7, i = lin >> 3;
    by = xcd*(gridDim.y >> 3) + i / gx;
    bx = i % gx;
  }
  const int z = blockIdx.z; const int zb = z / H; const int zh = z % H;
  const int col0 = bx << 6, m0 = by << 6;
  const float* Af = (const float*)Ab;
  const bf16*  Aw = (const bf16*)Ab;
  const long long aoff = zb*sAb + zh*sAh;
  const float* Bf = (const float*)Bb;
  const bf16* Bw = (const bf16*)Bb;
  const long long boff = zb*sBb + zh*sBh;
  float4v acc[4];
  #pragma unroll
  for (int i=0;i<4;++i) acc[i] = (float4v)(0.f);
  const int lane = tid & 63, w = tid >> 6;
  const int lr = lane & 15, quad = lane >> 4;

  for (int k0 = 0; k0 < K; k0 += 32){
    if (cA == 1){
      int row = tid >> 2, k8 = (tid & 3) << 3;
      short8v v = *(const short8v*)&Aw[aoff + (long long)(m0+row)*sAm + k0 + k8];
      *(short8v*)&As[row*40 + k8] = v;
    } else {
      #pragma unroll
      for (int i=0;i<2;++i){
        int g = tid + i*256;
        int row = g >> 3, k4 = (g & 7) << 2;
        float4 v = *(const float4*)&Af[aoff + (long long)(m0+row)*sAm + k0 + k4];
        short4v s4; s4.x=f2bfs(v.x); s4.y=f2bfs(v.y); s4.z=f2bfs(v.z); s4.w=f2bfs(v.w);
        *(short4v*)&As[row*40 + k4] = s4;
      }
    }
    if (cB == 2){
      int row = tid >> 2, k8 = (tid & 3) << 3;
      short8v v = *(const short8v*)&Bw[boff + (long long)(col0+row)*sBrow + k0 + k8];
      *(short8v*)&Bs[row*40 + k8] = v;
    } else {
      #pragma unroll
      for (int i=0;i<2;++i){
        int g = tid + i*256;
        int row = g >> 3, k4 = (g & 7) << 2;
        float4 v = *(const float4*)&Bf[boff + (long long)(col0+row)*sBrow + k0 + k4];
        short4v s4; s4.x=f2bfs(v.x); s4.y=f2bfs(v.y); s4.z=f2bfs(v.z); s4.w=f2bfs(v.w);
        *(short4v*)&Bs[row*40 + k4] = s4;
      }
    }
    __syncthreads();
    short8v a = *(short8v*)&As[(w*16 + lr)*40 + quad*8];
    #pragma unroll
    for (int cb=0; cb<4; ++cb){
      short8v bfr = *(short8v*)&Bs[(cb*16 + lr)*40 + quad*8];
      acc[cb] = __builtin_amdgcn_mfma_f32_16x16x32_bf16(a, bfr, acc[cb], 0, 0, 0);
    }
    __syncthreads();
  }
  #pragma unroll
  for (int cb=0; cb<4; ++cb){
    #pragma unroll
    for (int r=0;r<4;++r){
      int m = m0 + w*16 + quad*4 + r;
      int n = col0 + cb*16 + lr;
      float v = acc[cb][r] * scale;
      if (bias) v += bias[n];
      if (act==1) v = fmaxf(v,0.f);
      else if (act==2) v = 0.5f*v*(1.f + erff(v*0.70710678118654752f));
      else if (act==3) v = fmaxf(v,0.f) + log1pf(__expf(-fabsf(v)));
      if (outBf) ((bf16*)Cb)[zb*sCb + zh*sCh + (long long)m*sCm + n] = f2bf(v);
      else       ((float*)Cb)[zb*sCb + zh*sCh + (long long)m*sCm + n] = v;
    }
  }
}

// ---------------- 64x64 tile, BK=64 GEMM (8 MFMA/wave per barrier pair) ----------------
__global__ __launch_bounds__(256) void k_gemm64(
    const void* __restrict__ Ab, int cA, long long sAm,
    const bf16* __restrict__ Bw, long long sBrow,
    void* __restrict__ Cb, int outBf, long long sCm,
    const float* __restrict__ bias, int act, int K)
{
  __shared__ short As[64*72];
  __shared__ short Bs[64*72];
  const int tid = threadIdx.x;
  int bx = blockIdx.x, by = blockIdx.y;
  {
    int gx = gridDim.x;
    int lin = by*gx + bx;
    int xcd = lin & 7, i = lin >> 3;
    by = xcd*(gridDim.y >> 3) + i / gx;
    bx = i % gx;
  }
  const int col0 = bx << 6, m0 = by << 6;
  const float* Af = (const float*)Ab;
  const bf16*  Aw = (const bf16*)Ab;
  const int lane = tid & 63, w = tid >> 6;
  const int lr = lane & 15, quad = lane >> 4;
  float4v acc[4];
  #pragma unroll
  for (int i=0;i<4;++i) acc[i] = (float4v)(0.f);

  for (int k0 = 0; k0 < K; k0 += 64){
    if (cA == 1){
      #pragma unroll
      for (int i=0;i<2;++i){
        int idx = tid + i*256;
        int row = idx >> 3, k8 = (idx & 7) << 3;
        *(short8v*)&As[row*72 + k8] =
          *(const short8v*)&Aw[(long long)(m0+row)*sAm + k0 + k8];
      }
    } else {
      #pragma unroll
      for (int i=0;i<4;++i){
        int g = tid + i*256;
        int row = g >> 4, k4 = (g & 15) << 2;
        float4 v = *(const float4*)&Af[(long long)(m0+row)*sAm + k0 + k4];
        short4v s4; s4.x=f2bfs(v.x); s4.y=f2bfs(v.y); s4.z=f2bfs(v.z); s4.w=f2bfs(v.w);
        *(short4v*)&As[row*72 + k4] = s4;
      }
    }
    #pragma unroll
    for (int i=0;i<2;++i){
      int idx = tid + i*256;
      int row = idx >> 3, k8 = (idx & 7) << 3;
      *(short8v*)&Bs[row*72 + k8] =
        *(const short8v*)&Bw[(long long)(col0+row)*sBrow + k0 + k8];
    }
    __syncthreads();
    #pragma unroll
    for (int kk=0; kk<64; kk+=32){
      short8v a = *(short8v*)&As[(w*16 + lr)*72 + kk + quad*8];
      #pragma unroll
      for (int cb=0; cb<4; ++cb){
        short8v bfr = *(short8v*)&Bs[(cb*16 + lr)*72 + kk + quad*8];
        acc[cb] = __builtin_amdgcn_mfma_f32_16x16x32_bf16(a, bfr, acc[cb], 0, 0, 0);
      }
    }
    __syncthreads();
  }
  #pragma unroll
  for (int cb=0; cb<4; ++cb){
    #pragma unroll
    for (int r=0;r<4;++r){
      int m = m0 + w*16 + quad*4 + r;
      int n = col0 + cb*16 + lr;
      float v = acc[cb][r];
      if (bias) v += bias[n];
      if (act==1) v = fmaxf(v,0.f);
      else if (act==2) v = 0.5f*v*(1.f + erff(v*0.70710678118654752f));
      if (outBf) ((bf16*)Cb)[(long long)m*sCm + n] = f2bf(v);
      else       ((float*)Cb)[(long long)m*sCm + n] = v;
    }
  }
}

// ---------------- split-K BK=64 GEMM -> separate partial buffers ----------------
__global__ __launch_bounds__(256) void k_skp64(
    const void* __restrict__ Ab, int cA, long long sAz, long long sAm,
    const bf16* __restrict__ Bw, long long sBrow,
    float* __restrict__ Cp, long long sCp, long long sCm,
    const float* __restrict__ bias, int K, int KS)
{
  __shared__ short As[64*72];
  __shared__ short Bs[64*72];
  const int tid = threadIdx.x;
  int bx, by, bz;
  {
    int gx = gridDim.x, gy = gridDim.y, gz = gridDim.z;
    int lin = ((int)blockIdx.z*gy + blockIdx.y)*gx + blockIdx.x;
    int xcd = lin & 7, i = lin >> 3;
    bx = i % gx; int rest = i / gx;
    int pair = xcd * ((gy*gz) >> 3) + rest;
    by = pair % gy; bz = pair / gy;
  }
  const int zb = bz / KS, kc = bz % KS;
  const int Kc = K / KS;
  const int col0 = bx << 6, m0 = by << 6;
  const float* Af = (const float*)Ab;
  const bf16*  Aw = (const bf16*)Ab;
  const long long aoff = (long long)zb*sAz;
  float4v acc[4];
  #pragma unroll
  for (int i=0;i<4;++i) acc[i] = (float4v)(0.f);
  const int lane = tid & 63, w = tid >> 6;
  const int lr = lane & 15, quad = lane >> 4;

  const int kbeg = kc*Kc;
  for (int k0 = kbeg; k0 < kbeg + Kc; k0 += 64){
    if (cA == 1){
      #pragma unroll
      for (int i=0;i<2;++i){
        int idx = tid + i*256;
        int row = idx >> 3, k8 = (idx & 7) << 3;
        *(short8v*)&As[row*72 + k8] =
          *(const short8v*)&Aw[aoff + (long long)(m0+row)*sAm + k0 + k8];
      }
    } else {
      #pragma unroll
      for (int i=0;i<4;++i){
        int g = tid + i*256;
        int row = g >> 4, k4 = (g & 15) << 2;
        float4 v = *(const float4*)&Af[aoff + (long long)(m0+row)*sAm + k0 + k4];
        short4v s4; s4.x=f2bfs(v.x); s4.y=f2bfs(v.y); s4.z=f2bfs(v.z); s4.w=f2bfs(v.w);
        *(short4v*)&As[row*72 + k4] = s4;
      }
    }
    #pragma unroll
    for (int i=0;i<2;++i){
      int idx = tid + i*256;
      int row = idx >> 3, k8 = (idx & 7) << 3;
      *(short8v*)&Bs[row*72 + k8] =
        *(const short8v*)&Bw[(long long)(col0+row)*sBrow + k0 + k8];
    }
    __syncthreads();
    #pragma unroll
    for (int kk=0; kk<64; kk+=32){
      short8v a = *(short8v*)&As[(w*16 + lr)*72 + kk + quad*8];
      #pragma unroll
      for (int cb=0; cb<4; ++cb){
        short8v bfr = *(short8v*)&Bs[(cb*16 + lr)*72 + kk + quad*8];
        acc[cb] = __builtin_amdgcn_mfma_f32_16x16x32_bf16(a, bfr, acc[cb], 0, 0, 0);
      }
    }
    __syncthreads();
  }
  #pragma unroll
  for (int cb=0; cb<4; ++cb){
    #pragma unroll
    for (int r=0;r<4;++r){
      int m = m0 + w*16 + quad*4 + r;
      int n = col0 + cb*16 + lr;
      float v = acc[cb][r];
      if (kc == 0 && bias) v += bias[n];
      Cp[(long long)bz*sCp + (long long)m*sCm + n] = v;
    }
  }
}

// ---------------- split-K atomic GEMM (xproj only; dbc pre-zeroed by conv) ----------------
__global__ __launch_bounds__(256) void k_gemm_sk(
    const void* __restrict__ Ab, int cA, long long sAz, long long sAm,
    const bf16* __restrict__ Bw, long long sBrow,
    float* __restrict__ Cb, long long sCz, long long sCm,
    const float* __restrict__ bias, int K, int KS)
{
  __shared__ short As[64*40];
  __shared__ short Bs[64*40];
  const int tid = threadIdx.x;
  int bx, by, bz;
  {
    int gx = gridDim.x, gy = gridDim.y, gz = gridDim.z;
    int lin = ((int)blockIdx.z*gy + blockIdx.y)*gx + blockIdx.x;
    int xcd = lin & 7, i = lin >> 3;
    bx = i % gx; int rest = i / gx;
    int pair = xcd * ((gy*gz) >> 3) + rest;
    by = pair % gy; bz = pair / gy;
  }
  const int zb = bz / KS, kc = bz % KS;
  const int Kc = K / KS;
  const int col0 = bx << 6, m0 = by << 6;
  const bf16*  Aw = (const bf16*)Ab;
  const float* Af = (const float*)Ab;
  const long long aoff = (long long)zb*sAz;
  float4v acc[4];
  #pragma unroll
  for (int i=0;i<4;++i) acc[i] = (float4v)(0.f);
  const int lane = tid & 63, w = tid >> 6;
  const int lr = lane & 15, quad = lane >> 4;

  const int kbeg = kc*Kc;
  for (int k0 = kbeg; k0 < kbeg + Kc; k0 += 32){
    if (cA == 1){
      int row = tid >> 2, k8 = (tid & 3) << 3;
      *(short8v*)&As[row*40 + k8] =
        *(const short8v*)&Aw[aoff + (long long)(m0+row)*sAm + k0 + k8];
    } else {
      #pragma unroll
      for (int i=0;i<2;++i){
        int g = tid + i*256;
        int row = g >> 3, k4 = (g & 7) << 2;
        float4 v = *(const float4*)&Af[aoff + (long long)(m0+row)*sAm + k0 + k4];
        short4v s4; s4.x=f2bfs(v.x); s4.y=f2bfs(v.y); s4.z=f2bfs(v.z); s4.w=f2bfs(v.w);
        *(short4v*)&As[row*40 + k4] = s4;
      }
    }
    {
      int row = tid >> 2, k8 = (tid & 3) << 3;
      *(short8v*)&Bs[row*40 + k8] =
        *(const short8v*)&Bw[(long long)(col0+row)*sBrow + k0 + k8];
    }
    __syncthreads();
    short8v a = *(short8v*)&As[(w*16 + lr)*40 + quad*8];
    #pragma unroll
    for (int cb=0; cb<4; ++cb){
      short8v bfr = *(short8v*)&Bs[(cb*16 + lr)*40 + quad*8];
      acc[cb] = __builtin_amdgcn_mfma_f32_16x16x32_bf16(a, bfr, acc[cb], 0, 0, 0);
    }
    __syncthreads();
  }
  #pragma unroll
  for (int cb=0; cb<4; ++cb){
    #pragma unroll
    for (int r=0;r<4;++r){
      int m = m0 + w*16 + quad*4 + r;
      int n = col0 + cb*16 + lr;
      float v = acc[cb][r];
      if (kc == 0 && bias) v += bias[n];
      atomicAdd(&Cb[(long long)zb*sCz + (long long)m*sCm + n], v);
    }
  }
}

// ---------------- flash attention, split-K partials (8 chunks of 128 kpos), bf16 Opart ----------------
__global__ __launch_bounds__(256) void k_flash2(
    const bf16* __restrict__ Qb, int ldq, int qoff,
    const bf16* __restrict__ Kb, int ldk, int koff,
    const bf16* __restrict__ Vb, int ldv, int voff,
    bf16* __restrict__ Opart, float* __restrict__ Ml, float scale)
{
  __shared__ short Qs[64*40];
  __shared__ short Ks[64*40];
  __shared__ short Vs[64*40];
  __shared__ short Ps[64*40];
  const int tid = threadIdx.x;
  const int q0 = blockIdx.x << 6;
  const int z = blockIdx.y; const int b = z >> 3; const int hoff = (z & 7) << 6;
  const int kc = blockIdx.z;
  const int lane = tid & 63, w = tid >> 6;
  const int lr = lane & 15, quad = lane >> 4;

  #pragma unroll
  for (int i=0;i<2;++i){
    int idx = tid + i*256;
    int row = idx >> 3, d8 = (idx & 7) << 3;
    *(short8v*)&Qs[row*40 + d8] =
      *(const short8v*)&Qb[(size_t)((q0+row)*BB + b)*ldq + qoff + hoff + d8];
  }

  float m_r[4], l_r[4];
  #pragma unroll
  for (int r=0;r<4;++r){ m_r[r] = -1e30f; l_r[r] = 0.f; }
  float4v acc_o[4];
  #pragma unroll
  for (int cb=0;cb<4;++cb) acc_o[cb] = (float4v)(0.f);

  short8v kr[2], vr[2];
  #pragma unroll
  for (int i=0;i<2;++i){
    int idx = tid + i*256;
    int row = kc*128 + (idx >> 3); int d8 = (idx & 7) << 3;
    kr[i] = *(const short8v*)&Kb[(size_t)(row*BB + b)*ldk + koff + hoff + d8];
    vr[i] = *(const short8v*)&Vb[(size_t)(row*BB + b)*ldv + voff + hoff + d8];
  }

  for (int kt=0; kt<2; ++kt){
    __syncthreads();
    #pragma unroll
    for (int i=0;i<2;++i){
      int idx = tid + i*256;
      int row = idx >> 3, d8 = (idx & 7) << 3;
      *(short8v*)&Ks[row*40 + d8] = kr[i];
      int sc = row ^ d8;
      #pragma unroll
      for (int j=0;j<8;++j) Vs[(d8+j)*40 + sc] = vr[i][j];
    }
    if (kt < 1){
      #pragma unroll
      for (int i=0;i<2;++i){
        int idx = tid + i*256;
        int row = kc*128 + 64 + (idx >> 3); int d8 = (idx & 7) << 3;
        kr[i] = *(const short8v*)&Kb[(size_t)(row*BB + b)*ldk + koff + hoff + d8];
        vr[i] = *(const short8v*)&Vb[(size_t)(row*BB + b)*ldv + voff + hoff + d8];
      }
    }
    __syncthreads();
    short8v a0 = *(short8v*)&Qs[(w*16+lr)*40 + quad*8];
    short8v a1 = *(short8v*)&Qs[(w*16+lr)*40 + quad*8 + 32];
    float4v s[4];
    #pragma unroll
    for (int cb=0;cb<4;++cb){
      short8v b0 = *(short8v*)&Ks[(cb*16+lr)*40 + quad*8];
      short8v b1 = *(short8v*)&Ks[(cb*16+lr)*40 + quad*8 + 32];
      float4v t = __builtin_amdgcn_mfma_f32_16x16x32_bf16(a0, b0, (float4v)(0.f), 0,0,0);
      s[cb] = __builtin_amdgcn_mfma_f32_16x16x32_bf16(a1, b1, t, 0,0,0);
    }
    #pragma unroll
    for (int cb=0;cb<4;++cb)
      #pragma unroll
      for (int r=0;r<4;++r) s[cb][r] *= scale;
    float al[4];
    #pragma unroll
    for (int r=0;r<4;++r){
      float mx = fmaxf(fmaxf(s[0][r],s[1][r]),fmaxf(s[2][r],s[3][r]));
      #pragma unroll
      for (int ofs=1; ofs<16; ofs<<=1) mx = fmaxf(mx, __shfl_xor(mx, ofs));
      float mnew = fmaxf(m_r[r], mx);
      al[r] = __expf(m_r[r] - mnew);
      float sum = 0.f;
      #pragma unroll
      for (int cb=0;cb<4;++cb){
        float p = __expf(s[cb][r] - mnew);
        s[cb][r] = p;
        sum += p;
      }
      #pragma unroll
      for (int ofs=1; ofs<16; ofs<<=1) sum += __shfl_xor(sum, ofs);
      l_r[r] = l_r[r]*al[r] + sum;
      m_r[r] = mnew;
    }
    #pragma unroll
    for (int cb=0;cb<4;++cb)
      #pragma unroll
      for (int r=0;r<4;++r){
        acc_o[cb][r] *= al[r];
        Ps[(w*16 + quad*4 + r)*40 + cb*16 + lr] = f2bfs(s[cb][r]);
      }
    __syncthreads();
    short8v p0 = *(short8v*)&Ps[(w*16+lr)*40 + quad*8];
    short8v p1 = *(short8v*)&Ps[(w*16+lr)*40 + quad*8 + 32];
    #pragma unroll
    for (int cb=0;cb<4;++cb){
      int dcol = cb*16 + lr;
      int sw = (dcol >> 3) & 7;
      short8v v0 = *(short8v*)&Vs[dcol*40 + ((quad ^ sw) << 3)];
      short8v v1 = *(short8v*)&Vs[dcol*40 + (((quad+4) ^ sw) << 3)];
      acc_o[cb] = __builtin_amdgcn_mfma_f32_16x16x32_bf16(p0, v0, acc_o[cb], 0,0,0);
      acc_o[cb] = __builtin_amdgcn_mfma_f32_16x16x32_bf16(p1, v1, acc_o[cb], 0,0,0);
    }
  }
  #pragma unroll
  for (int r=0;r<4;++r){
    int row = q0 + w*16 + quad*4 + r;
    size_t obase = ((size_t)(kc*16 + z)*1024 + row)*64;
    #pragma unroll
    for (int cb=0;cb<4;++cb)
      Opart[obase + cb*16 + lr] = f2bf(acc_o[cb][r]);
    if (lr == 0){
      size_t mi = ((size_t)kc*16384 + z*1024 + row)*2;
      Ml[mi] = m_r[r]; Ml[mi+1] = l_r[r];
    }
  }
}

// ---------------- combine 8 split-K partials (bf16 Opart) ----------------
__global__ __launch_bounds__(256) void k_fcomb(const bf16* __restrict__ Opart, const float* __restrict__ Ml,
                                               bf16* __restrict__ O, float* __restrict__ Mfin)
{
  int gid = blockIdx.x*256 + threadIdx.x;   // 1M
  int row = gid >> 6, d = gid & 63;
  int z = row >> 10, q = row & 1023;
  float m[8], l[8];
  #pragma unroll
  for (int kc=0;kc<8;++kc){
    size_t mi = ((size_t)kc*16384 + row)*2;
    m[kc] = Ml[mi]; l[kc] = Ml[mi+1];
  }
  float ms = -1e30f;
  #pragma unroll
  for (int kc=0;kc<8;++kc) ms = fmaxf(ms, m[kc]);
  float ls = 0.f, o = 0.f;
  #pragma unroll
  for (int kc=0;kc<8;++kc){
    float c = __expf(m[kc]-ms);
    ls += l[kc]*c;
    o  += bf2f(Opart[((size_t)kc*16384 + row)*64 + d]) * c;
  }
  o /= ls;
  int b = z >> 3, hoff = (z & 7) << 6;
  O[((size_t)q*BB + b)*512 + hoff + d] = f2bf(o);
  if (d == 0){ Mfin[(size_t)row*2] = ms; Mfin[(size_t)row*2+1] = ls; }
}

// ---------------- head-mean of P from Q,K + final m,l ----------------
__global__ __launch_bounds__(256) void k_pmean(
    const bf16* __restrict__ Qb, int ldq,
    const bf16* __restrict__ Kb, int ldk,
    const float* __restrict__ Mfin, void* __restrict__ out,
    const int* __restrict__ flag, float scale)
{
  __shared__ short Qs[64*40];
  __shared__ short Ks[64*40];
  const int tid = threadIdx.x;
  const int k0 = blockIdx.x << 6, q0 = blockIdx.y << 6;
  const int b = blockIdx.z;
  const int lane = tid & 63, w = tid >> 6;
  const int lr = lane & 15, quad = lane >> 4;
  float acc[4][4];
  #pragma unroll
  for (int cb=0;cb<4;++cb)
    #pragma unroll
    for (int r=0;r<4;++r) acc[cb][r] = 0.f;

  for (int h=0; h<8; ++h){
    int z = b*8 + h, hoff = h << 6;
    __syncthreads();
    #pragma unroll
    for (int i=0;i<2;++i){
      int idx = tid + i*256;
      int row = idx >> 3, d8 = (idx & 7) << 3;
      *(short8v*)&Qs[row*40 + d8] = *(const short8v*)&Qb[((size_t)(q0+row)*BB + b)*ldq + hoff + d8];
      *(short8v*)&Ks[row*40 + d8] = *(const short8v*)&Kb[((size_t)(k0+row)*BB + b)*ldk + hoff + d8];
    }
    __syncthreads();
    float mm[4], li[4];
    #pragma unroll
    for (int r=0;r<4;++r){
      int qrow = q0 + w*16 + quad*4 + r;
      size_t mi = ((size_t)z*1024 + qrow)*2;
      mm[r] = Mfin[mi]; li[r] = 1.f/Mfin[mi+1];
    }
    short8v a0 = *(short8v*)&Qs[(w*16+lr)*40 + quad*8];
    short8v a1 = *(short8v*)&Qs[(w*16+lr)*40 + quad*8 + 32];
    #pragma unroll
    for (int cb=0;cb<4;++cb){
      short8v b0 = *(short8v*)&Ks[(cb*16+lr)*40 + quad*8];
      short8v b1 = *(short8v*)&Ks[(cb*16+lr)*40 + quad*8 + 32];
      float4v t = __builtin_amdgcn_mfma_f32_16x16x32_bf16(a0, b0, (float4v)(0.f), 0,0,0);
      t = __builtin_amdgcn_mfma_f32_16x16x32_bf16(a1, b1, t, 0,0,0);
      #pragma unroll
      for (int r=0;r<4;++r)
        acc[cb][r] += __expf(t[r]*scale - mm[r]) * li[r];
    }
  }
  #pragma unroll
  for (int cb=0;cb<4;++cb)
    #pragma unroll
    for (int r=0;r<4;++r){
      int q = q0 + w*16 + quad*4 + r;
      int k = k0 + cb*16 + lr;
      float v = acc[cb][r] * 0.125f;
      size_t o = (size_t)(1u<<20) + ((size_t)b<<20) + (size_t)q*1024 + k;
      if (flag[0]) ((bf16*)out)[o] = f2bf(v);
      else         ((float*)out)[o] = v;
    }
}

// ---------------- norms (consume split-K partials) ----------------
__global__ __launch_bounds__(256) void k_add_rmsnorm(float* __restrict__ x, const float* __restrict__ tp,
                                                     long long pstr, int KS, const float* __restrict__ w){
  int row = blockIdx.x; size_t base = (size_t)row*DD;
  int tid = threadIdx.x;
  float v0 = x[base+tid], v1 = x[base+tid+256];
  for (int k=0;k<KS;++k){ v0 += tp[k*pstr + base+tid]; v1 += tp[k*pstr + base+tid+256]; }
  __shared__ float red[256];
  red[tid] = v0*v0 + v1*v1; __syncthreads();
  for (int s=128;s>0;s>>=1){ if(tid<s) red[tid]+=red[tid+s]; __syncthreads(); }
  float rms = rsqrtf(red[0]*(1.f/DD) + EPSF);
  x[base+tid]     = v0 * w[tid]     * rms;
  x[base+tid+256] = v1 * w[tid+256] * rms;
}

__global__ __launch_bounds__(256) void k_add_rmsnorm_out(const float* __restrict__ x, const float* __restrict__ tp,
                                                         long long pstr, int KS,
                                                         const float* __restrict__ w, void* __restrict__ out,
                                                         const int* __restrict__ flag){
  int row = blockIdx.x; size_t base = (size_t)row*DD;
  int tid = threadIdx.x;
  float v0 = x[base+tid], v1 = x[base+tid+256];
  for (int k=0;k<KS;++k){ v0 += tp[k*pstr + base+tid]; v1 += tp[k*pstr + base+tid+256]; }
  __shared__ float red[256];
  red[tid] = v0*v0 + v1*v1; __syncthreads();
  for (int s=128;s>0;s>>=1){ if(tid<s) red[tid]+=red[tid+s]; __syncthreads(); }
  float rms = rsqrtf(red[0]*(1.f/DD) + EPSF);
  float o0 = v0 * w[tid]     * rms;
  float o1 = v1 * w[tid+256] * rms;
  if (flag[0]){ ((bf16*)out)[base+tid] = f2bf(o0); ((bf16*)out)[base+tid+256] = f2bf(o1); }
  else        { ((float*)out)[base+tid] = o0;      ((float*)out)[base+tid+256] = o1; }
}

// fused: tgt = rmsnorm(tgt + sum tp, n2w); xn = layernorm(tgt, ln1) (bf16)
__global__ __launch_bounds__(256) void k_rms_ln(float* __restrict__ tgt, const float* __restrict__ tp,
                                                long long pstr, const float* __restrict__ n2w,
                                                const float* __restrict__ lw, const float* __restrict__ lb,
                                                bf16* __restrict__ xn){
  int r = blockIdx.x;
  int b = r >> 10, l = r & 1023;
  size_t base = ((size_t)l*BB + b)*DD;
  int tid = threadIdx.x;
  float v0 = tgt[base+tid] + tp[base+tid] + tp[pstr + base+tid];
  float v1 = tgt[base+tid+256] + tp[base+tid+256] + tp[pstr + base+tid+256];
  __shared__ float red[256];
  red[tid] = v0*v0 + v1*v1; __syncthreads();
  for (int s=128;s>0;s>>=1){ if(tid<s) red[tid]+=red[tid+s]; __syncthreads(); }
  float rms = rsqrtf(red[0]*(1.f/DD) + EPSF);
  v0 = v0 * n2w[tid]     * rms;
  v1 = v1 * n2w[tid+256] * rms;
  tgt[base+tid] = v0; tgt[base+tid+256] = v1;
  __syncthreads();
  red[tid] = v0 + v1; __syncthreads();
  for (int s=128;s>0;s>>=1){ if(tid<s) red[tid]+=red[tid+s]; __syncthreads(); }
  float mean = red[0]*(1.f/DD);
  __syncthreads();
  red[tid] = v0*v0 + v1*v1; __syncthreads();
  for (int s=128;s>0;s>>=1){ if(tid<s) red[tid]+=red[tid+s]; __syncthreads(); }
  float var = red[0]*(1.f/DD) - mean*mean;
  float rstd = rsqrtf(var + EPSF);
  size_t dst = (size_t)r*DD;
  xn[dst+tid]     = f2bf((v0-mean)*rstd*lw[tid]     + lb[tid]);
  xn[dst+tid+256] = f2bf((v1-mean)*rstd*lw[tid+256] + lb[tid+256]);
}

// combine_ln over yproj partials
__global__ __launch_bounds__(256) void k_combine_ln(const float* __restrict__ yp, long long pstr,
                                                    const float* __restrict__ w, const float* __restrict__ bias,
                                                    bf16* __restrict__ mo){
  int r = blockIdx.x; int b = r>>10, l = r&1023;
  size_t rf = (size_t)r*DD;
  size_t rb = ((size_t)(b<<10) + (1023 - l))*DD;
  int tid = threadIdx.x;
  float v0 = yp[rf+tid]     + yp[pstr + rf+tid]     + yp[2*pstr + rb+tid]     + yp[3*pstr + rb+tid];
  float v1 = yp[rf+tid+256] + yp[pstr + rf+tid+256] + yp[2*pstr + rb+tid+256] + yp[3*pstr + rb+tid+256];
  __shared__ float red[256];
  red[tid] = v0 + v1; __syncthreads();
  for (int s=128;s>0;s>>=1){ if(tid<s) red[tid]+=red[tid+s]; __syncthreads(); }
  float mean = red[0]*(1.f/DD);
  __syncthreads();
  red[tid] = v0*v0 + v1*v1; __syncthreads();
  for (int s=128;s>0;s>>=1){ if(tid<s) red[tid]+=red[tid+s]; __syncthreads(); }
  float var = red[0]*(1.f/DD) - mean*mean;
  float rstd = rsqrtf(var + EPSF);
  mo[rf+tid]     = f2bf((v0-mean)*rstd*w[tid]     + bias[tid]);
  mo[rf+tid+256] = f2bf((v1-mean)*rstd*w[tid+256] + bias[tid+256]);
}

__global__ __launch_bounds__(256) void k_bimamba_final(float* __restrict__ tgt, const float* __restrict__ fp,
                                                       long long pstr, const float* __restrict__ w){
  int r = blockIdx.x; int b = r>>10, l = r&1023;
  size_t t = ((size_t)l*BB + b)*DD;
  size_t f = (size_t)r*DD;
  int tid = threadIdx.x;
  float v0 = 2.f*tgt[t+tid], v1 = 2.f*tgt[t+tid+256];
  #pragma unroll
  for (int k=0;k<4;++k){ v0 += fp[k*pstr + f+tid]; v1 += fp[k*pstr + f+tid+256]; }
  __shared__ float red[256];
  red[tid] = v0*v0 + v1*v1; __syncthreads();
  for (int s=128;s>0;s>>=1){ if(tid<s) red[tid]+=red[tid+s]; __syncthreads(); }
  float rms = rsqrtf(red[0]*(1.f/DD) + EPSF);
  tgt[t+tid]     = v0 * w[tid]     * rms;
  tgt[t+tid+256] = v1 * w[tid+256] * rms;
}

// ---------------- causal depthwise conv + silu -> bf16 (+dbc zeroing) ----------------
__global__ __launch_bounds__(256) void k_conv_silu(const float* __restrict__ xz, const float* __restrict__ cw,
                                                   const float* __restrict__ cb, bf16* __restrict__ xmc,
                                                   float* __restrict__ dbcz){
  int rev = blockIdx.y;
  int idx = blockIdx.x*256 + threadIdx.x;  // 2M
  if (rev == 0 && blockIdx.x < 1024) dbcz[idx] = 0.f;   // zero 262144 dbc floats
  int c = idx & 1023;
  int l = (idx >> 10) & 1023;
  int b = idx >> 20;
  float acc = cb[c];
  float w4[4];
  #pragma unroll
  for (int j=0;j<4;++j) w4[j] = cw[(c<<2)+j];
  #pragma unroll
  for (int j=0;j<4;++j){
    int t = l - 3 + j;
    if (t >= 0){
      int src = rev ? (1023 - t) : t;
      acc = fmaf(w4[j], xz[((size_t)(b<<10) + src)*2048 + c], acc);
    }
  }
  xmc[(size_t)rev*(2u<<20) + idx] = f2bf(acc / (1.f + __expf(-acc)));
}

// ---------------- chunked selective scan: 64 chunks of 16 steps ----------------
__global__ __launch_bounds__(256) void k_scan1(
    const bf16* __restrict__ delta_f, const bf16* __restrict__ delta_b,
    const bf16* __restrict__ xmc_f,  const bf16* __restrict__ xmc_b,
    const float* __restrict__ dbc_f,  const float* __restrict__ dbc_b,
    const float* __restrict__ Alog,
    float* __restrict__ hend, float* __restrict__ Sdl)
{
  int ch = blockIdx.x*256 + threadIdx.x;
  int c = blockIdx.y;
  int dir = ch >> 11, b = (ch >> 10) & 1, d = ch & 1023;
  const bf16* delta = dir ? delta_b : delta_f;
  const bf16* xmc   = dir ? xmc_b   : xmc_f;
  const float* dbc  = dir ? dbc_b   : dbc_f;
  float Av[NSTATE]; bool fast = true;
  #pragma unroll
  for (int n=0;n<NSTATE;++n){
    Av[n] = -__expf(Alog[d*NSTATE+n]);
    fast = fast && (fabsf(Av[n] + (float)(n+1)) < 1e-4f*(float)(n+1));
  }
  float h[NSTATE];
  #pragma unroll
  for (int n=0;n<NSTATE;++n) h[n]=0.f;
  float S = 0.f;
  int r0 = b*1024 + c*16;
  for (int t=0;t<16;++t){
    int r = r0 + t;
    float dl = bf2f(delta[((size_t)r<<10) + d]);
    float x  = bf2f(xmc[((size_t)r<<10) + d]);
    const float4* bp = (const float4*)(dbc + (size_t)r*64 + 32);
    float Bv[NSTATE];
    ((float4*)Bv)[0]=bp[0]; ((float4*)Bv)[1]=bp[1]; ((float4*)Bv)[2]=bp[2]; ((float4*)Bv)[3]=bp[3];
    S += dl;
    float dx = dl*x;
    float dA[NSTATE];
    if (fast){ powtab(__expf(-dl), dA); }
    else {
      #pragma unroll
      for (int n=0;n<NSTATE;++n) dA[n] = __expf(dl*Av[n]);
    }
    #pragma unroll
    for (int n=0;n<NSTATE;++n)
      h[n] = fmaf(dA[n], h[n], dx*Bv[n]);
  }
  size_t base = ((size_t)c*4096 + ch)*16;
  #pragma unroll
  for (int n=0;n<NSTATE;++n) hend[base+n] = h[n];
  Sdl[c*4096 + ch] = S;
}

__global__ __launch_bounds__(256) void k_scan_carry(const float* __restrict__ Alog,
                                                    float* __restrict__ hh, const float* __restrict__ Sdl)
{
  int g = blockIdx.x*256 + threadIdx.x;   // 65536
  int ch = g >> 4, n = g & 15;
  int d = ch & 1023;
  float Av = -__expf(Alog[d*16+n]);
  float h = 0.f;
  for (int c=0;c<64;++c){
    size_t base = ((size_t)c*4096 + ch)*16 + n;
    float he = hh[base];
    hh[base] = h;
    h = fmaf(__expf(Av*Sdl[c*4096+ch]), h, he);
  }
}

__global__ __launch_bounds__(256) void k_scan2(
    const bf16* __restrict__ delta_f, const bf16* __restrict__ delta_b,
    const bf16* __restrict__ xmc_f,  const bf16* __restrict__ xmc_b,
    const float* __restrict__ dbc_f,  const float* __restrict__ dbc_b,
    const float* __restrict__ Alog,   const float* __restrict__ hin,
    const float* __restrict__ xz,     const float* __restrict__ Dp,
    bf16* __restrict__ yo)
{
  int ch = blockIdx.x*256 + threadIdx.x;
  int c = blockIdx.y;
  int dir = ch >> 11, b = (ch >> 10) & 1, d = ch & 1023;
  const bf16* delta = dir ? delta_b : delta_f;
  const bf16* xmc   = dir ? xmc_b   : xmc_f;
  const float* dbc  = dir ? dbc_b   : dbc_f;
  float Av[NSTATE]; bool fast = true;
  #pragma unroll
  for (int n=0;n<NSTATE;++n){
    Av[n] = -__expf(Alog[d*NSTATE+n]);
    fast = fast && (fabsf(Av[n] + (float)(n+1)) < 1e-4f*(float)(n+1));
  }
  float h[NSTATE];
  size_t cbase = ((size_t)c*4096 + ch)*16;
  #pragma unroll
  for (int n=0;n<NSTATE;++n) h[n] = hin[cbase+n];
  float Dd = Dp[d];
  int r0 = b*1024 + c*16;
  for (int t=0;t<16;++t){
    int r = r0 + t;
    int lidx = c*16 + t;
    float dl = bf2f(delta[((size_t)r<<10) + d]);
    float x  = bf2f(xmc[((size_t)r<<10) + d]);
    const float4* bp = (const float4*)(dbc + (size_t)r*64 + 32);
    float Bv[NSTATE], Cv[NSTATE];
    ((float4*)Bv)[0]=bp[0]; ((float4*)Bv)[1]=bp[1]; ((float4*)Bv)[2]=bp[2]; ((float4*)Bv)[3]=bp[3];
    ((float4*)Cv)[0]=bp[4]; ((float4*)Cv)[1]=bp[5]; ((float4*)Cv)[2]=bp[6]; ((float4*)Cv)[3]=bp[7];
    float dx = dl*x;
    float dA[NSTATE];
    if (fast){ powtab(__expf(-dl), dA); }
    else {
      #pragma unroll
      for (int n=0;n<NSTATE;++n) dA[n] = __expf(dl*Av[n]);
    }
    float acc0 = 0.f, acc1 = 0.f;
    #pragma unroll
    for (int n=0;n<NSTATE;n+=2){
      h[n]   = fmaf(dA[n],   h[n],   dx*Bv[n]);
      h[n+1] = fmaf(dA[n+1], h[n+1], dx*Bv[n+1]);
      acc0 = fmaf(h[n],   Cv[n],   acc0);
      acc1 = fmaf(h[n+1], Cv[n+1], acc1);
    }
    float acc = acc0 + acc1;
    int src = dir ? (1023 - lidx) : lidx;
    float zz = xz[((size_t)(b<<10) + src)*2048 + 1024 + d];
    float sg = zz / (1.f + __expf(-zz));
    yo[(size_t)dir*(2u<<20) + ((size_t)r<<10) + d] = f2bf((acc + Dd*x) * sg);
  }
}

extern "C" void kernel_launch(void* const* d_in, const int* in_sizes, int n_in,
                              void* d_out, int out_size, void* d_ws, size_t ws_size,
                              hipStream_t stream)
{
  if (n_in < 37) return;
  static const unsigned int SZ[37] = {
    1048576,1048576,786432,1536,262144,512,786432,1536,262144,512,
    512,512,512,512,1048576,2048,1048576,512,512,512,
    512,512,1048576,2048,1048576,512,1048576,2048,4096,1024,
    65536,32768,1024,16384,1024,524288,512
  };
  static const unsigned char ISW[37] = {
    0,0,1,0,1,0,1,0,1,0, 0,0,0,0,1,0,1,0,0,0,
    0,0,1,0,1,0,1,0,0,0, 1,1,0,0,0,1,0
  };
  const long long MF = 1u<<20;
  if (ws_size < (size_t)(32*MF)*sizeof(float)) return;   // 128 MB

  float* ws = (float*)d_ws;
  float* inF = ws;                       // fp32 params arena  [0, 3MF)
  bf16*  inB = (bf16*)(ws + 3*MF);       // bf16 weight arena  [3MF, 7MF)
  float* t2    = ws + 7*MF;
  float* mbuf  = ws + 8*MF;
  float* proj  = ws + 9*MF;              // 3MF
  float* big   = ws + 12*MF;             // 16MF
  float* ff1   = ws + 28*MF;             // 2MF (bf16 4M els; ybf/ff1B)

  CvtTabF tf; CvtTabW tb;
  unsigned int fOff[37], bOff[37];
  {
    int nf=0, nb=0; unsigned int of=0, ob=0;
    for (int i=0;i<37;++i){
      if (ISW[i]){ tb.src[nb]=d_in[i]; tb.off[nb]=ob; bOff[i]=ob; ob+=SZ[i]; ++nb; }
      else       { tf.src[nf]=d_in[i]; tf.off[nf]=of; fOff[i]=of; of+=SZ[i]; ++nf; }
    }
    tf.off[25]=of; tb.off[12]=ob;
    int* flag = (int*)(ws + 3*MF - 16);

    #define PF(i) (inF + fOff[i])
    #define PW(i) (inB + bOff[i])

    float* tgt_f = PF(0);
    float* mem_f = PF(1);
    bf16* qkvB   = (bf16*)proj;          // 3M els
    bf16* qB     = (bf16*)proj;          // 1M els (CA)
    bf16* kvB    = (bf16*)(proj + 1*MF); // 2M els (CA)
    bf16* attnoB = (bf16*)mbuf;          // 1M els
    bf16* xnB    = (bf16*)t2;            // 1M els
    // attention phase (big):
    bf16*  OpartB  = (bf16*)big;            // 8M els = 4MF
    float* Ml      = big + 4*MF;            // 256K floats
    float* Mfin    = big + 4*MF + 262144;   // 32K
    float* tpart   = big + 5*MF;            // 2 partials x 1MF
    // mamba phase (big):
    float* xz      = big;                   // 4MF
    bf16*  xmc_f   = (bf16*)(big + 4*MF);   // 2M els
    bf16*  xmc_b   = (bf16*)(big + 5*MF);
    bf16*  delta_f = (bf16*)(big + 6*MF);
    bf16*  delta_b = (bf16*)(big + 7*MF);
    float* hend    = big + 8*MF;            // 4MF
    float* Sdl     = big + 12*MF;           // 256K
    float* dbc_f   = proj;
    float* dbc_b   = proj + 131072;
    float* ffop    = big;                   // 4 partials x 1MF (after xz dead)
    float* lin2p   = big + 4*MF;            // 4 partials x 1MF
    float* yprojp  = big + 8*MF;            // 4 partials x 1MF (after hend dead)
    bf16*  ybf     = (bf16*)ff1;            // 4M els
    bf16*  ff1B    = (bf16*)ff1;
    bf16*  mbufB   = (bf16*)mbuf;

    k_cvt<<<4096,256,0,stream>>>(tf, tb, (const unsigned int*)d_in[0], inF, inB, flag,
                                 (int)(of>>2), (int)(ob>>2));

    // ---- self attention ----
    k_gemm64<<<dim3(24,32),256,0,stream>>>(tgt_f,0,512, PW(2),512, qkvB,1,1536, PF(3),0,512);
    k_flash2<<<dim3(16,16,8),256,0,stream>>>(qkvB,1536,0, qkvB,1536,512, qkvB,1536,1024, OpartB, Ml, 0.125f);
    k_fcomb<<<4096,256,0,stream>>>(OpartB, Ml, attnoB, Mfin);
    k_skp64<<<dim3(8,32,2),256,0,stream>>>(attnoB,1,0,512, PW(4),512, tpart,MF,512, PF(5), 512, 2);
    k_add_rmsnorm<<<2048,256,0,stream>>>(tgt_f, tpart, MF, 2, PF(10));

    // ---- cross attention ----
    k_mfma_gemm<<<dim3(8,32,1),256,0,stream>>>(tgt_f,0,0,0,512, PW(6),0,0,512,2, qB,1,0,0,512, PF(7),1.f,0,512,1);
    k_mfma_gemm<<<dim3(16,32,1),256,0,stream>>>(mem_f,0,0,0,512, PW(6)+(size_t)512*512,0,0,512,2, kvB,1,0,0,1024, PF(7)+512,1.f,0,512,1);
    k_flash2<<<dim3(16,16,8),256,0,stream>>>(qB,512,0, kvB,1024,0, kvB,1024,512, OpartB, Ml, 0.125f);
    k_fcomb<<<4096,256,0,stream>>>(OpartB, Ml, attnoB, Mfin);
    k_pmean<<<dim3(16,16,2),256,0,stream>>>(qB,512, kvB,1024, Mfin, d_out, flag, 0.125f);
    k_skp64<<<dim3(8,32,2),256,0,stream>>>(attnoB,1,0,512, PW(8),512, tpart,MF,512, PF(9), 512, 2);
    k_rms_ln<<<2048,256,0,stream>>>(tgt_f, tpart, MF, PF(11), PF(18), PF(19), xnB);

    // ---- bimamba ----
    k_gemm64<<<dim3(32,32),256,0,stream>>>(xnB,1,512, PW(26),512, xz,0,2048, PF(27),0,512);
    k_conv_silu<<<dim3(8192,2),256,0,stream>>>(xz, PF(28), PF(29), xmc_f, dbc_f);
    k_gemm_sk<<<dim3(1,32,8),256,0,stream>>>(xmc_f,1,2*MF,1024, PW(30),1024, dbc_f,131072,64, nullptr, 1024, 4);
    k_mfma_gemm<<<dim3(16,32,2),256,0,stream>>>(dbc_f,0,131072,0,64, PW(31),0,0,32,2, delta_f,1,2*MF,0,1024, PF(32),1.f,3,32,1);
    k_scan1<<<dim3(16,64),256,0,stream>>>(delta_f,delta_b,xmc_f,xmc_b,dbc_f,dbc_b, PF(33), hend, Sdl);
    k_scan_carry<<<256,256,0,stream>>>(PF(33), hend, Sdl);
    k_scan2<<<dim3(16,64),256,0,stream>>>(delta_f,delta_b,xmc_f,xmc_b,dbc_f,dbc_b, PF(33), hend, xz, PF(34), ybf);
    k_skp64<<<dim3(8,32,4),256,0,stream>>>(ybf,1,2*MF,1024, PW(35),1024, yprojp,MF,512, PF(36), 1024, 2);
    k_combine_ln<<<2048,256,0,stream>>>(yprojp, MF, PF(20), PF(21), mbufB);
    k_gemm64<<<dim3(32,32),256,0,stream>>>(mbufB,1,512, PW(22),512, ff1B,1,2048, PF(23),2,512);
    k_skp64<<<dim3(8,32,4),256,0,stream>>>(ff1B,1,0,2048, PW(24),2048, ffop,MF,512, PF(25), 2048, 4);
    k_bimamba_final<<<2048,256,0,stream>>>(tgt_f, ffop, MF, PF(12));

    // ---- final FFN ----
    k_gemm64<<<dim3(32,32),256,0,stream>>>(tgt_f,0,512, PW(14),512, ff1B,1,2048, PF(15),1,512);
    k_skp64<<<dim3(8,32,4),256,0,stream>>>(ff1B,1,0,2048, PW(16),2048, lin2p,MF,512, PF(17), 2048, 4);
    k_add_rmsnorm_out<<<2048,256,0,stream>>>(tgt_f, lin2p, MF, 4, PF(13), d_out, flag);
    #undef PF
    #undef PW
  }
}

// Round 13
// 510.864 us; speedup vs baseline: 1.1393x; 1.0182x over previous
//
#include <hip/hip_runtime.h>
#include <hip/hip_bf16.h>
#include <math.h>

#define L_SEQ 1024
#define BB 2
#define DD 512
#define HH 8
#define DFFN 2048
#define NSTATE 16
#define DI 1024
#define EPSF 1e-5f

typedef __hip_bfloat16 bf16;
typedef __attribute__((ext_vector_type(8))) short short8v;
typedef __attribute__((ext_vector_type(4))) short short4v;
typedef __attribute__((ext_vector_type(4))) float float4v;

__device__ __forceinline__ float bf2f(bf16 v){ return __bfloat162float(v); }
__device__ __forceinline__ bf16 f2bf(float v){ return __float2bfloat16(v); }
__device__ __forceinline__ short f2bfs(float v){
  bf16 t = __float2bfloat16(v);
  short s; __builtin_memcpy(&s, &t, 2);
  return s;
}
__device__ __forceinline__ float s2f(short s){
  union{unsigned int i; float f;} c; c.i = ((unsigned int)(unsigned short)s) << 16; return c.f;
}

// dA[n] = q^(n+1) via binary powers
__device__ __forceinline__ void powtab(float q1, float* dA){
  float q2=q1*q1, q4=q2*q2, q8=q4*q4;
  dA[0]=q1;       dA[1]=q2;       dA[2]=q2*q1;     dA[3]=q4;
  dA[4]=q4*q1;    dA[5]=q4*q2;    dA[6]=q4*q2*q1;  dA[7]=q8;
  dA[8]=q8*q1;    dA[9]=q8*q2;    dA[10]=q8*q2*q1; dA[11]=q8*q4;
  dA[12]=q8*q4*q1;dA[13]=q8*q4*q2;dA[14]=q8*q4*q2*q1;dA[15]=q8*q8;
}

// ---------------- fused convert + dtype detect (4-wide vectorized) ----------------
struct CvtTabF { const void* src[25]; unsigned int off[26]; };
struct CvtTabW { const void* src[12]; unsigned int off[13]; };

__global__ __launch_bounds__(256) void k_cvt(CvtTabF tf, CvtTabW tb,
                                             const unsigned int* __restrict__ w0,
                                             float* __restrict__ dstF, bf16* __restrict__ dstB,
                                             int* __restrict__ flag, int totF4, int totB4){
  __shared__ int cnt;
  if (threadIdx.x==0) cnt = 0;
  __syncthreads();
  {
    unsigned int x = w0[threadIdx.x];
    unsigned int low = x & 0xffffu;
    int e = (int)((low >> 7) & 0xffu);
    int vote = (low==0u) || (e >= 110 && e <= 140);
    atomicAdd(&cnt, vote);
  }
  __syncthreads();
  const int isbf = (cnt >= 128) ? 1 : 0;      // 1 = bf16 inputs, 0 = fp32
  if (blockIdx.x==0 && threadIdx.x==0) flag[0] = isbf;
  const int tot4 = totF4 + totB4;
  for (int g4 = blockIdx.x*256 + threadIdx.x; g4 < tot4; g4 += gridDim.x*256){
    if (g4 < totF4){
      int g = g4 << 2;
      int k = 0;
      while (tf.off[k+1] <= (unsigned int)g) ++k;
      int e = g - (int)tf.off[k];
      float4 o;
      if (isbf){
        short4v s = *(const short4v*)((const bf16*)tf.src[k] + e);
        o.x=s2f(s.x); o.y=s2f(s.y); o.z=s2f(s.z); o.w=s2f(s.w);
      } else {
        o = *(const float4*)((const float*)tf.src[k] + e);
      }
      *(float4*)(dstF + g) = o;
    } else {
      int g = (g4 - totF4) << 2;
      int k = 0;
      while (tb.off[k+1] <= (unsigned int)g) ++k;
      int e = g - (int)tb.off[k];
      short4v s;
      if (isbf){
        s = *(const short4v*)((const bf16*)tb.src[k] + e);
      } else {
        float4 v = *(const float4*)((const float*)tb.src[k] + e);
        s.x=f2bfs(v.x); s.y=f2bfs(v.y); s.z=f2bfs(v.z); s.w=f2bfs(v.w);
      }
      *(short4v*)((short*)dstB + g) = s;
    }
  }
}

// ---------------- 64-tile batched MFMA GEMM (BK=32; used for dt) ----------------
__global__ __launch_bounds__(256) void k_mfma_gemm(
    const void* __restrict__ Ab, int cA, long long sAb, long long sAh, long long sAm,
    const void* __restrict__ Bb, long long sBb, long long sBh, long long sBrow, int cB,
    void* __restrict__ Cb, int outBf, long long sCb, long long sCh, long long sCm,
    const float* __restrict__ bias, float scale, int act, int K, int H)
{
  __shared__ short As[64*40];
  __shared__ short Bs[64*40];
  const int tid = threadIdx.x;
  int bx = blockIdx.x, by = blockIdx.y;
  if (gridDim.z == 1 && (gridDim.y & 7) == 0){
    int gx = gridDim.x;
    int lin = by*gx + bx;
    int xcd = lin & 7, i = lin >> 3;
    by = xcd*(gridDim.y >> 3) + i / gx;
    bx = i % gx;
  }
  const int z = blockIdx.z; const int zb = z / H; const int zh = z % H;
  const int col0 = bx << 6, m0 = by << 6;
  const float* Af = (const float*)Ab;
  const bf16*  Aw = (const bf16*)Ab;
  const long long aoff = zb*sAb + zh*sAh;
  const float* Bf = (const float*)Bb;
  const bf16* Bw = (const bf16*)Bb;
  const long long boff = zb*sBb + zh*sBh;
  float4v acc[4];
  #pragma unroll
  for (int i=0;i<4;++i) acc[i] = (float4v)(0.f);
  const int lane = tid & 63, w = tid >> 6;
  const int lr = lane & 15, quad = lane >> 4;

  for (int k0 = 0; k0 < K; k0 += 32){
    if (cA == 1){
      int row = tid >> 2, k8 = (tid & 3) << 3;
      short8v v = *(const short8v*)&Aw[aoff + (long long)(m0+row)*sAm + k0 + k8];
      *(short8v*)&As[row*40 + k8] = v;
    } else {
      #pragma unroll
      for (int i=0;i<2;++i){
        int g = tid + i*256;
        int row = g >> 3, k4 = (g & 7) << 2;
        float4 v = *(const float4*)&Af[aoff + (long long)(m0+row)*sAm + k0 + k4];
        short4v s4; s4.x=f2bfs(v.x); s4.y=f2bfs(v.y); s4.z=f2bfs(v.z); s4.w=f2bfs(v.w);
        *(short4v*)&As[row*40 + k4] = s4;
      }
    }
    if (cB == 2){
      int row = tid >> 2, k8 = (tid & 3) << 3;
      short8v v = *(const short8v*)&Bw[boff + (long long)(col0+row)*sBrow + k0 + k8];
      *(short8v*)&Bs[row*40 + k8] = v;
    } else {
      #pragma unroll
      for (int i=0;i<2;++i){
        int g = tid + i*256;
        int row = g >> 3, k4 = (g & 7) << 2;
        float4 v = *(const float4*)&Bf[boff + (long long)(col0+row)*sBrow + k0 + k4];
        short4v s4; s4.x=f2bfs(v.x); s4.y=f2bfs(v.y); s4.z=f2bfs(v.z); s4.w=f2bfs(v.w);
        *(short4v*)&Bs[row*40 + k4] = s4;
      }
    }
    __syncthreads();
    short8v a = *(short8v*)&As[(w*16 + lr)*40 + quad*8];
    #pragma unroll
    for (int cb=0; cb<4; ++cb){
      short8v bfr = *(short8v*)&Bs[(cb*16 + lr)*40 + quad*8];
      acc[cb] = __builtin_amdgcn_mfma_f32_16x16x32_bf16(a, bfr, acc[cb], 0, 0, 0);
    }
    __syncthreads();
  }
  #pragma unroll
  for (int cb=0; cb<4; ++cb){
    #pragma unroll
    for (int r=0;r<4;++r){
      int m = m0 + w*16 + quad*4 + r;
      int n = col0 + cb*16 + lr;
      float v = acc[cb][r] * scale;
      if (bias) v += bias[n];
      if (act==1) v = fmaxf(v,0.f);
      else if (act==2) v = 0.5f*v*(1.f + erff(v*0.70710678118654752f));
      else if (act==3) v = fmaxf(v,0.f) + log1pf(__expf(-fabsf(v)));
      if (outBf) ((bf16*)Cb)[zb*sCb + zh*sCh + (long long)m*sCm + n] = f2bf(v);
      else       ((float*)Cb)[zb*sCb + zh*sCh + (long long)m*sCm + n] = v;
    }
  }
}

// ---------------- 64x64 tile, BK=64 GEMM (8 MFMA/wave per barrier pair) ----------------
__global__ __launch_bounds__(256) void k_gemm64(
    const void* __restrict__ Ab, int cA, long long sAm,
    const bf16* __restrict__ Bw, long long sBrow,
    void* __restrict__ Cb, int outBf, long long sCm,
    const float* __restrict__ bias, int act, int K)
{
  __shared__ short As[64*72];
  __shared__ short Bs[64*72];
  const int tid = threadIdx.x;
  int bx = blockIdx.x, by = blockIdx.y;
  {
    int gx = gridDim.x;
    int lin = by*gx + bx;
    int xcd = lin & 7, i = lin >> 3;
    by = xcd*(gridDim.y >> 3) + i / gx;
    bx = i % gx;
  }
  const int col0 = bx << 6, m0 = by << 6;
  const float* Af = (const float*)Ab;
  const bf16*  Aw = (const bf16*)Ab;
  const int lane = tid & 63, w = tid >> 6;
  const int lr = lane & 15, quad = lane >> 4;
  float4v acc[4];
  #pragma unroll
  for (int i=0;i<4;++i) acc[i] = (float4v)(0.f);

  for (int k0 = 0; k0 < K; k0 += 64){
    if (cA == 1){
      #pragma unroll
      for (int i=0;i<2;++i){
        int idx = tid + i*256;
        int row = idx >> 3, k8 = (idx & 7) << 3;
        *(short8v*)&As[row*72 + k8] =
          *(const short8v*)&Aw[(long long)(m0+row)*sAm + k0 + k8];
      }
    } else {
      #pragma unroll
      for (int i=0;i<4;++i){
        int g = tid + i*256;
        int row = g >> 4, k4 = (g & 15) << 2;
        float4 v = *(const float4*)&Af[(long long)(m0+row)*sAm + k0 + k4];
        short4v s4; s4.x=f2bfs(v.x); s4.y=f2bfs(v.y); s4.z=f2bfs(v.z); s4.w=f2bfs(v.w);
        *(short4v*)&As[row*72 + k4] = s4;
      }
    }
    #pragma unroll
    for (int i=0;i<2;++i){
      int idx = tid + i*256;
      int row = idx >> 3, k8 = (idx & 7) << 3;
      *(short8v*)&Bs[row*72 + k8] =
        *(const short8v*)&Bw[(long long)(col0+row)*sBrow + k0 + k8];
    }
    __syncthreads();
    #pragma unroll
    for (int kk=0; kk<64; kk+=32){
      short8v a = *(short8v*)&As[(w*16 + lr)*72 + kk + quad*8];
      #pragma unroll
      for (int cb=0; cb<4; ++cb){
        short8v bfr = *(short8v*)&Bs[(cb*16 + lr)*72 + kk + quad*8];
        acc[cb] = __builtin_amdgcn_mfma_f32_16x16x32_bf16(a, bfr, acc[cb], 0, 0, 0);
      }
    }
    __syncthreads();
  }
  #pragma unroll
  for (int cb=0; cb<4; ++cb){
    #pragma unroll
    for (int r=0;r<4;++r){
      int m = m0 + w*16 + quad*4 + r;
      int n = col0 + cb*16 + lr;
      float v = acc[cb][r];
      if (bias) v += bias[n];
      if (act==1) v = fmaxf(v,0.f);
      else if (act==2) v = 0.5f*v*(1.f + erff(v*0.70710678118654752f));
      if (outBf) ((bf16*)Cb)[(long long)m*sCm + n] = f2bf(v);
      else       ((float*)Cb)[(long long)m*sCm + n] = v;
    }
  }
}

// ---------------- split-K BK=64 GEMM -> separate partial buffers ----------------
__global__ __launch_bounds__(256) void k_skp64(
    const void* __restrict__ Ab, int cA, long long sAz, long long sAm,
    const bf16* __restrict__ Bw, long long sBrow,
    float* __restrict__ Cp, long long sCp, long long sCm,
    const float* __restrict__ bias, int K, int KS)
{
  __shared__ short As[64*72];
  __shared__ short Bs[64*72];
  const int tid = threadIdx.x;
  int bx, by, bz;
  {
    int gx = gridDim.x, gy = gridDim.y, gz = gridDim.z;
    int lin = ((int)blockIdx.z*gy + blockIdx.y)*gx + blockIdx.x;
    int xcd = lin & 7, i = lin >> 3;
    bx = i % gx; int rest = i / gx;
    int pair = xcd * ((gy*gz) >> 3) + rest;
    by = pair % gy; bz = pair / gy;
  }
  const int zb = bz / KS, kc = bz % KS;
  const int Kc = K / KS;
  const int col0 = bx << 6, m0 = by << 6;
  const float* Af = (const float*)Ab;
  const bf16*  Aw = (const bf16*)Ab;
  const long long aoff = (long long)zb*sAz;
  float4v acc[4];
  #pragma unroll
  for (int i=0;i<4;++i) acc[i] = (float4v)(0.f);
  const int lane = tid & 63, w = tid >> 6;
  const int lr = lane & 15, quad = lane >> 4;

  const int kbeg = kc*Kc;
  for (int k0 = kbeg; k0 < kbeg + Kc; k0 += 64){
    if (cA == 1){
      #pragma unroll
      for (int i=0;i<2;++i){
        int idx = tid + i*256;
        int row = idx >> 3, k8 = (idx & 7) << 3;
        *(short8v*)&As[row*72 + k8] =
          *(const short8v*)&Aw[aoff + (long long)(m0+row)*sAm + k0 + k8];
      }
    } else {
      #pragma unroll
      for (int i=0;i<4;++i){
        int g = tid + i*256;
        int row = g >> 4, k4 = (g & 15) << 2;
        float4 v = *(const float4*)&Af[aoff + (long long)(m0+row)*sAm + k0 + k4];
        short4v s4; s4.x=f2bfs(v.x); s4.y=f2bfs(v.y); s4.z=f2bfs(v.z); s4.w=f2bfs(v.w);
        *(short4v*)&As[row*72 + k4] = s4;
      }
    }
    #pragma unroll
    for (int i=0;i<2;++i){
      int idx = tid + i*256;
      int row = idx >> 3, k8 = (idx & 7) << 3;
      *(short8v*)&Bs[row*72 + k8] =
        *(const short8v*)&Bw[(long long)(col0+row)*sBrow + k0 + k8];
    }
    __syncthreads();
    #pragma unroll
    for (int kk=0; kk<64; kk+=32){
      short8v a = *(short8v*)&As[(w*16 + lr)*72 + kk + quad*8];
      #pragma unroll
      for (int cb=0; cb<4; ++cb){
        short8v bfr = *(short8v*)&Bs[(cb*16 + lr)*72 + kk + quad*8];
        acc[cb] = __builtin_amdgcn_mfma_f32_16x16x32_bf16(a, bfr, acc[cb], 0, 0, 0);
      }
    }
    __syncthreads();
  }
  #pragma unroll
  for (int cb=0; cb<4; ++cb){
    #pragma unroll
    for (int r=0;r<4;++r){
      int m = m0 + w*16 + quad*4 + r;
      int n = col0 + cb*16 + lr;
      float v = acc[cb][r];
      if (kc == 0 && bias) v += bias[n];
      Cp[(long long)bz*sCp + (long long)m*sCm + n] = v;
    }
  }
}

// ---------------- split-K atomic GEMM (xproj only; dbc pre-zeroed by conv) ----------------
__global__ __launch_bounds__(256) void k_gemm_sk(
    const void* __restrict__ Ab, int cA, long long sAz, long long sAm,
    const bf16* __restrict__ Bw, long long sBrow,
    float* __restrict__ Cb, long long sCz, long long sCm,
    const float* __restrict__ bias, int K, int KS)
{
  __shared__ short As[64*40];
  __shared__ short Bs[64*40];
  const int tid = threadIdx.x;
  int bx, by, bz;
  {
    int gx = gridDim.x, gy = gridDim.y, gz = gridDim.z;
    int lin = ((int)blockIdx.z*gy + blockIdx.y)*gx + blockIdx.x;
    int xcd = lin & 7, i = lin >> 3;
    bx = i % gx; int rest = i / gx;
    int pair = xcd * ((gy*gz) >> 3) + rest;
    by = pair % gy; bz = pair / gy;
  }
  const int zb = bz / KS, kc = bz % KS;
  const int Kc = K / KS;
  const int col0 = bx << 6, m0 = by << 6;
  const bf16*  Aw = (const bf16*)Ab;
  const float* Af = (const float*)Ab;
  const long long aoff = (long long)zb*sAz;
  float4v acc[4];
  #pragma unroll
  for (int i=0;i<4;++i) acc[i] = (float4v)(0.f);
  const int lane = tid & 63, w = tid >> 6;
  const int lr = lane & 15, quad = lane >> 4;

  const int kbeg = kc*Kc;
  for (int k0 = kbeg; k0 < kbeg + Kc; k0 += 32){
    if (cA == 1){
      int row = tid >> 2, k8 = (tid & 3) << 3;
      *(short8v*)&As[row*40 + k8] =
        *(const short8v*)&Aw[aoff + (long long)(m0+row)*sAm + k0 + k8];
    } else {
      #pragma unroll
      for (int i=0;i<2;++i){
        int g = tid + i*256;
        int row = g >> 3, k4 = (g & 7) << 2;
        float4 v = *(const float4*)&Af[aoff + (long long)(m0+row)*sAm + k0 + k4];
        short4v s4; s4.x=f2bfs(v.x); s4.y=f2bfs(v.y); s4.z=f2bfs(v.z); s4.w=f2bfs(v.w);
        *(short4v*)&As[row*40 + k4] = s4;
      }
    }
    {
      int row = tid >> 2, k8 = (tid & 3) << 3;
      *(short8v*)&Bs[row*40 + k8] =
        *(const short8v*)&Bw[(long long)(col0+row)*sBrow + k0 + k8];
    }
    __syncthreads();
    short8v a = *(short8v*)&As[(w*16 + lr)*40 + quad*8];
    #pragma unroll
    for (int cb=0; cb<4; ++cb){
      short8v bfr = *(short8v*)&Bs[(cb*16 + lr)*40 + quad*8];
      acc[cb] = __builtin_amdgcn_mfma_f32_16x16x32_bf16(a, bfr, acc[cb], 0, 0, 0);
    }
    __syncthreads();
  }
  #pragma unroll
  for (int cb=0; cb<4; ++cb){
    #pragma unroll
    for (int r=0;r<4;++r){
      int m = m0 + w*16 + quad*4 + r;
      int n = col0 + cb*16 + lr;
      float v = acc[cb][r];
      if (kc == 0 && bias) v += bias[n];
      atomicAdd(&Cb[(long long)zb*sCz + (long long)m*sCm + n], v);
    }
  }
}

// ---------------- flash attention, split-K partials (8 chunks of 128 kpos), bf16 Opart ----------------
__global__ __launch_bounds__(256) void k_flash2(
    const bf16* __restrict__ Qb, int ldq, int qoff,
    const bf16* __restrict__ Kb, int ldk, int koff,
    const bf16* __restrict__ Vb, int ldv, int voff,
    bf16* __restrict__ Opart, float* __restrict__ Ml, float scale)
{
  __shared__ short Qs[64*40];
  __shared__ short Ks[64*40];
  __shared__ short Vs[64*40];
  __shared__ short Ps[64*40];
  const int tid = threadIdx.x;
  const int q0 = blockIdx.x << 6;
  const int z = blockIdx.y; const int b = z >> 3; const int hoff = (z & 7) << 6;
  const int kc = blockIdx.z;
  const int lane = tid & 63, w = tid >> 6;
  const int lr = lane & 15, quad = lane >> 4;

  #pragma unroll
  for (int i=0;i<2;++i){
    int idx = tid + i*256;
    int row = idx >> 3, d8 = (idx & 7) << 3;
    *(short8v*)&Qs[row*40 + d8] =
      *(const short8v*)&Qb[(size_t)((q0+row)*BB + b)*ldq + qoff + hoff + d8];
  }

  float m_r[4], l_r[4];
  #pragma unroll
  for (int r=0;r<4;++r){ m_r[r] = -1e30f; l_r[r] = 0.f; }
  float4v acc_o[4];
  #pragma unroll
  for (int cb=0;cb<4;++cb) acc_o[cb] = (float4v)(0.f);

  short8v kr[2], vr[2];
  #pragma unroll
  for (int i=0;i<2;++i){
    int idx = tid + i*256;
    int row = kc*128 + (idx >> 3); int d8 = (idx & 7) << 3;
    kr[i] = *(const short8v*)&Kb[(size_t)(row*BB + b)*ldk + koff + hoff + d8];
    vr[i] = *(const short8v*)&Vb[(size_t)(row*BB + b)*ldv + voff + hoff + d8];
  }

  for (int kt=0; kt<2; ++kt){
    __syncthreads();
    #pragma unroll
    for (int i=0;i<2;++i){
      int idx = tid + i*256;
      int row = idx >> 3, d8 = (idx & 7) << 3;
      *(short8v*)&Ks[row*40 + d8] = kr[i];
      int sc = row ^ d8;
      #pragma unroll
      for (int j=0;j<8;++j) Vs[(d8+j)*40 + sc] = vr[i][j];
    }
    if (kt < 1){
      #pragma unroll
      for (int i=0;i<2;++i){
        int idx = tid + i*256;
        int row = kc*128 + 64 + (idx >> 3); int d8 = (idx & 7) << 3;
        kr[i] = *(const short8v*)&Kb[(size_t)(row*BB + b)*ldk + koff + hoff + d8];
        vr[i] = *(const short8v*)&Vb[(size_t)(row*BB + b)*ldv + voff + hoff + d8];
      }
    }
    __syncthreads();
    short8v a0 = *(short8v*)&Qs[(w*16+lr)*40 + quad*8];
    short8v a1 = *(short8v*)&Qs[(w*16+lr)*40 + quad*8 + 32];
    float4v s[4];
    #pragma unroll
    for (int cb=0;cb<4;++cb){
      short8v b0 = *(short8v*)&Ks[(cb*16+lr)*40 + quad*8];
      short8v b1 = *(short8v*)&Ks[(cb*16+lr)*40 + quad*8 + 32];
      float4v t = __builtin_amdgcn_mfma_f32_16x16x32_bf16(a0, b0, (float4v)(0.f), 0,0,0);
      s[cb] = __builtin_amdgcn_mfma_f32_16x16x32_bf16(a1, b1, t, 0,0,0);
    }
    #pragma unroll
    for (int cb=0;cb<4;++cb)
      #pragma unroll
      for (int r=0;r<4;++r) s[cb][r] *= scale;
    float al[4];
    #pragma unroll
    for (int r=0;r<4;++r){
      float mx = fmaxf(fmaxf(s[0][r],s[1][r]),fmaxf(s[2][r],s[3][r]));
      #pragma unroll
      for (int ofs=1; ofs<16; ofs<<=1) mx = fmaxf(mx, __shfl_xor(mx, ofs));
      float mnew = fmaxf(m_r[r], mx);
      al[r] = __expf(m_r[r] - mnew);
      float sum = 0.f;
      #pragma unroll
      for (int cb=0;cb<4;++cb){
        float p = __expf(s[cb][r] - mnew);
        s[cb][r] = p;
        sum += p;
      }
      #pragma unroll
      for (int ofs=1; ofs<16; ofs<<=1) sum += __shfl_xor(sum, ofs);
      l_r[r] = l_r[r]*al[r] + sum;
      m_r[r] = mnew;
    }
    #pragma unroll
    for (int cb=0;cb<4;++cb)
      #pragma unroll
      for (int r=0;r<4;++r){
        acc_o[cb][r] *= al[r];
        Ps[(w*16 + quad*4 + r)*40 + cb*16 + lr] = f2bfs(s[cb][r]);
      }
    __syncthreads();
    short8v p0 = *(short8v*)&Ps[(w*16+lr)*40 + quad*8];
    short8v p1 = *(short8v*)&Ps[(w*16+lr)*40 + quad*8 + 32];
    #pragma unroll
    for (int cb=0;cb<4;++cb){
      int dcol = cb*16 + lr;
      int sw = (dcol >> 3) & 7;
      short8v v0 = *(short8v*)&Vs[dcol*40 + ((quad ^ sw) << 3)];
      short8v v1 = *(short8v*)&Vs[dcol*40 + (((quad+4) ^ sw) << 3)];
      acc_o[cb] = __builtin_amdgcn_mfma_f32_16x16x32_bf16(p0, v0, acc_o[cb], 0,0,0);
      acc_o[cb] = __builtin_amdgcn_mfma_f32_16x16x32_bf16(p1, v1, acc_o[cb], 0,0,0);
    }
  }
  #pragma unroll
  for (int r=0;r<4;++r){
    int row = q0 + w*16 + quad*4 + r;
    size_t obase = ((size_t)(kc*16 + z)*1024 + row)*64;
    #pragma unroll
    for (int cb=0;cb<4;++cb)
      Opart[obase + cb*16 + lr] = f2bf(acc_o[cb][r]);
    if (lr == 0){
      size_t mi = ((size_t)kc*16384 + z*1024 + row)*2;
      Ml[mi] = m_r[r]; Ml[mi+1] = l_r[r];
    }
  }
}

// ---------------- combine 8 split-K partials (bf16 Opart) ----------------
__global__ __launch_bounds__(256) void k_fcomb(const bf16* __restrict__ Opart, const float* __restrict__ Ml,
                                               bf16* __restrict__ O, float* __restrict__ Mfin)
{
  int gid = blockIdx.x*256 + threadIdx.x;   // 1M
  int row = gid >> 6, d = gid & 63;
  int z = row >> 10, q = row & 1023;
  float m[8], l[8];
  #pragma unroll
  for (int kc=0;kc<8;++kc){
    size_t mi = ((size_t)kc*16384 + row)*2;
    m[kc] = Ml[mi]; l[kc] = Ml[mi+1];
  }
  float ms = -1e30f;
  #pragma unroll
  for (int kc=0;kc<8;++kc) ms = fmaxf(ms, m[kc]);
  float ls = 0.f, o = 0.f;
  #pragma unroll
  for (int kc=0;kc<8;++kc){
    float c = __expf(m[kc]-ms);
    ls += l[kc]*c;
    o  += bf2f(Opart[((size_t)kc*16384 + row)*64 + d]) * c;
  }
  o /= ls;
  int b = z >> 3, hoff = (z & 7) << 6;
  O[((size_t)q*BB + b)*512 + hoff + d] = f2bf(o);
  if (d == 0){ Mfin[(size_t)row*2] = ms; Mfin[(size_t)row*2+1] = ls; }
}

// ---------------- head-mean of P from Q,K + final m,l ----------------
__global__ __launch_bounds__(256) void k_pmean(
    const bf16* __restrict__ Qb, int ldq,
    const bf16* __restrict__ Kb, int ldk,
    const float* __restrict__ Mfin, void* __restrict__ out,
    const int* __restrict__ flag, float scale)
{
  __shared__ short Qs[64*40];
  __shared__ short Ks[64*40];
  const int tid = threadIdx.x;
  const int k0 = blockIdx.x << 6, q0 = blockIdx.y << 6;
  const int b = blockIdx.z;
  const int lane = tid & 63, w = tid >> 6;
  const int lr = lane & 15, quad = lane >> 4;
  float acc[4][4];
  #pragma unroll
  for (int cb=0;cb<4;++cb)
    #pragma unroll
    for (int r=0;r<4;++r) acc[cb][r] = 0.f;

  for (int h=0; h<8; ++h){
    int z = b*8 + h, hoff = h << 6;
    __syncthreads();
    #pragma unroll
    for (int i=0;i<2;++i){
      int idx = tid + i*256;
      int row = idx >> 3, d8 = (idx & 7) << 3;
      *(short8v*)&Qs[row*40 + d8] = *(const short8v*)&Qb[((size_t)(q0+row)*BB + b)*ldq + hoff + d8];
      *(short8v*)&Ks[row*40 + d8] = *(const short8v*)&Kb[((size_t)(k0+row)*BB + b)*ldk + hoff + d8];
    }
    __syncthreads();
    float mm[4], li[4];
    #pragma unroll
    for (int r=0;r<4;++r){
      int qrow = q0 + w*16 + quad*4 + r;
      size_t mi = ((size_t)z*1024 + qrow)*2;
      mm[r] = Mfin[mi]; li[r] = 1.f/Mfin[mi+1];
    }
    short8v a0 = *(short8v*)&Qs[(w*16+lr)*40 + quad*8];
    short8v a1 = *(short8v*)&Qs[(w*16+lr)*40 + quad*8 + 32];
    #pragma unroll
    for (int cb=0;cb<4;++cb){
      short8v b0 = *(short8v*)&Ks[(cb*16+lr)*40 + quad*8];
      short8v b1 = *(short8v*)&Ks[(cb*16+lr)*40 + quad*8 + 32];
      float4v t = __builtin_amdgcn_mfma_f32_16x16x32_bf16(a0, b0, (float4v)(0.f), 0,0,0);
      t = __builtin_amdgcn_mfma_f32_16x16x32_bf16(a1, b1, t, 0,0,0);
      #pragma unroll
      for (int r=0;r<4;++r)
        acc[cb][r] += __expf(t[r]*scale - mm[r]) * li[r];
    }
  }
  #pragma unroll
  for (int cb=0;cb<4;++cb)
    #pragma unroll
    for (int r=0;r<4;++r){
      int q = q0 + w*16 + quad*4 + r;
      int k = k0 + cb*16 + lr;
      float v = acc[cb][r] * 0.125f;
      size_t o = (size_t)(1u<<20) + ((size_t)b<<20) + (size_t)q*1024 + k;
      if (flag[0]) ((bf16*)out)[o] = f2bf(v);
      else         ((float*)out)[o] = v;
    }
}

// ---------------- norms (consume split-K partials) ----------------
__global__ __launch_bounds__(256) void k_add_rmsnorm(float* __restrict__ x, const float* __restrict__ tp,
                                                     long long pstr, int KS, const float* __restrict__ w){
  int row = blockIdx.x; size_t base = (size_t)row*DD;
  int tid = threadIdx.x;
  float v0 = x[base+tid], v1 = x[base+tid+256];
  for (int k=0;k<KS;++k){ v0 += tp[k*pstr + base+tid]; v1 += tp[k*pstr + base+tid+256]; }
  __shared__ float red[256];
  red[tid] = v0*v0 + v1*v1; __syncthreads();
  for (int s=128;s>0;s>>=1){ if(tid<s) red[tid]+=red[tid+s]; __syncthreads(); }
  float rms = rsqrtf(red[0]*(1.f/DD) + EPSF);
  x[base+tid]     = v0 * w[tid]     * rms;
  x[base+tid+256] = v1 * w[tid+256] * rms;
}

__global__ __launch_bounds__(256) void k_add_rmsnorm_out(const float* __restrict__ x, const float* __restrict__ tp,
                                                         long long pstr, int KS,
                                                         const float* __restrict__ w, void* __restrict__ out,
                                                         const int* __restrict__ flag){
  int row = blockIdx.x; size_t base = (size_t)row*DD;
  int tid = threadIdx.x;
  float v0 = x[base+tid], v1 = x[base+tid+256];
  for (int k=0;k<KS;++k){ v0 += tp[k*pstr + base+tid]; v1 += tp[k*pstr + base+tid+256]; }
  __shared__ float red[256];
  red[tid] = v0*v0 + v1*v1; __syncthreads();
  for (int s=128;s>0;s>>=1){ if(tid<s) red[tid]+=red[tid+s]; __syncthreads(); }
  float rms = rsqrtf(red[0]*(1.f/DD) + EPSF);
  float o0 = v0 * w[tid]     * rms;
  float o1 = v1 * w[tid+256] * rms;
  if (flag[0]){ ((bf16*)out)[base+tid] = f2bf(o0); ((bf16*)out)[base+tid+256] = f2bf(o1); }
  else        { ((float*)out)[base+tid] = o0;      ((float*)out)[base+tid+256] = o1; }
}

// fused: tgt = rmsnorm(tgt + sum tp, n2w); xn = layernorm(tgt, ln1) (bf16)
__global__ __launch_bounds__(256) void k_rms_ln(float* __restrict__ tgt, const float* __restrict__ tp,
                                                long long pstr, const float* __restrict__ n2w,
                                                const float* __restrict__ lw, const float* __restrict__ lb,
                                                bf16* __restrict__ xn){
  int r = blockIdx.x;
  int b = r >> 10, l = r & 1023;
  size_t base = ((size_t)l*BB + b)*DD;
  int tid = threadIdx.x;
  float v0 = tgt[base+tid] + tp[base+tid] + tp[pstr + base+tid];
  float v1 = tgt[base+tid+256] + tp[base+tid+256] + tp[pstr + base+tid+256];
  __shared__ float red[256];
  red[tid] = v0*v0 + v1*v1; __syncthreads();
  for (int s=128;s>0;s>>=1){ if(tid<s) red[tid]+=red[tid+s]; __syncthreads(); }
  float rms = rsqrtf(red[0]*(1.f/DD) + EPSF);
  v0 = v0 * n2w[tid]     * rms;
  v1 = v1 * n2w[tid+256] * rms;
  tgt[base+tid] = v0; tgt[base+tid+256] = v1;
  __syncthreads();
  red[tid] = v0 + v1; __syncthreads();
  for (int s=128;s>0;s>>=1){ if(tid<s) red[tid]+=red[tid+s]; __syncthreads(); }
  float mean = red[0]*(1.f/DD);
  __syncthreads();
  red[tid] = v0*v0 + v1*v1; __syncthreads();
  for (int s=128;s>0;s>>=1){ if(tid<s) red[tid]+=red[tid+s]; __syncthreads(); }
  float var = red[0]*(1.f/DD) - mean*mean;
  float rstd = rsqrtf(var + EPSF);
  size_t dst = (size_t)r*DD;
  xn[dst+tid]     = f2bf((v0-mean)*rstd*lw[tid]     + lb[tid]);
  xn[dst+tid+256] = f2bf((v1-mean)*rstd*lw[tid+256] + lb[tid+256]);
}

// combine_ln over yproj partials
__global__ __launch_bounds__(256) void k_combine_ln(const float* __restrict__ yp, long long pstr,
                                                    const float* __restrict__ w, const float* __restrict__ bias,
                                                    bf16* __restrict__ mo){
  int r = blockIdx.x; int b = r>>10, l = r&1023;
  size_t rf = (size_t)r*DD;
  size_t rb = ((size_t)(b<<10) + (1023 - l))*DD;
  int tid = threadIdx.x;
  float v0 = yp[rf+tid]     + yp[pstr + rf+tid]     + yp[2*pstr + rb+tid]     + yp[3*pstr + rb+tid];
  float v1 = yp[rf+tid+256] + yp[pstr + rf+tid+256] + yp[2*pstr + rb+tid+256] + yp[3*pstr + rb+tid+256];
  __shared__ float red[256];
  red[tid] = v0 + v1; __syncthreads();
  for (int s=128;s>0;s>>=1){ if(tid<s) red[tid]+=red[tid+s]; __syncthreads(); }
  float mean = red[0]*(1.f/DD);
  __syncthreads();
  red[tid] = v0*v0 + v1*v1; __syncthreads();
  for (int s=128;s>0;s>>=1){ if(tid<s) red[tid]+=red[tid+s]; __syncthreads(); }
  float var = red[0]*(1.f/DD) - mean*mean;
  float rstd = rsqrtf(var + EPSF);
  mo[rf+tid]     = f2bf((v0-mean)*rstd*w[tid]     + bias[tid]);
  mo[rf+tid+256] = f2bf((v1-mean)*rstd*w[tid+256] + bias[tid+256]);
}

__global__ __launch_bounds__(256) void k_bimamba_final(float* __restrict__ tgt, const float* __restrict__ fp,
                                                       long long pstr, const float* __restrict__ w){
  int r = blockIdx.x; int b = r>>10, l = r&1023;
  size_t t = ((size_t)l*BB + b)*DD;
  size_t f = (size_t)r*DD;
  int tid = threadIdx.x;
  float v0 = 2.f*tgt[t+tid], v1 = 2.f*tgt[t+tid+256];
  #pragma unroll
  for (int k=0;k<4;++k){ v0 += fp[k*pstr + f+tid]; v1 += fp[k*pstr + f+tid+256]; }
  __shared__ float red[256];
  red[tid] = v0*v0 + v1*v1; __syncthreads();
  for (int s=128;s>0;s>>=1){ if(tid<s) red[tid]+=red[tid+s]; __syncthreads(); }
  float rms = rsqrtf(red[0]*(1.f/DD) + EPSF);
  tgt[t+tid]     = v0 * w[tid]     * rms;
  tgt[t+tid+256] = v1 * w[tid+256] * rms;
}

// ---------------- causal depthwise conv + silu -> bf16 (+dbc zeroing) ----------------
__global__ __launch_bounds__(256) void k_conv_silu(const float* __restrict__ xz, const float* __restrict__ cw,
                                                   const float* __restrict__ cb, bf16* __restrict__ xmc,
                                                   float* __restrict__ dbcz){
  int rev = blockIdx.y;
  int idx = blockIdx.x*256 + threadIdx.x;  // 2M
  if (rev == 0 && blockIdx.x < 1024) dbcz[idx] = 0.f;   // zero 262144 dbc floats
  int c = idx & 1023;
  int l = (idx >> 10) & 1023;
  int b = idx >> 20;
  float acc = cb[c];
  float w4[4];
  #pragma unroll
  for (int j=0;j<4;++j) w4[j] = cw[(c<<2)+j];
  #pragma unroll
  for (int j=0;j<4;++j){
    int t = l - 3 + j;
    if (t >= 0){
      int src = rev ? (1023 - t) : t;
      acc = fmaf(w4[j], xz[((size_t)(b<<10) + src)*2048 + c], acc);
    }
  }
  xmc[(size_t)rev*(2u<<20) + idx] = f2bf(acc / (1.f + __expf(-acc)));
}

// ---------------- chunked selective scan: 64 chunks of 16 steps ----------------
__global__ __launch_bounds__(256) void k_scan1(
    const bf16* __restrict__ delta_f, const bf16* __restrict__ delta_b,
    const bf16* __restrict__ xmc_f,  const bf16* __restrict__ xmc_b,
    const float* __restrict__ dbc_f,  const float* __restrict__ dbc_b,
    const float* __restrict__ Alog,
    float* __restrict__ hend, float* __restrict__ Sdl)
{
  int ch = blockIdx.x*256 + threadIdx.x;
  int c = blockIdx.y;
  int dir = ch >> 11, b = (ch >> 10) & 1, d = ch & 1023;
  const bf16* delta = dir ? delta_b : delta_f;
  const bf16* xmc   = dir ? xmc_b   : xmc_f;
  const float* dbc  = dir ? dbc_b   : dbc_f;
  float Av[NSTATE]; bool fast = true;
  #pragma unroll
  for (int n=0;n<NSTATE;++n){
    Av[n] = -__expf(Alog[d*NSTATE+n]);
    fast = fast && (fabsf(Av[n] + (float)(n+1)) < 1e-4f*(float)(n+1));
  }
  float h[NSTATE];
  #pragma unroll
  for (int n=0;n<NSTATE;++n) h[n]=0.f;
  float S = 0.f;
  int r0 = b*1024 + c*16;
  for (int t=0;t<16;++t){
    int r = r0 + t;
    float dl = bf2f(delta[((size_t)r<<10) + d]);
    float x  = bf2f(xmc[((size_t)r<<10) + d]);
    const float4* bp = (const float4*)(dbc + (size_t)r*64 + 32);
    float Bv[NSTATE];
    ((float4*)Bv)[0]=bp[0]; ((float4*)Bv)[1]=bp[1]; ((float4*)Bv)[2]=bp[2]; ((float4*)Bv)[3]=bp[3];
    S += dl;
    float dx = dl*x;
    float dA[NSTATE];
    if (fast){ powtab(__expf(-dl), dA); }
    else {
      #pragma unroll
      for (int n=0;n<NSTATE;++n) dA[n] = __expf(dl*Av[n]);
    }
    #pragma unroll
    for (int n=0;n<NSTATE;++n)
      h[n] = fmaf(dA[n], h[n], dx*Bv[n]);
  }
  size_t base = ((size_t)c*4096 + ch)*16;
  #pragma unroll
  for (int n=0;n<NSTATE;++n) hend[base+n] = h[n];
  Sdl[c*4096 + ch] = S;
}

__global__ __launch_bounds__(256) void k_scan_carry(const float* __restrict__ Alog,
                                                    float* __restrict__ hh, const float* __restrict__ Sdl)
{
  int g = blockIdx.x*256 + threadIdx.x;   // 65536
  int ch = g >> 4, n = g & 15;
  int d = ch & 1023;
  float Av = -__expf(Alog[d*16+n]);
  float h = 0.f;
  for (int c=0;c<64;++c){
    size_t base = ((size_t)c*4096 + ch)*16 + n;
    float he = hh[base];
    hh[base] = h;
    h = fmaf(__expf(Av*Sdl[c*4096+ch]), h, he);
  }
}

__global__ __launch_bounds__(256) void k_scan2(
    const bf16* __restrict__ delta_f, const bf16* __restrict__ delta_b,
    const bf16* __restrict__ xmc_f,  const bf16* __restrict__ xmc_b,
    const float* __restrict__ dbc_f,  const float* __restrict__ dbc_b,
    const float* __restrict__ Alog,   const float* __restrict__ hin,
    const float* __restrict__ xz,     const float* __restrict__ Dp,
    bf16* __restrict__ yo)
{
  int ch = blockIdx.x*256 + threadIdx.x;
  int c = blockIdx.y;
  int dir = ch >> 11, b = (ch >> 10) & 1, d = ch & 1023;
  const bf16* delta = dir ? delta_b : delta_f;
  const bf16* xmc   = dir ? xmc_b   : xmc_f;
  const float* dbc  = dir ? dbc_b   : dbc_f;
  float Av[NSTATE]; bool fast = true;
  #pragma unroll
  for (int n=0;n<NSTATE;++n){
    Av[n] = -__expf(Alog[d*NSTATE+n]);
    fast = fast && (fabsf(Av[n] + (float)(n+1)) < 1e-4f*(float)(n+1));
  }
  float h[NSTATE];
  size_t cbase = ((size_t)c*4096 + ch)*16;
  #pragma unroll
  for (int n=0;n<NSTATE;++n) h[n] = hin[cbase+n];
  float Dd = Dp[d];
  int r0 = b*1024 + c*16;
  for (int t=0;t<16;++t){
    int r = r0 + t;
    int lidx = c*16 + t;
    float dl = bf2f(delta[((size_t)r<<10) + d]);
    float x  = bf2f(xmc[((size_t)r<<10) + d]);
    const float4* bp = (const float4*)(dbc + (size_t)r*64 + 32);
    float Bv[NSTATE], Cv[NSTATE];
    ((float4*)Bv)[0]=bp[0]; ((float4*)Bv)[1]=bp[1]; ((float4*)Bv)[2]=bp[2]; ((float4*)Bv)[3]=bp[3];
    ((float4*)Cv)[0]=bp[4]; ((float4*)Cv)[1]=bp[5]; ((float4*)Cv)[2]=bp[6]; ((float4*)Cv)[3]=bp[7];
    float dx = dl*x;
    float dA[NSTATE];
    if (fast){ powtab(__expf(-dl), dA); }
    else {
      #pragma unroll
      for (int n=0;n<NSTATE;++n) dA[n] = __expf(dl*Av[n]);
    }
    float acc0 = 0.f, acc1 = 0.f;
    #pragma unroll
    for (int n=0;n<NSTATE;n+=2){
      h[n]   = fmaf(dA[n],   h[n],   dx*Bv[n]);
      h[n+1] = fmaf(dA[n+1], h[n+1], dx*Bv[n+1]);
      acc0 = fmaf(h[n],   Cv[n],   acc0);
      acc1 = fmaf(h[n+1], Cv[n+1], acc1);
    }
    float acc = acc0 + acc1;
    int src = dir ? (1023 - lidx) : lidx;
    float zz = xz[((size_t)(b<<10) + src)*2048 + 1024 + d];
    float sg = zz / (1.f + __expf(-zz));
    yo[(size_t)dir*(2u<<20) + ((size_t)r<<10) + d] = f2bf((acc + Dd*x) * sg);
  }
}

extern "C" void kernel_launch(void* const* d_in, const int* in_sizes, int n_in,
                              void* d_out, int out_size, void* d_ws, size_t ws_size,
                              hipStream_t stream)
{
  if (n_in < 37) return;
  static const unsigned int SZ[37] = {
    1048576,1048576,786432,1536,262144,512,786432,1536,262144,512,
    512,512,512,512,1048576,2048,1048576,512,512,512,
    512,512,1048576,2048,1048576,512,1048576,2048,4096,1024,
    65536,32768,1024,16384,1024,524288,512
  };
  static const unsigned char ISW[37] = {
    0,0,1,0,1,0,1,0,1,0, 0,0,0,0,1,0,1,0,0,0,
    0,0,1,0,1,0,1,0,0,0, 1,1,0,0,0,1,0
  };
  const long long MF = 1u<<20;
  if (ws_size < (size_t)(32*MF)*sizeof(float)) return;   // 128 MB

  float* ws = (float*)d_ws;
  float* inF = ws;                       // fp32 params arena  [0, 3MF)
  bf16*  inB = (bf16*)(ws + 3*MF);       // bf16 weight arena  [3MF, 7MF)
  float* t2    = ws + 7*MF;
  float* mbuf  = ws + 8*MF;
  float* proj  = ws + 9*MF;              // 3MF
  float* big   = ws + 12*MF;             // 16MF
  float* ff1   = ws + 28*MF;             // 2MF (bf16 4M els; ybf/ff1B)

  CvtTabF tf; CvtTabW tb;
  unsigned int fOff[37], bOff[37];
  {
    int nf=0, nb=0; unsigned int of=0, ob=0;
    for (int i=0;i<37;++i){
      if (ISW[i]){ tb.src[nb]=d_in[i]; tb.off[nb]=ob; bOff[i]=ob; ob+=SZ[i]; ++nb; }
      else       { tf.src[nf]=d_in[i]; tf.off[nf]=of; fOff[i]=of; of+=SZ[i]; ++nf; }
    }
    tf.off[25]=of; tb.off[12]=ob;
    int* flag = (int*)(ws + 3*MF - 16);

    #define PF(i) (inF + fOff[i])
    #define PW(i) (inB + bOff[i])

    float* tgt_f = PF(0);
    float* mem_f = PF(1);
    bf16* qkvB   = (bf16*)proj;          // 3M els
    bf16* qB     = (bf16*)proj;          // 1M els (CA)
    bf16* kvB    = (bf16*)(proj + 1*MF); // 2M els (CA)
    bf16* attnoB = (bf16*)mbuf;          // 1M els
    bf16* xnB    = (bf16*)t2;            // 1M els
    // attention phase (big):
    bf16*  OpartB  = (bf16*)big;            // 8M els = 4MF
    float* Ml      = big + 4*MF;            // 256K floats
    float* Mfin    = big + 4*MF + 262144;   // 32K
    float* tpart   = big + 5*MF;            // 2 partials x 1MF
    // mamba phase (big):
    float* xz      = big;                   // 4MF
    bf16*  xmc_f   = (bf16*)(big + 4*MF);   // 2M els
    bf16*  xmc_b   = (bf16*)(big + 5*MF);
    bf16*  delta_f = (bf16*)(big + 6*MF);
    bf16*  delta_b = (bf16*)(big + 7*MF);
    float* hend    = big + 8*MF;            // 4MF
    float* Sdl     = big + 12*MF;           // 256K
    float* dbc_f   = proj;
    float* dbc_b   = proj + 131072;
    float* ffop    = big;                   // 4 partials x 1MF (after xz dead)
    float* lin2p   = big + 4*MF;            // 4 partials x 1MF
    float* yprojp  = big + 8*MF;            // 4 partials x 1MF (after hend dead)
    bf16*  ybf     = (bf16*)ff1;            // 4M els
    bf16*  ff1B    = (bf16*)ff1;
    bf16*  mbufB   = (bf16*)mbuf;

    k_cvt<<<4096,256,0,stream>>>(tf, tb, (const unsigned int*)d_in[0], inF, inB, flag,
                                 (int)(of>>2), (int)(ob>>2));

    // ---- self attention ----
    k_gemm64<<<dim3(24,32),256,0,stream>>>(tgt_f,0,512, PW(2),512, qkvB,1,1536, PF(3),0,512);
    k_flash2<<<dim3(16,16,8),256,0,stream>>>(qkvB,1536,0, qkvB,1536,512, qkvB,1536,1024, OpartB, Ml, 0.125f);
    k_fcomb<<<4096,256,0,stream>>>(OpartB, Ml, attnoB, Mfin);
    k_skp64<<<dim3(8,32,2),256,0,stream>>>(attnoB,1,0,512, PW(4),512, tpart,MF,512, PF(5), 512, 2);
    k_add_rmsnorm<<<2048,256,0,stream>>>(tgt_f, tpart, MF, 2, PF(10));

    // ---- cross attention ----
    k_gemm64<<<dim3(8,32),256,0,stream>>>(tgt_f,0,512, PW(6),512, qB,1,512, PF(7),0,512);
    k_gemm64<<<dim3(16,32),256,0,stream>>>(mem_f,0,512, PW(6)+(size_t)512*512,512, kvB,1,1024, PF(7)+512,0,512);
    k_flash2<<<dim3(16,16,8),256,0,stream>>>(qB,512,0, kvB,1024,0, kvB,1024,512, OpartB, Ml, 0.125f);
    k_fcomb<<<4096,256,0,stream>>>(OpartB, Ml, attnoB, Mfin);
    k_pmean<<<dim3(16,16,2),256,0,stream>>>(qB,512, kvB,1024, Mfin, d_out, flag, 0.125f);
    k_skp64<<<dim3(8,32,2),256,0,stream>>>(attnoB,1,0,512, PW(8),512, tpart,MF,512, PF(9), 512, 2);
    k_rms_ln<<<2048,256,0,stream>>>(tgt_f, tpart, MF, PF(11), PF(18), PF(19), xnB);

    // ---- bimamba ----
    k_gemm64<<<dim3(32,32),256,0,stream>>>(xnB,1,512, PW(26),512, xz,0,2048, PF(27),0,512);
    k_conv_silu<<<dim3(8192,2),256,0,stream>>>(xz, PF(28), PF(29), xmc_f, dbc_f);
    k_gemm_sk<<<dim3(1,32,8),256,0,stream>>>(xmc_f,1,2*MF,1024, PW(30),1024, dbc_f,131072,64, nullptr, 1024, 4);
    k_mfma_gemm<<<dim3(16,32,2),256,0,stream>>>(dbc_f,0,131072,0,64, PW(31),0,0,32,2, delta_f,1,2*MF,0,1024, PF(32),1.f,3,32,1);
    k_scan1<<<dim3(16,64),256,0,stream>>>(delta_f,delta_b,xmc_f,xmc_b,dbc_f,dbc_b, PF(33), hend, Sdl);
    k_scan_carry<<<256,256,0,stream>>>(PF(33), hend, Sdl);
    k_scan2<<<dim3(16,64),256,0,stream>>>(delta_f,delta_b,xmc_f,xmc_b,dbc_f,dbc_b, PF(33), hend, xz, PF(34), ybf);
    k_skp64<<<dim3(8,32,4),256,0,stream>>>(ybf,1,2*MF,1024, PW(35),1024, yprojp,MF,512, PF(36), 1024, 2);
    k_combine_ln<<<2048,256,0,stream>>>(yprojp, MF, PF(20), PF(21), mbufB);
    k_gemm64<<<dim3(32,32),256,0,stream>>>(mbufB,1,512, PW(22),512, ff1B,1,2048, PF(23),2,512);
    k_skp64<<<dim3(8,32,4),256,0,stream>>>(ff1B,1,0,2048, PW(24),2048, ffop,MF,512, PF(25), 2048, 4);
    k_bimamba_final<<<2048,256,0,stream>>>(tgt_f, ffop, MF, PF(12));

    // ---- final FFN ----
    k_gemm64<<<dim3(32,32),256,0,stream>>>(tgt_f,0,512, PW(14),512, ff1B,1,2048, PF(15),1,512);
    k_skp64<<<dim3(8,32,4),256,0,stream>>>(ff1B,1,0,2048, PW(16),2048, lin2p,MF,512, PF(17), 2048, 4);
    k_add_rmsnorm_out<<<2048,256,0,stream>>>(tgt_f, lin2p, MF, 4, PF(13), d_out, flag);
    #undef PF
    #undef PW
  }
}